// Round 7
// baseline (524.046 us; speedup 1.0000x reference)
//
#include <hip/hip_runtime.h>

#define EPS_LN 1e-8f

typedef __bf16 bf16x8 __attribute__((ext_vector_type(8)));
typedef float  f32x4  __attribute__((ext_vector_type(4)));

__device__ __forceinline__ float sigmoidf_(float x){ return 1.0f/(1.0f+__expf(-x)); }
__device__ __forceinline__ float siluf_(float x){ return x*sigmoidf_(x); }
__device__ __forceinline__ unsigned short f2bf(float x){ union{ __bf16 b; unsigned short u;} c; c.b = (__bf16)x; return c.u; }
__device__ __forceinline__ float bf2f(unsigned short u){ return __uint_as_float(((unsigned)u)<<16); }

union F4 { float4 v; float f[4]; };

// swizzled bf16 LDS store (fused fallback path)
__device__ __forceinline__ void st_bf4(char* base, int row, int stride_bytes, int k,
                                       float x0, float x1, float x2, float x3){
    union { __bf16 h[4]; unsigned long long u; } p;
    p.h[0]=(__bf16)x0; p.h[1]=(__bf16)x1; p.h[2]=(__bf16)x2; p.h[3]=(__bf16)x3;
    *(unsigned long long*)(base + row*stride_bytes + ((2*k) ^ ((row&7)<<4))) = p.u;
}
__device__ __forceinline__ bf16x8 ld_frag(const char* base, int row, int stride_bytes, int kbyte){
    return *(const bf16x8*)(base + row*stride_bytes + (kbyte ^ ((row&7)<<4)));
}
__device__ __forceinline__ void st_g4(__bf16* p, float x0, float x1, float x2, float x3){
    union { __bf16 h[4]; unsigned long long u; } pk;
    pk.h[0]=(__bf16)x0; pk.h[1]=(__bf16)x1; pk.h[2]=(__bf16)x2; pk.h[3]=(__bf16)x3;
    *(unsigned long long*)p = pk.u;
}
__device__ __forceinline__ uint4 pack8(float4 a, float4 b){
    union { __bf16 h[8]; uint4 u; } p;
    p.h[0]=(__bf16)a.x; p.h[1]=(__bf16)a.y; p.h[2]=(__bf16)a.z; p.h[3]=(__bf16)a.w;
    p.h[4]=(__bf16)b.x; p.h[5]=(__bf16)b.y; p.h[6]=(__bf16)b.z; p.h[7]=(__bf16)b.w;
    return p.u;
}
// fragment-major dest index for B[n][k] tiles (16 cols x 32 k per fragment)
__device__ __forceinline__ int fm_idx(int n, int k, int NKT){
    return ((n>>4)*NKT + (k>>5))*512 + ((k>>3)&3)*128 + (n&15)*8 + (k&7);
}

// ---------------- weight prep: transposes + f32->bf16 + fragment-major packs ----------------
__global__ void prep_weights(const float* __restrict__ w0,
                             const float* __restrict__ w1r, const float* __restrict__ w1i,
                             const float* __restrict__ env_w, const float* __restrict__ lp_ws,
                             const float* __restrict__ lp_wv,
                             __bf16* __restrict__ Wt, __bf16* __restrict__ w1rt, __bf16* __restrict__ w1it,
                             __bf16* __restrict__ Wfm, __bf16* __restrict__ Bvfm,
                             __bf16* __restrict__ envfm, __bf16* __restrict__ lpsfm,
                             __bf16* __restrict__ lpvfm)
{
    int t = blockIdx.x*256 + threadIdx.x;
    if (t < 576*256){
        int n = t/576, k = t%576;
        float v = w0[(size_t)k*256 + n];
        Wt[t] = (__bf16)v;                       // row-major [256][576] (fallback)
        Wfm[fm_idx(n,k,18)] = (__bf16)v;         // fragment-major
    }
    if (t < 64*192){
        int c = t/192, k = t%192;
        w1rt[t] = (__bf16)w1r[(size_t)k*64 + c];
        w1it[t] = (__bf16)w1i[(size_t)k*64 + c];
    }
    if (t < 128*384){
        int n = t/384, k = t%384;
        float v;
        if (n < 64) v = (k<192) ? w1r[(size_t)k*64+n] : -w1i[(size_t)(k-192)*64+n];
        else        v = (k<192) ? w1i[(size_t)k*64+(n-64)] : w1r[(size_t)(k-192)*64+(n-64)];
        Bvfm[fm_idx(n,k,12)] = (__bf16)v;
    }
    if (t < 192*128){ int n=t/128, k=t%128; envfm[fm_idx(n,k,4)] = (__bf16)env_w[(size_t)k*192+n]; }
    if (t < 128*128){ int n=t/128, k=t%128; lpsfm[fm_idx(n,k,4)] = (__bf16)lp_ws[(size_t)k*128+n]; }
    if (t < 64*64)  { int n=t/64,  k=t%64;  lpvfm[fm_idx(n,k,2)] = (__bf16)lp_wv[(size_t)k*64+n]; }
}

// ---------------- onehot weight transpose: [u][at][k] -> [at][u][k] bf16 ----------------
__global__ void prep_oh(const float* __restrict__ oh_ss, const float* __restrict__ oh_sg,
                        const float* __restrict__ oh_vv,
                        __bf16* __restrict__ ssT, __bf16* __restrict__ sgT, __bf16* __restrict__ vvT)
{
    int t = blockIdx.x*256 + threadIdx.x;
    if (t < 64*128*128){                       // ssT[at][u][k], u=128,k=128
        int at = t / 16384;
        int r  = t & 16383;
        int u = r >> 7, k = r & 127;
        ssT[t] = (__bf16)oh_ss[((size_t)u*64 + at)*128 + k];
    }
    if (t < 64*128*64){                        // sgT[at][u][k], u=128,k=64
        int at = t / 8192;
        int r  = t & 8191;
        int u = r >> 6, k = r & 63;
        sgT[t] = (__bf16)oh_sg[((size_t)u*64 + at)*64 + k];
    }
    if (t < 64*64*64){                         // vvT[at][u][k], u=64,k=64
        int at = t / 4096;
        int r  = t & 4095;
        int u = r >> 6, k = r & 63;
        vvT[t] = (__bf16)oh_vv[((size_t)u*64 + at)*64 + k];
    }
}

// ---------------- CSR build ----------------
__global__ void csr_count(const int* __restrict__ ei, const int* __restrict__ act,
                          int* __restrict__ cnt, int EA)
{
    int e = blockIdx.x*256 + threadIdx.x;
    if (e < EA) atomicAdd(&cnt[ei[act[e]]], 1);
}
__global__ void csr_scan(const int* __restrict__ cnt, int* __restrict__ offs,
                         int* __restrict__ cursor, int N)
{
    __shared__ int part[256];
    int t = threadIdx.x;
    int chunk = (N + 255) / 256;
    int lo = t*chunk, hi = lo+chunk; if (hi > N) hi = N; if (lo > N) lo = N;
    int s = 0;
    for (int i=lo;i<hi;i++) s += cnt[i];
    part[t] = s;
    __syncthreads();
    for (int d=1; d<256; d<<=1){
        int v = (t>=d) ? part[t-d] : 0;
        __syncthreads();
        part[t] += v;
        __syncthreads();
    }
    int run = (t==0) ? 0 : part[t-1];
    for (int i=lo;i<hi;i++){
        offs[i] = run; cursor[i] = run;
        run += cnt[i];
    }
    if (t==255) offs[N] = part[255];
}
__global__ void csr_fill(const int* __restrict__ ei, const int* __restrict__ act,
                         int* __restrict__ cursor, int* __restrict__ elist, int EA)
{
    int e = blockIdx.x*256 + threadIdx.x;
    if (e < EA){
        int n = ei[act[e]];
        int p = atomicAdd(&cursor[n], 1);
        elist[p] = e;
    }
}

// ---------------- node separable layernorm ----------------
__global__ void node_ln_kernel(const float* __restrict__ nf,
                               const float* __restrict__ ws, const float* __restrict__ bs,
                               const float* __restrict__ wv,
                               float* __restrict__ ns, float* __restrict__ nv, int N)
{
    int t = threadIdx.x;
    int lane = t & 63;
    int n = blockIdx.x*4 + (t>>6);
    if (n >= N) return;
    const float* row = nf + (size_t)n*320;
    float s0 = row[lane], s1 = row[64+lane];
    float sum = s0+s1, sq = s0*s0+s1*s1;
    #pragma unroll
    for (int m=1;m<64;m<<=1){ sum += __shfl_xor(sum,m,64); sq += __shfl_xor(sq,m,64); }
    float mu = sum*(1.0f/128.0f);
    float rs = rsqrtf(sq*(1.0f/128.0f) - mu*mu + EPS_LN);
    ns[(size_t)n*128+lane]    = (s0-mu)*rs*ws[lane]    + bs[lane];
    ns[(size_t)n*128+64+lane] = (s1-mu)*rs*ws[64+lane] + bs[64+lane];
    float v0 = row[128+lane], v1 = row[192+lane], v2 = row[256+lane];
    float vs = v0*v0+v1*v1+v2*v2;
    #pragma unroll
    for (int m=1;m<64;m<<=1) vs += __shfl_xor(vs,m,64);
    float rv = rsqrtf(vs*(1.0f/192.0f) + EPS_LN);
    nv[(size_t)n*192+lane]     = v0*rv*wv[lane/3];
    nv[(size_t)n*192+64+lane]  = v1*rv*wv[(64+lane)/3];
    nv[(size_t)n*192+128+lane] = v2*rv*wv[(128+lane)/3];
}

// ---------------- per-edge staging -> global bf16 ----------------
__global__ void stage_kernel(
    const float* __restrict__ ef_all,
    const int*   __restrict__ edge_index,
    const float* __restrict__ edge_vector,
    const int*   __restrict__ active_edges,
    const float* __restrict__ e_ws, const float* __restrict__ e_bs, const float* __restrict__ e_wv,
    const float* __restrict__ ns, const float* __restrict__ nv,
    __bf16* __restrict__ m0in, __bf16* __restrict__ vfg,
    float* __restrict__ Rg,
    int EA, int EF)
{
    int tid = blockIdx.x*256 + threadIdx.x;
    int e = tid >> 4, l = tid & 15;
    if (e >= EA) return;
    int ae = active_edges[e];
    int ct = edge_index[ae];
    int nb = edge_index[EF + ae];
    float ex = edge_vector[(size_t)ae*3+0];
    float ey = edge_vector[(size_t)ae*3+1];
    float ez = edge_vector[(size_t)ae*3+2];
    float rn = rsqrtf(ex*ex+ey*ey+ez*ez + EPS_LN);
    float ax = ex*rn, ay = ey*rn, az = ez*rn;
    float rx, ry;
    if (fabsf(ax) < 0.9f) { rx = 1.0f; ry = 0.0f; } else { rx = 0.0f; ry = 1.0f; }
    float bx = -az*ry, by = az*rx, bz = ax*ry - ay*rx;
    float bn = rsqrtf(bx*bx+by*by+bz*bz + EPS_LN);
    bx*=bn; by*=bn; bz*=bn;
    float cx = ay*bz - az*by;
    float cy = az*bx - ax*bz;
    float cz = ax*by - ay*bx;
    if (l == 0){
        float* Rr = Rg + (size_t)e*12;
        *(float4*)(Rr)   = make_float4(ax,ay,az,bx);
        *(float4*)(Rr+4) = make_float4(by,bz,cx,cy);
        *(float4*)(Rr+8) = make_float4(cz,0.f,0.f,0.f);
    }
    __bf16* Arow = m0in + (size_t)e*576;
    __bf16* V1r  = vfg + (size_t)e*384;
    __bf16* V2r  = V1r + 192;
    {
        const float4* pc4 = (const float4*)(ns + (size_t)ct*128);
        const float4* pn4 = (const float4*)(ns + (size_t)nb*128);
        F4 a,b2,c,d;
        a.v = pc4[l]; b2.v = pc4[16+l]; c.v = pn4[l]; d.v = pn4[16+l];
        st_g4(Arow + l*4,       a.f[0],a.f[1],a.f[2],a.f[3]);
        st_g4(Arow + 64 + l*4,  b2.f[0],b2.f[1],b2.f[2],b2.f[3]);
        st_g4(Arow + 256 + l*4, c.f[0],c.f[1],c.f[2],c.f[3]);
        st_g4(Arow + 320 + l*4, d.f[0],d.f[1],d.f[2],d.f[3]);
    }
    const float* ef = ef_all + (size_t)e*320;
    {
        F4 sa, sb;
        sa.v = *(const float4*)(ef + l*4);
        sb.v = *(const float4*)(ef + 64 + l*4);
        float sum=0.f, sq=0.f;
        #pragma unroll
        for (int i=0;i<4;i++){ sum += sa.f[i]+sb.f[i]; sq += sa.f[i]*sa.f[i]+sb.f[i]*sb.f[i]; }
        #pragma unroll
        for (int m=1;m<16;m<<=1){ sum += __shfl_xor(sum,m,64); sq += __shfl_xor(sq,m,64); }
        float mu = sum*(1.0f/128.0f);
        float rs = rsqrtf(sq*(1.0f/128.0f)-mu*mu + EPS_LN);
        float o0[4], o1[4];
        #pragma unroll
        for (int i=0;i<4;i++){
            int c0 = l*4+i, c1 = 64+l*4+i;
            o0[i] = (sa.f[i]-mu)*rs*e_ws[c0]+e_bs[c0];
            o1[i] = (sb.f[i]-mu)*rs*e_ws[c1]+e_bs[c1];
        }
        st_g4(Arow + 128 + l*4, o0[0],o0[1],o0[2],o0[3]);
        st_g4(Arow + 192 + l*4, o1[0],o1[1],o1[2],o1[3]);
    }
    {   // edge vector LN + rotate (u 64..127)
        F4 va, vb, vc;
        va.v = *(const float4*)(ef + 128 + l*12);
        vb.v = *(const float4*)(ef + 128 + l*12 + 4);
        vc.v = *(const float4*)(ef + 128 + l*12 + 8);
        float vv[12];
        #pragma unroll
        for (int i=0;i<4;i++){ vv[i]=va.f[i]; vv[4+i]=vb.f[i]; vv[8+i]=vc.f[i]; }
        float sq=0.f;
        #pragma unroll
        for (int i=0;i<12;i++) sq += vv[i]*vv[i];
        #pragma unroll
        for (int m=1;m<16;m<<=1) sq += __shfl_xor(sq,m,64);
        float rv = rsqrtf(sq*(1.0f/192.0f) + EPS_LN);
        float f0[4], f1[4], f2[4];
        #pragma unroll
        for (int j=0;j<4;j++){
            int u = 4*l + j;
            float sc = rv * e_wv[u];
            float x = vv[3*j]*sc, y = vv[3*j+1]*sc, z = vv[3*j+2]*sc;
            f0[j] = ax*x+ay*y+az*z;
            f1[j] = bx*x+by*y+bz*z;
            f2[j] = cx*x+cy*y+cz*z;
        }
        st_g4(Arow + 384 + 64 + 4*l, f0[0],f0[1],f0[2],f0[3]);
        st_g4(V1r + 64 + 4*l, f1[0],f1[1],f1[2],f1[3]);
        st_g4(V2r + 64 + 4*l, f2[0],f2[1],f2[2],f2[3]);
    }
    {   // nv[ctr] (u 0..63)
        const float* pv = nv + (size_t)ct*192 + l*12;
        F4 va, vb, vc;
        va.v = *(const float4*)(pv);
        vb.v = *(const float4*)(pv+4);
        vc.v = *(const float4*)(pv+8);
        float vv[12];
        #pragma unroll
        for (int i=0;i<4;i++){ vv[i]=va.f[i]; vv[4+i]=vb.f[i]; vv[8+i]=vc.f[i]; }
        float f0[4], f1[4], f2[4];
        #pragma unroll
        for (int j=0;j<4;j++){
            float x = vv[3*j], y = vv[3*j+1], z = vv[3*j+2];
            f0[j] = ax*x+ay*y+az*z;
            f1[j] = bx*x+by*y+bz*z;
            f2[j] = cx*x+cy*y+cz*z;
        }
        st_g4(Arow + 384 + 4*l, f0[0],f0[1],f0[2],f0[3]);
        st_g4(V1r + 4*l, f1[0],f1[1],f1[2],f1[3]);
        st_g4(V2r + 4*l, f2[0],f2[1],f2[2],f2[3]);
    }
    {   // nv[nbr] (u 128..191)
        const float* pv = nv + (size_t)nb*192 + l*12;
        F4 va, vb, vc;
        va.v = *(const float4*)(pv);
        vb.v = *(const float4*)(pv+4);
        vc.v = *(const float4*)(pv+8);
        float vv[12];
        #pragma unroll
        for (int i=0;i<4;i++){ vv[i]=va.f[i]; vv[4+i]=vb.f[i]; vv[8+i]=vc.f[i]; }
        float f0[4], f1[4], f2[4];
        #pragma unroll
        for (int j=0;j<4;j++){
            float x = vv[3*j], y = vv[3*j+1], z = vv[3*j+2];
            f0[j] = ax*x+ay*y+az*z;
            f1[j] = bx*x+by*y+bz*z;
            f2[j] = cx*x+cy*y+cz*z;
        }
        st_g4(Arow + 384 + 128 + 4*l, f0[0],f0[1],f0[2],f0[3]);
        st_g4(V1r + 128 + 4*l, f1[0],f1[1],f1[2],f1[3]);
        st_g4(V2r + 128 + 4*l, f2[0],f2[1],f2[2],f2[3]);
    }
}

// ---------------- tiled MFMA GEMM, fragment-major B direct from global (L2-resident) ----
enum { EPI_PLAIN=0, EPI_LPS=1, EPI_LPV=2 };

template<int N, int K, int RT, int EPI, bool AGATHER>
__global__ __launch_bounds__((N/64)*RT*64)
void gemm_k(const __bf16* __restrict__ Ag, const float* __restrict__ Agf,
            const int* __restrict__ aidx,
            const __bf16* __restrict__ Bfm,
            unsigned short* __restrict__ outp,
            const unsigned short* __restrict__ wenv,
            const float* __restrict__ bias,
            float scale, int M)
{
    constexpr int NT  = N/64;
    constexpr int BM  = RT*64;
    constexpr int T   = NT*RT*64;
    constexpr int NKT = K/32;
    constexpr int NK  = K/64;
    constexpr int CA  = (BM*8 + T - 1)/T;
    __shared__ __align__(16) char lA[2][BM*128];

    const int tid  = threadIdx.x;
    const int brow = blockIdx.x*BM;
    const int mpl  = blockIdx.y;
    const __bf16* A = AGATHER ? nullptr : (Ag + (size_t)mpl*M*K);

    uint4 ra[CA];
    auto loadA = [&](int ks){
        #pragma unroll
        for (int i=0;i<CA;i++){
            int c = tid + i*T;
            if (c < BM*8){
                int r = c>>3;
                int gr = brow + r; if (gr >= M) gr = M-1;
                if constexpr (AGATHER){
                    int ae = aidx[gr];
                    const float* base = Agf + (size_t)ae*K + ks*64 + (c&7)*8;
                    float4 f0 = *(const float4*)(base);
                    float4 f1 = *(const float4*)(base+4);
                    ra[i] = pack8(f0, f1);
                } else {
                    ra[i] = *(const uint4*)((const char*)(A + (size_t)gr*K + ks*64) + (c&7)*16);
                }
            }
        }
    };
    auto storeA = [&](int buf){
        #pragma unroll
        for (int i=0;i<CA;i++){
            int c = tid + i*T;
            if (c < BM*8){
                int r = c>>3, off = (c&7)*16;
                *(uint4*)(&lA[buf][r*128 + (off ^ ((r&7)<<4))]) = ra[i];
            }
        }
    };

    const int wid = tid>>6, ln = tid&63;
    const int cc = ln & 15, gq = ln >> 4;
    const int wn = wid % NT, wm = wid / NT;
    const __bf16* bbase = Bfm + ((size_t)wn*4*NKT)*512 + (size_t)ln*8;

    f32x4 acc[4][4];
    #pragma unroll
    for (int i=0;i<4;i++)
        #pragma unroll
        for (int j=0;j<4;j++) acc[i][j] = (f32x4){0,0,0,0};

    loadA(0); storeA(0);
    int cur = 0;
    for (int ks=0; ks<NK; ks++){
        __syncthreads();
        if (ks+1 < NK) loadA(ks+1);
        #pragma unroll
        for (int kt2=0;kt2<2;kt2++){
            const int kt = ks*2 + kt2;
            const int kb = kt2*64 + 16*gq;
            bf16x8 af[4];
            #pragma unroll
            for (int mf=0;mf<4;mf++){
                int r = wm*64 + mf*16 + cc;
                af[mf] = *(const bf16x8*)(&lA[cur][r*128 + (kb ^ ((r&7)<<4))]);
            }
            #pragma unroll
            for (int nf=0;nf<4;nf++){
                bf16x8 bfr = *(const bf16x8*)(bbase + ((size_t)nf*NKT + kt)*512);
                #pragma unroll
                for (int mf=0;mf<4;mf++)
                    acc[mf][nf] = __builtin_amdgcn_mfma_f32_16x16x32_bf16(af[mf], bfr, acc[mf][nf], 0,0,0);
            }
        }
        if (ks+1 < NK) storeA(cur^1);
        cur ^= 1;
    }

    const float inv_avg_ = 0.288675134595f;
    #pragma unroll
    for (int mf=0;mf<4;mf++){
        #pragma unroll
        for (int nf=0;nf<4;nf++){
            #pragma unroll
            for (int j=0;j<4;j++){
                int gr = brow + wm*64 + mf*16 + gq*4 + j;
                if (gr >= M) continue;
                int col = wn*64 + nf*16 + cc;
                float v = acc[mf][nf][j];
                if constexpr (EPI == EPI_PLAIN){
                    outp[(size_t)gr*N + col] = f2bf(v*scale);
                } else if constexpr (EPI == EPI_LPS){
                    float val = (v*scale + bias[col]) * bf2f(wenv[(size_t)gr*192 + col]) * inv_avg_;
                    outp[(size_t)gr*320 + col] = f2bf(val);
                } else {
                    float val = v*0.125f * bf2f(wenv[(size_t)gr*192 + 128 + col]) * inv_avg_;
                    outp[(size_t)gr*320 + 128 + mpl*64 + col] = f2bf(val);
                }
            }
        }
    }
}

// ---------------- mid: gate + rotate-back + silu (elementwise) ----------------
__global__ void mid_kernel(const unsigned short* __restrict__ m0out,
                           const unsigned short* __restrict__ vpvm,
                           const float* __restrict__ Rg,
                           unsigned short* __restrict__ As,
                           unsigned short* __restrict__ MVp, int EA)
{
    int tid = blockIdx.x*256 + threadIdx.x;
    int e = tid>>6, u = tid&63;
    if (e >= EA) return;
    // lanes 0..11 load R, broadcast via shfl (wave = one edge)
    float rl = (u < 12) ? Rg[(size_t)e*12 + u] : 0.f;
    float R0=__shfl(rl,0,64), R1=__shfl(rl,1,64), R2=__shfl(rl,2,64);
    float R3=__shfl(rl,3,64), R4=__shfl(rl,4,64), R5=__shfl(rl,5,64);
    float R6=__shfl(rl,6,64), R7=__shfl(rl,7,64), R8=__shfl(rl,8,64);
    const unsigned short* mo = m0out + (size_t)e*256;
    float s0 = bf2f(mo[192 + u]);
    float gt = sigmoidf_(bf2f(mo[128 + u]));
    float p  = bf2f(vpvm[(size_t)e*128 + u]);
    float q  = bf2f(vpvm[(size_t)e*128 + 64 + u]);
    size_t eu = (size_t)e*64 + u;
    size_t P  = (size_t)EA*64;
    MVp[eu]       = f2bf(gt*(R0*s0 + R3*p + R6*q));
    MVp[P + eu]   = f2bf(gt*(R1*s0 + R4*p + R7*q));
    MVp[2*P + eu] = f2bf(gt*(R2*s0 + R5*p + R8*q));
    As[(size_t)e*128 + u]      = f2bf(siluf_(bf2f(mo[u])));
    As[(size_t)e*128 + 64 + u] = f2bf(siluf_(bf2f(mo[64 + u])));
}

// ---------------- fallback: fused edge kernel (round-3, plane-layout stores) ----------------
__launch_bounds__(256, 3)
__global__ void edge_kernel_fused(
    const float* __restrict__ latents,
    const float* __restrict__ ef_all,
    const int*   __restrict__ edge_index,
    const float* __restrict__ edge_vector,
    const int*   __restrict__ active_edges,
    const float* __restrict__ e_ws, const float* __restrict__ e_bs, const float* __restrict__ e_wv,
    const __bf16* __restrict__ Wt,
    const __bf16* __restrict__ w1rt,
    const __bf16* __restrict__ w1it,
    const float* __restrict__ env_w,
    const float* __restrict__ lp_ws, const float* __restrict__ lp_bs, const float* __restrict__ lp_wv,
    const float* __restrict__ ns, const float* __restrict__ nv,
    unsigned short* __restrict__ eout,
    int EA, int EF)
{
    __shared__ __align__(16) char smem[46592];
    char* sAbC = smem;
    char* sVFC = smem + 18432;
    float* sO  = (float*)smem;
    float* MV  = (float*)(smem + 16640);
    float* WE  = (float*)(smem + 33280);
    float* sR  = (float*)(smem + 45824);

    const int t = threadIdx.x;
    const int g = t >> 4, l = t & 15;
    const int e = blockIdx.x*16 + g;
    const bool act = (e < EA);

    int ct = 0, ae = 0;

    if (act) {
        ae = active_edges[e];
        ct = edge_index[ae];
        int nb = edge_index[EF + ae];
        float ex = edge_vector[(size_t)ae*3+0];
        float ey = edge_vector[(size_t)ae*3+1];
        float ez = edge_vector[(size_t)ae*3+2];
        float rn = rsqrtf(ex*ex+ey*ey+ez*ez + EPS_LN);
        float ax = ex*rn, ay = ey*rn, az = ez*rn;
        float rx, ry;
        if (fabsf(ax) < 0.9f) { rx = 1.0f; ry = 0.0f; } else { rx = 0.0f; ry = 1.0f; }
        float bx = -az*ry, by = az*rx, bz = ax*ry - ay*rx;
        float bn = rsqrtf(bx*bx+by*by+bz*bz + EPS_LN);
        bx*=bn; by*=bn; bz*=bn;
        float cx = ay*bz - az*by;
        float cy = az*bx - ax*bz;
        float cz = ax*by - ay*bx;
        if (l == 0){
            float* Rr = &sR[g*12];
            Rr[0]=ax; Rr[1]=ay; Rr[2]=az;
            Rr[3]=bx; Rr[4]=by; Rr[5]=bz;
            Rr[6]=cx; Rr[7]=cy; Rr[8]=cz;
        }
        {
            const float4* pc4 = (const float4*)(ns + (size_t)ct*128);
            const float4* pn4 = (const float4*)(ns + (size_t)nb*128);
            F4 a,b2,c,d;
            a.v = pc4[l]; b2.v = pc4[16+l]; c.v = pn4[l]; d.v = pn4[16+l];
            st_bf4(sAbC, g, 1152, l*4,       a.f[0],a.f[1],a.f[2],a.f[3]);
            st_bf4(sAbC, g, 1152, 64+l*4,    b2.f[0],b2.f[1],b2.f[2],b2.f[3]);
            st_bf4(sAbC, g, 1152, 256+l*4,   c.f[0],c.f[1],c.f[2],c.f[3]);
            st_bf4(sAbC, g, 1152, 320+l*4,   d.f[0],d.f[1],d.f[2],d.f[3]);
        }
        const float* ef = ef_all + (size_t)e*320;
        {
            F4 sa, sb;
            sa.v = *(const float4*)(ef + l*4);
            sb.v = *(const float4*)(ef + 64 + l*4);
            float sum=0.f, sq=0.f;
            #pragma unroll
            for (int i=0;i<4;i++){ sum += sa.f[i]+sb.f[i]; sq += sa.f[i]*sa.f[i]+sb.f[i]*sb.f[i]; }
            #pragma unroll
            for (int m=1;m<16;m<<=1){ sum += __shfl_xor(sum,m,64); sq += __shfl_xor(sq,m,64); }
            float mu = sum*(1.0f/128.0f);
            float rs = rsqrtf(sq*(1.0f/128.0f)-mu*mu + EPS_LN);
            float o0[4], o1[4];
            #pragma unroll
            for (int i=0;i<4;i++){
                int c0 = l*4+i, c1 = 64+l*4+i;
                o0[i] = (sa.f[i]-mu)*rs*e_ws[c0]+e_bs[c0];
                o1[i] = (sb.f[i]-mu)*rs*e_ws[c1]+e_bs[c1];
            }
            st_bf4(sAbC, g, 1152, 128+l*4, o0[0],o0[1],o0[2],o0[3]);
            st_bf4(sAbC, g, 1152, 192+l*4, o1[0],o1[1],o1[2],o1[3]);
        }
        {
            F4 va, vb, vc;
            va.v = *(const float4*)(ef + 128 + l*12);
            vb.v = *(const float4*)(ef + 128 + l*12 + 4);
            vc.v = *(const float4*)(ef + 128 + l*12 + 8);
            float vv[12];
            #pragma unroll
            for (int i=0;i<4;i++){ vv[i]=va.f[i]; vv[4+i]=vb.f[i]; vv[8+i]=vc.f[i]; }
            float sq=0.f;
            #pragma unroll
            for (int i=0;i<12;i++) sq += vv[i]*vv[i];
            #pragma unroll
            for (int m=1;m<16;m<<=1) sq += __shfl_xor(sq,m,64);
            float rv = rsqrtf(sq*(1.0f/192.0f) + EPS_LN);
            float f0[4], f1[4], f2[4];
            #pragma unroll
            for (int j=0;j<4;j++){
                int u = 4*l + j;
                float sc = rv * e_wv[u];
                float x = vv[3*j]*sc, y = vv[3*j+1]*sc, z = vv[3*j+2]*sc;
                f0[j] = ax*x+ay*y+az*z;
                f1[j] = bx*x+by*y+bz*z;
                f2[j] = cx*x+cy*y+cz*z;
            }
            st_bf4(sAbC, g, 1152, 384+64+4*l, f0[0],f0[1],f0[2],f0[3]);
            st_bf4(sVFC, g, 384, 64+4*l, f1[0],f1[1],f1[2],f1[3]);
            st_bf4(sVFC+6144, g, 384, 64+4*l, f2[0],f2[1],f2[2],f2[3]);
        }
        {
            const float* pv = nv + (size_t)ct*192 + l*12;
            F4 va, vb, vc;
            va.v = *(const float4*)(pv);
            vb.v = *(const float4*)(pv+4);
            vc.v = *(const float4*)(pv+8);
            float vv[12];
            #pragma unroll
            for (int i=0;i<4;i++){ vv[i]=va.f[i]; vv[4+i]=vb.f[i]; vv[8+i]=vc.f[i]; }
            float f0[4], f1[4], f2[4];
            #pragma unroll
            for (int j=0;j<4;j++){
                float x = vv[3*j], y = vv[3*j+1], z = vv[3*j+2];
                f0[j] = ax*x+ay*y+az*z;
                f1[j] = bx*x+by*y+bz*z;
                f2[j] = cx*x+cy*y+cz*z;
            }
            st_bf4(sAbC, g, 1152, 384+4*l, f0[0],f0[1],f0[2],f0[3]);
            st_bf4(sVFC, g, 384, 4*l, f1[0],f1[1],f1[2],f1[3]);
            st_bf4(sVFC+6144, g, 384, 4*l, f2[0],f2[1],f2[2],f2[3]);
        }
        {
            const float* pv = nv + (size_t)nb*192 + l*12;
            F4 va, vb, vc;
            va.v = *(const float4*)(pv);
            vb.v = *(const float4*)(pv+4);
            vc.v = *(const float4*)(pv+8);
            float vv[12];
            #pragma unroll
            for (int i=0;i<4;i++){ vv[i]=va.f[i]; vv[4+i]=vb.f[i]; vv[8+i]=vc.f[i]; }
            float f0[4], f1[4], f2[4];
            #pragma unroll
            for (int j=0;j<4;j++){
                float x = vv[3*j], y = vv[3*j+1], z = vv[3*j+2];
                f0[j] = ax*x+ay*y+az*z;
                f1[j] = bx*x+by*y+bz*z;
                f2[j] = cx*x+cy*y+cz*z;
            }
            st_bf4(sAbC, g, 1152, 384+128+4*l, f0[0],f0[1],f0[2],f0[3]);
            st_bf4(sVFC, g, 384, 128+4*l, f1[0],f1[1],f1[2],f1[3]);
            st_bf4(sVFC+6144, g, 384, 128+4*l, f2[0],f2[1],f2[2],f2[3]);
        }
    }
    __syncthreads();

    const int w  = t >> 6;
    const int ln = t & 63;
    const int cc = ln & 15;
    const int gq = ln >> 4;

    f32x4 accM[4] = {{0,0,0,0},{0,0,0,0},{0,0,0,0},{0,0,0,0}};
    {
        const __bf16* wb0 = Wt + (size_t)(64*w + 0  + cc)*576;
        const __bf16* wb1 = Wt + (size_t)(64*w + 16 + cc)*576;
        const __bf16* wb2 = Wt + (size_t)(64*w + 32 + cc)*576;
        const __bf16* wb3 = Wt + (size_t)(64*w + 48 + cc)*576;
        for (int ks=0; ks<18; ks++){
            bf16x8 a = ld_frag(sAbC, cc, 1152, ks*64 + 16*gq);
            int ko = ks*32 + 8*gq;
            bf16x8 b0 = *(const bf16x8*)(wb0 + ko);
            bf16x8 b1 = *(const bf16x8*)(wb1 + ko);
            bf16x8 b2 = *(const bf16x8*)(wb2 + ko);
            bf16x8 b3 = *(const bf16x8*)(wb3 + ko);
            accM[0] = __builtin_amdgcn_mfma_f32_16x16x32_bf16(a, b0, accM[0], 0,0,0);
            accM[1] = __builtin_amdgcn_mfma_f32_16x16x32_bf16(a, b1, accM[1], 0,0,0);
            accM[2] = __builtin_amdgcn_mfma_f32_16x16x32_bf16(a, b2, accM[2], 0,0,0);
            accM[3] = __builtin_amdgcn_mfma_f32_16x16x32_bf16(a, b3, accM[3], 0,0,0);
        }
    }
    f32x4 aP1={0,0,0,0}, aP2={0,0,0,0}, aM1={0,0,0,0}, aM2={0,0,0,0};
    {
        const __bf16* wr = w1rt + (size_t)(16*w + cc)*192;
        const __bf16* wi = w1it + (size_t)(16*w + cc)*192;
        for (int ks=0; ks<6; ks++){
            bf16x8 a1 = ld_frag(sVFC,        cc, 384, ks*64 + 16*gq);
            bf16x8 a2 = ld_frag(sVFC + 6144, cc, 384, ks*64 + 16*gq);
            int ko = ks*32 + 8*gq;
            bf16x8 br = *(const bf16x8*)(wr + ko);
            bf16x8 bi = *(const bf16x8*)(wi + ko);
            aP1 = __builtin_amdgcn_mfma_f32_16x16x32_bf16(a1, br, aP1, 0,0,0);
            aP2 = __builtin_amdgcn_mfma_f32_16x16x32_bf16(a2, bi, aP2, 0,0,0);
            aM1 = __builtin_amdgcn_mfma_f32_16x16x32_bf16(a1, bi, aM1, 0,0,0);
            aM2 = __builtin_amdgcn_mfma_f32_16x16x32_bf16(a2, br, aM2, 0,0,0);
        }
    }
    __syncthreads();

    {
        const float rn0 = 0.0416666666667f;
        #pragma unroll
        for (int jt=0;jt<4;jt++){
            #pragma unroll
            for (int j=0;j<4;j++){
                sO[(gq*4+j)*260 + 64*w + 16*jt + cc] = accM[jt][j]*rn0;
            }
        }
    }
    float vp[4], vm[4];
    {
        const float n1 = 0.0721687836487f;
        #pragma unroll
        for (int j=0;j<4;j++){ vp[j] = (aP1[j]-aP2[j])*n1; vm[j] = (aM1[j]+aM2[j])*n1; }
    }
    __syncthreads();

    {
        int u = w*16 + cc;
        #pragma unroll
        for (int j=0;j<4;j++){
            int er = gq*4 + j;
            if (blockIdx.x*16 + er < EA){
                const float* Rr = &sR[er*12];
                float s0 = sO[er*260 + 192 + u];
                float gt = sigmoidf_(sO[er*260 + 128 + u]);
                float p = vp[j], q = vm[j];
                float4 o;
                o.x = gt*(Rr[0]*s0 + Rr[3]*p + Rr[6]*q);
                o.y = gt*(Rr[1]*s0 + Rr[4]*p + Rr[7]*q);
                o.z = gt*(Rr[2]*s0 + Rr[5]*p + Rr[8]*q);
                o.w = 0.0f;
                *(float4*)&MV[er*260 + u*4] = o;
            }
        }
    }
    if (act) {
        {
            int i0 = l*8;
            F4 oa, ob;
            oa.v = *(const float4*)&sO[g*260 + i0];
            ob.v = *(const float4*)&sO[g*260 + i0 + 4];
            #pragma unroll
            for (int i=0;i<4;i++){ oa.f[i] = siluf_(oa.f[i]); ob.f[i] = siluf_(ob.f[i]); }
            *(float4*)&sO[g*260 + i0]     = oa.v;
            *(float4*)&sO[g*260 + i0 + 4] = ob.v;
        }
        {
            const int cc2 = l*12;
            float wacc[12];
            #pragma unroll
            for (int i=0;i<12;i++) wacc[i]=0.f;
            const float* lat = latents + (size_t)ae*128;
            for (int k=0;k<128;k+=4){
                F4 la;
                la.v = *(const float4*)(lat + k);
                #pragma unroll
                for (int kk=0;kk<4;kk++){
                    const float* er_ = env_w + (size_t)(k+kk)*192 + cc2;
                    F4 e0v,e1v,e2v;
                    e0v.v = *(const float4*)(er_);
                    e1v.v = *(const float4*)(er_+4);
                    e2v.v = *(const float4*)(er_+8);
                    #pragma unroll
                    for (int i=0;i<4;i++){
                        wacc[i]   += la.f[kk]*e0v.f[i];
                        wacc[4+i] += la.f[kk]*e1v.f[i];
                        wacc[8+i] += la.f[kk]*e2v.f[i];
                    }
                }
            }
            const float inv128 = 0.0883883476483f;
            #pragma unroll
            for (int i=0;i<12;i++) WE[g*196 + cc2 + i] = wacc[i]*inv128;
        }
    }
    __syncthreads();

    if (act) {
        const float inv_avg = 0.288675134595f;
        unsigned short* orow = eout + (size_t)e*320;
        {
            int c0 = l*8;
            float a8[8];
            #pragma unroll
            for (int i=0;i<8;i++) a8[i]=0.f;
            for (int k=0;k<128;k+=4){
                F4 av;
                av.v = *(const float4*)&sO[g*260 + k];
                #pragma unroll
                for (int kk=0;kk<4;kk++){
                    const float* wr = lp_ws + (size_t)(k+kk)*128 + c0;
                    F4 w0, w1_;
                    w0.v  = *(const float4*)(wr);
                    w1_.v = *(const float4*)(wr+4);
                    #pragma unroll
                    for (int i=0;i<4;i++){ a8[i] += av.f[kk]*w0.f[i]; a8[4+i] += av.f[kk]*w1_.f[i]; }
                }
            }
            const float s128 = 0.0883883476483f;
            union { unsigned short h[8]; uint4 u; } ps;
            #pragma unroll
            for (int i=0;i<8;i++){
                int c = c0+i;
                ps.h[i] = f2bf((a8[i]*s128 + lp_bs[c]) * WE[g*196 + c] * inv_avg);
            }
            *(uint4*)(orow + c0) = ps.u;
        }
        {
            int k0 = l*4;
            float av[4][3];
            #pragma unroll
            for (int j=0;j<4;j++)
                #pragma unroll
                for (int m2=0;m2<3;m2++) av[j][m2]=0.f;
            for (int u=0;u<64;u++){
                F4 wv4, mv4;
                wv4.v = *(const float4*)(lp_wv + (size_t)u*64 + k0);
                mv4.v = *(const float4*)&MV[g*260 + u*4];
                #pragma unroll
                for (int j=0;j<4;j++){
                    av[j][0] += wv4.f[j]*mv4.f[0];
                    av[j][1] += wv4.f[j]*mv4.f[1];
                    av[j][2] += wv4.f[j]*mv4.f[2];
                }
            }
            #pragma unroll
            for (int j=0;j<4;j++){
                int k = k0+j;
                float wk = WE[g*196 + 128 + k] * 0.125f * inv_avg;
                orow[128 +       k] = f2bf(av[j][0]*wk);
                orow[128 + 64  + k] = f2bf(av[j][1]*wk);
                orow[128 + 128 + k] = f2bf(av[j][2]*wk);
            }
        }
    }
}

// ---------------- node CSR aggregate + onehot path + output (transposed bf16 oh) ----------------
__global__ void node_out_kernel(
    const float* __restrict__ nf,
    const int* __restrict__ atom_type,
    const int* __restrict__ offs, const int* __restrict__ elist,
    const unsigned short* __restrict__ eout,
    const __bf16* __restrict__ ssT, const __bf16* __restrict__ sgT, const __bf16* __restrict__ vvT,
    const float* __restrict__ ohl_ws, const float* __restrict__ ohl_bs, const float* __restrict__ ohl_wv,
    const float* __restrict__ res_param,
    float* __restrict__ out, int N)
{
    __shared__ float AGS[128];
    __shared__ float AGV[192];
    __shared__ float TSs[128];
    __shared__ float SG[64];
    __shared__ float TV[192];
    const int n = blockIdx.x;
    const int t = threadIdx.x;
    const int at = atom_type[n];

    {
        int lo = offs[n], hi = offs[n+1];
        float a0 = 0.f, a1 = 0.f;
        for (int i=lo;i<hi;i++){
            const unsigned short* row = eout + (size_t)elist[i]*320;
            a0 += bf2f(row[t]);
            if (t < 64) a1 += bf2f(row[256+t]);
        }
        if (t < 128) AGS[t] = a0;
        else { int idx = t-128; AGV[(idx&63)*3 + (idx>>6)] = a0; }
        if (t < 64) AGV[t*3+2] = a1;
    }
    __syncthreads();
    const float n_ss = 0.0110485434560f;
    const float n_vv = 0.015625f;
    if (t < 128) {
        const __bf16* w = ssT + (size_t)at*16384 + t;   // [at][u][k], k=t, stride 128
        float acc = 0.0f;
        #pragma unroll 4
        for (int u=0;u<128;u++) acc += AGS[u]*(float)w[(size_t)u*128];
        TSs[t] = siluf_(acc*n_ss);
    } else if (t < 192) {
        int k = t-128;
        const __bf16* w = sgT + (size_t)at*8192 + k;    // stride 64
        float acc = 0.0f;
        #pragma unroll 4
        for (int u=0;u<128;u++) acc += AGS[u]*(float)w[(size_t)u*64];
        SG[k] = sigmoidf_(acc*n_ss);
    } else {
        int k = t-192;
        const __bf16* w = vvT + (size_t)at*4096 + k;    // stride 64
        float a0=0,a1=0,a2=0;
        #pragma unroll 4
        for (int u=0;u<64;u++){
            float wv = (float)w[(size_t)u*64];
            a0 += AGV[u*3+0]*wv;
            a1 += AGV[u*3+1]*wv;
            a2 += AGV[u*3+2]*wv;
        }
        TV[k*3+0]=a0*n_vv; TV[k*3+1]=a1*n_vv; TV[k*3+2]=a2*n_vv;
    }
    __syncthreads();
    const float alpha = sigmoidf_(res_param[0]);
    const float beta  = 1.0f - alpha;
    if (t < 128) {
        float acc = 0.0f;
        for (int k=0;k<128;k++) acc += TSs[k]*ohl_ws[(size_t)k*128 + t];
        float val = acc*0.0883883476483f + ohl_bs[t];
        out[(size_t)n*320 + t] = alpha*nf[(size_t)n*320 + t] + beta*val;
    } else if (t >= 192) {
        int k = t-192;
        float a0=0,a1=0,a2=0;
        for (int u=0;u<64;u++){
            float w = ohl_wv[(size_t)u*64 + k]*SG[u];
            a0 += TV[u*3+0]*w; a1 += TV[u*3+1]*w; a2 += TV[u*3+2]*w;
        }
        size_t base = (size_t)n*320 + 128 + (size_t)k*3;
        out[base+0] = alpha*nf[base+0] + beta*(a0*0.125f);
        out[base+1] = alpha*nf[base+1] + beta*(a1*0.125f);
        out[base+2] = alpha*nf[base+2] + beta*(a2*0.125f);
    }
}

extern "C" void kernel_launch(void* const* d_in, const int* in_sizes, int n_in,
                              void* d_out, int out_size, void* d_ws, size_t ws_size,
                              hipStream_t stream)
{
    const float* latents       = (const float*)d_in[0];
    const float* node_features = (const float*)d_in[1];
    const float* edge_features = (const float*)d_in[2];
    const int*   atom_type     = (const int*)d_in[3];
    const int*   edge_index    = (const int*)d_in[5];
    const float* edge_vector   = (const float*)d_in[6];
    const int*   active_edges  = (const int*)d_in[7];
    const float* sln_n_ws = (const float*)d_in[8];
    const float* sln_n_bs = (const float*)d_in[9];
    const float* sln_n_wv = (const float*)d_in[10];
    const float* sln_e_ws = (const float*)d_in[11];
    const float* sln_e_bs = (const float*)d_in[12];
    const float* sln_e_wv = (const float*)d_in[13];
    const float* so2_w0   = (const float*)d_in[14];
    const float* so2_w1r  = (const float*)d_in[15];
    const float* so2_w1i  = (const float*)d_in[16];
    const float* env_w    = (const float*)d_in[17];
    const float* lp_ws    = (const float*)d_in[18];
    const float* lp_bs    = (const float*)d_in[19];
    const float* lp_wv    = (const float*)d_in[20];
    const float* oh_w_ss  = (const float*)d_in[21];
    const float* oh_w_sg  = (const float*)d_in[22];
    const float* oh_w_vv  = (const float*)d_in[23];
    const float* ohl_ws   = (const float*)d_in[24];
    const float* ohl_bs   = (const float*)d_in[25];
    const float* ohl_wv   = (const float*)d_in[26];
    const float* res_param= (const float*)d_in[27];
    float* out = (float*)d_out;

    const int N  = in_sizes[1] / 320;
    const int EF = in_sizes[5] / 2;
    const int EA = in_sizes[7];

    // workspace layout (256B-aligned chunks)
    char* p = (char*)d_ws;
    auto alloc = [&](size_t bytes) -> char* {
        char* r = p; p += (bytes + 255) & ~(size_t)255; return r;
    };
    float* ns      = (float*)alloc((size_t)N*128*4);
    float* nv      = (float*)alloc((size_t)N*192*4);
    int*   cnt     = (int*)  alloc((size_t)N*4);
    int*   offs    = (int*)  alloc(((size_t)N+1)*4);
    int*   cursor  = (int*)  alloc((size_t)N*4);
    int*   elist   = (int*)  alloc((size_t)EA*4);
    __bf16* Wt     = (__bf16*)alloc((size_t)576*256*2);
    __bf16* w1rt   = (__bf16*)alloc((size_t)64*192*2);
    __bf16* w1it   = (__bf16*)alloc((size_t)64*192*2);
    __bf16* Wfm    = (__bf16*)alloc((size_t)576*256*2);
    __bf16* Bvfm   = (__bf16*)alloc((size_t)128*384*2);
    __bf16* envfm  = (__bf16*)alloc((size_t)192*128*2);
    __bf16* lpsfm  = (__bf16*)alloc((size_t)128*128*2);
    __bf16* lpvfm  = (__bf16*)alloc((size_t)64*64*2);
    __bf16* ssT    = (__bf16*)alloc((size_t)64*128*128*2);
    __bf16* sgT    = (__bf16*)alloc((size_t)64*128*64*2);
    __bf16* vvT    = (__bf16*)alloc((size_t)64*64*64*2);
    unsigned short* eout = (unsigned short*)alloc((size_t)EA*320*2);
    float*  Rg    = (float*) alloc((size_t)EA*12*4);
    __bf16* m0in  = (__bf16*)alloc((size_t)EA*576*2);
    __bf16* vfg   = (__bf16*)alloc((size_t)EA*384*2);
    size_t split_need = (size_t)(p - (char*)d_ws);
    const bool use_split = (split_need <= ws_size);

    // aliases (split path only; all uses are stream-ordered)
    unsigned short* vpvm  = eout;                                  // [EA][128], dead before eout written
    unsigned short* m0out = (unsigned short*)vfg;                  // [EA][256], written after vfg consumed
    unsigned short* As    = (unsigned short*)m0in;                 // [EA][128], after m0in consumed
    unsigned short* MVp   = As + (size_t)EA*128;                   // 3 planes [EA][64]
    unsigned short* w_env = MVp + (size_t)EA*192;                  // [EA][192]; 128+192+192=512 <= 576 ok

    hipMemsetAsync(cnt, 0, (size_t)N*sizeof(int), stream);
    prep_weights<<<576, 256, 0, stream>>>(so2_w0, so2_w1r, so2_w1i, env_w, lp_ws, lp_wv,
                                          Wt, w1rt, w1it, Wfm, Bvfm, envfm, lpsfm, lpvfm);
    prep_oh<<<4096, 256, 0, stream>>>(oh_w_ss, oh_w_sg, oh_w_vv, ssT, sgT, vvT);
    node_ln_kernel<<<(N+3)/4, 256, 0, stream>>>(node_features, sln_n_ws, sln_n_bs, sln_n_wv, ns, nv, N);
    csr_count<<<(EA+255)/256, 256, 0, stream>>>(edge_index, active_edges, cnt, EA);
    csr_scan<<<1, 256, 0, stream>>>(cnt, offs, cursor, N);
    csr_fill<<<(EA+255)/256, 256, 0, stream>>>(edge_index, active_edges, cursor, elist, EA);

    const float rn0    = 0.0416666666667f;   // 1/sqrt(576)
    const float n1     = 0.0721687836487f;   // 1/sqrt(192)
    const float inv128 = 0.0883883476483f;   // 1/sqrt(128)

    if (use_split){
        const int NB64  = (EA + 63) / 64;
        const int NB128 = (EA + 127) / 128;
        stage_kernel<<<(EA+15)/16, 256, 0, stream>>>(edge_features, edge_index, edge_vector, active_edges,
            sln_e_ws, sln_e_bs, sln_e_wv, ns, nv, m0in, vfg, Rg, EA, EF);
        gemm_k<128,384,2,EPI_PLAIN,false><<<dim3(NB128,1), 256, 0, stream>>>(
            vfg, nullptr, nullptr, Bvfm, vpvm, nullptr, nullptr, n1, EA);
        gemm_k<256,576,1,EPI_PLAIN,false><<<dim3(NB64,1), 256, 0, stream>>>(
            m0in, nullptr, nullptr, Wfm, m0out, nullptr, nullptr, rn0, EA);
        mid_kernel<<<(EA*64+255)/256, 256, 0, stream>>>(m0out, vpvm, Rg, As, MVp, EA);
        gemm_k<192,128,1,EPI_PLAIN,true><<<dim3(NB64,1), 192, 0, stream>>>(
            nullptr, latents, active_edges, envfm, w_env, nullptr, nullptr, inv128, EA);
        gemm_k<128,128,2,EPI_LPS,false><<<dim3(NB128,1), 256, 0, stream>>>(
            (const __bf16*)As, nullptr, nullptr, lpsfm, eout, w_env, lp_bs, inv128, EA);
        gemm_k<64,64,2,EPI_LPV,false><<<dim3(NB128,3), 128, 0, stream>>>(
            (const __bf16*)MVp, nullptr, nullptr, lpvfm, eout, w_env, nullptr, 0.125f, EA);
    } else {
        edge_kernel_fused<<<(EA+15)/16, 256, 0, stream>>>(latents, edge_features, edge_index, edge_vector, active_edges,
            sln_e_ws, sln_e_bs, sln_e_wv, Wt, w1rt, w1it, env_w, lp_ws, lp_bs, lp_wv,
            ns, nv, eout, EA, EF);
    }
    node_out_kernel<<<N, 256, 0, stream>>>(node_features, atom_type, offs, elist, eout,
        ssT, sgT, vvT, ohl_ws, ohl_bs, ohl_wv, res_param, out, N);
}

// Round 8
// 513.531 us; speedup vs baseline: 1.0205x; 1.0205x over previous
//
#include <hip/hip_runtime.h>

#define EPS_LN 1e-8f

typedef __bf16 bf16x8 __attribute__((ext_vector_type(8)));
typedef float  f32x4  __attribute__((ext_vector_type(4)));

__device__ __forceinline__ float sigmoidf_(float x){ return 1.0f/(1.0f+__expf(-x)); }
__device__ __forceinline__ float siluf_(float x){ return x*sigmoidf_(x); }
__device__ __forceinline__ unsigned short f2bf(float x){ union{ __bf16 b; unsigned short u;} c; c.b = (__bf16)x; return c.u; }
__device__ __forceinline__ float bf2f(unsigned short u){ return __uint_as_float(((unsigned)u)<<16); }

union F4 { float4 v; float f[4]; };

// swizzled bf16 LDS store (fused fallback path)
__device__ __forceinline__ void st_bf4(char* base, int row, int stride_bytes, int k,
                                       float x0, float x1, float x2, float x3){
    union { __bf16 h[4]; unsigned long long u; } p;
    p.h[0]=(__bf16)x0; p.h[1]=(__bf16)x1; p.h[2]=(__bf16)x2; p.h[3]=(__bf16)x3;
    *(unsigned long long*)(base + row*stride_bytes + ((2*k) ^ ((row&7)<<4))) = p.u;
}
__device__ __forceinline__ bf16x8 ld_frag(const char* base, int row, int stride_bytes, int kbyte){
    return *(const bf16x8*)(base + row*stride_bytes + (kbyte ^ ((row&7)<<4)));
}
__device__ __forceinline__ void st_g4(__bf16* p, float x0, float x1, float x2, float x3){
    union { __bf16 h[4]; unsigned long long u; } pk;
    pk.h[0]=(__bf16)x0; pk.h[1]=(__bf16)x1; pk.h[2]=(__bf16)x2; pk.h[3]=(__bf16)x3;
    *(unsigned long long*)p = pk.u;
}
__device__ __forceinline__ uint4 pack8(float4 a, float4 b){
    union { __bf16 h[8]; uint4 u; } p;
    p.h[0]=(__bf16)a.x; p.h[1]=(__bf16)a.y; p.h[2]=(__bf16)a.z; p.h[3]=(__bf16)a.w;
    p.h[4]=(__bf16)b.x; p.h[5]=(__bf16)b.y; p.h[6]=(__bf16)b.z; p.h[7]=(__bf16)b.w;
    return p.u;
}
// fragment-major dest index for B[n][k] tiles (16 cols x 32 k per fragment)
__device__ __forceinline__ int fm_idx(int n, int k, int NKT){
    return ((n>>4)*NKT + (k>>5))*512 + ((k>>3)&3)*128 + (n&15)*8 + (k&7);
}

// ---------------- weight prep (all packs in one kernel) ----------------
__global__ void prep_all(const float* __restrict__ w0,
                         const float* __restrict__ w1r, const float* __restrict__ w1i,
                         const float* __restrict__ env_w, const float* __restrict__ lp_ws,
                         const float* __restrict__ lp_wv,
                         const float* __restrict__ oh_ss, const float* __restrict__ oh_sg,
                         const float* __restrict__ oh_vv,
                         __bf16* __restrict__ Wt, __bf16* __restrict__ w1rt, __bf16* __restrict__ w1it,
                         __bf16* __restrict__ Wevfm, __bf16* __restrict__ Bnodefm,
                         __bf16* __restrict__ Bvfm,
                         __bf16* __restrict__ envfm, __bf16* __restrict__ lpsfm,
                         __bf16* __restrict__ lpvfm,
                         __bf16* __restrict__ ssT, __bf16* __restrict__ sgT, __bf16* __restrict__ vvT)
{
    int t = blockIdx.x*256 + threadIdx.x;
    if (t < 576*256){                          // fallback row-major Wt[256][576]
        int n = t/576, k = t%576;
        Wt[t] = (__bf16)w0[(size_t)k*256 + n];
    }
    if (t < 256*320){                          // edge GEMM weights: rows {128..255}U{384..575}
        int n = t/320, k = t%320;
        int src = (k<128) ? (128+k) : (384+(k-128));
        Wevfm[fm_idx(n,k,10)] = (__bf16)w0[(size_t)src*256 + n];
    }
    if (t < 512*128){                          // node GEMM: cols 0..255 = W rows 0..127; 256..511 = rows 256..383
        int n = t/128, k = t%128;
        float v = (n<256) ? w0[(size_t)k*256 + n] : w0[(size_t)(256+k)*256 + (n-256)];
        Bnodefm[fm_idx(n,k,4)] = (__bf16)v;
    }
    if (t < 64*192){
        int c = t/192, k = t%192;
        w1rt[t] = (__bf16)w1r[(size_t)k*64 + c];
        w1it[t] = (__bf16)w1i[(size_t)k*64 + c];
    }
    if (t < 128*384){
        int n = t/384, k = t%384;
        float v;
        if (n < 64) v = (k<192) ? w1r[(size_t)k*64+n] : -w1i[(size_t)(k-192)*64+n];
        else        v = (k<192) ? w1i[(size_t)k*64+(n-64)] : w1r[(size_t)(k-192)*64+(n-64)];
        Bvfm[fm_idx(n,k,12)] = (__bf16)v;
    }
    if (t < 192*128){ int n=t/128, k=t%128; envfm[fm_idx(n,k,4)] = (__bf16)env_w[(size_t)k*192+n]; }
    if (t < 128*128){ int n=t/128, k=t%128; lpsfm[fm_idx(n,k,4)] = (__bf16)lp_ws[(size_t)k*128+n]; }
    if (t < 64*64)  { int n=t/64,  k=t%64;  lpvfm[fm_idx(n,k,2)] = (__bf16)lp_wv[(size_t)k*64+n]; }
    if (t < 64*128*128){                       // ssT[at][u][k]
        int at = t / 16384; int r = t & 16383; int u = r >> 7, k = r & 127;
        ssT[t] = (__bf16)oh_ss[((size_t)u*64 + at)*128 + k];
    }
    if (t < 64*128*64){                        // sgT[at][u][k]
        int at = t / 8192; int r = t & 8191; int u = r >> 6, k = r & 63;
        sgT[t] = (__bf16)oh_sg[((size_t)u*64 + at)*64 + k];
    }
    if (t < 64*64*64){                         // vvT[at][u][k]
        int at = t / 4096; int r = t & 4095; int u = r >> 6, k = r & 63;
        vvT[t] = (__bf16)oh_vv[((size_t)u*64 + at)*64 + k];
    }
}

// ---------------- CSR build ----------------
__global__ void csr_count(const int* __restrict__ ei, const int* __restrict__ act,
                          int* __restrict__ cnt, int EA)
{
    int e = blockIdx.x*256 + threadIdx.x;
    if (e < EA) atomicAdd(&cnt[ei[act[e]]], 1);
}
__global__ void csr_scan(const int* __restrict__ cnt, int* __restrict__ offs,
                         int* __restrict__ cursor, int N)
{
    __shared__ int part[256];
    int t = threadIdx.x;
    int chunk = (N + 255) / 256;
    int lo = t*chunk, hi = lo+chunk; if (hi > N) hi = N; if (lo > N) lo = N;
    int s = 0;
    for (int i=lo;i<hi;i++) s += cnt[i];
    part[t] = s;
    __syncthreads();
    for (int d=1; d<256; d<<=1){
        int v = (t>=d) ? part[t-d] : 0;
        __syncthreads();
        part[t] += v;
        __syncthreads();
    }
    int run = (t==0) ? 0 : part[t-1];
    for (int i=lo;i<hi;i++){
        offs[i] = run; cursor[i] = run;
        run += cnt[i];
    }
    if (t==255) offs[N] = part[255];
}
__global__ void csr_fill(const int* __restrict__ ei, const int* __restrict__ act,
                         int* __restrict__ cursor, int* __restrict__ elist, int EA)
{
    int e = blockIdx.x*256 + threadIdx.x;
    if (e < EA){
        int n = ei[act[e]];
        int p = atomicAdd(&cursor[n], 1);
        elist[p] = e;
    }
}

// ---------------- node separable layernorm (+ bf16 scalar copy for node GEMM) ----------------
__global__ void node_ln_kernel(const float* __restrict__ nf,
                               const float* __restrict__ ws, const float* __restrict__ bs,
                               const float* __restrict__ wv,
                               float* __restrict__ ns, float* __restrict__ nv,
                               __bf16* __restrict__ nsb, int N)
{
    int t = threadIdx.x;
    int lane = t & 63;
    int n = blockIdx.x*4 + (t>>6);
    if (n >= N) return;
    const float* row = nf + (size_t)n*320;
    float s0 = row[lane], s1 = row[64+lane];
    float sum = s0+s1, sq = s0*s0+s1*s1;
    #pragma unroll
    for (int m=1;m<64;m<<=1){ sum += __shfl_xor(sum,m,64); sq += __shfl_xor(sq,m,64); }
    float mu = sum*(1.0f/128.0f);
    float rs = rsqrtf(sq*(1.0f/128.0f) - mu*mu + EPS_LN);
    float o0 = (s0-mu)*rs*ws[lane]    + bs[lane];
    float o1 = (s1-mu)*rs*ws[64+lane] + bs[64+lane];
    ns[(size_t)n*128+lane]    = o0;
    ns[(size_t)n*128+64+lane] = o1;
    nsb[(size_t)n*128+lane]    = (__bf16)o0;
    nsb[(size_t)n*128+64+lane] = (__bf16)o1;
    float v0 = row[128+lane], v1 = row[192+lane], v2 = row[256+lane];
    float vs = v0*v0+v1*v1+v2*v2;
    #pragma unroll
    for (int m=1;m<64;m<<=1) vs += __shfl_xor(vs,m,64);
    float rv = rsqrtf(vs*(1.0f/192.0f) + EPS_LN);
    nv[(size_t)n*192+lane]     = v0*rv*wv[lane/3];
    nv[(size_t)n*192+64+lane]  = v1*rv*wv[(64+lane)/3];
    nv[(size_t)n*192+128+lane] = v2*rv*wv[(128+lane)/3];
}

// ---------------- per-edge staging -> global bf16 (no node-scalar copies) ----------------
__global__ void stage_kernel(
    const float* __restrict__ ef_all,
    const int*   __restrict__ edge_index,
    const float* __restrict__ edge_vector,
    const int*   __restrict__ active_edges,
    const float* __restrict__ e_ws, const float* __restrict__ e_bs, const float* __restrict__ e_wv,
    const float* __restrict__ nv,
    __bf16* __restrict__ m0in,   // [EA][320]: [es(128) | vf0(192)]
    __bf16* __restrict__ vfg,    // [EA][384]: [vf1(192) | vf2(192)]
    float* __restrict__ Rg, int2* __restrict__ ctnb,
    int EA, int EF)
{
    int tid = blockIdx.x*256 + threadIdx.x;
    int e = tid >> 4, l = tid & 15;
    if (e >= EA) return;
    int ae = active_edges[e];
    int ct = edge_index[ae];
    int nb = edge_index[EF + ae];
    float ex = edge_vector[(size_t)ae*3+0];
    float ey = edge_vector[(size_t)ae*3+1];
    float ez = edge_vector[(size_t)ae*3+2];
    float rn = rsqrtf(ex*ex+ey*ey+ez*ez + EPS_LN);
    float ax = ex*rn, ay = ey*rn, az = ez*rn;
    float rx, ry;
    if (fabsf(ax) < 0.9f) { rx = 1.0f; ry = 0.0f; } else { rx = 0.0f; ry = 1.0f; }
    float bx = -az*ry, by = az*rx, bz = ax*ry - ay*rx;
    float bn = rsqrtf(bx*bx+by*by+bz*bz + EPS_LN);
    bx*=bn; by*=bn; bz*=bn;
    float cx = ay*bz - az*by;
    float cy = az*bx - ax*bz;
    float cz = ax*by - ay*bx;
    if (l == 0){
        float* Rr = Rg + (size_t)e*12;
        *(float4*)(Rr)   = make_float4(ax,ay,az,bx);
        *(float4*)(Rr+4) = make_float4(by,bz,cx,cy);
        *(float4*)(Rr+8) = make_float4(cz,0.f,0.f,0.f);
        ctnb[e] = make_int2(ct, nb);
    }
    __bf16* Arow = m0in + (size_t)e*320;
    __bf16* V1r  = vfg + (size_t)e*384;
    __bf16* V2r  = V1r + 192;
    const float* ef = ef_all + (size_t)e*320;
    {   // edge scalar LN -> Arow[0:128)
        F4 sa, sb;
        sa.v = *(const float4*)(ef + l*4);
        sb.v = *(const float4*)(ef + 64 + l*4);
        float sum=0.f, sq=0.f;
        #pragma unroll
        for (int i=0;i<4;i++){ sum += sa.f[i]+sb.f[i]; sq += sa.f[i]*sa.f[i]+sb.f[i]*sb.f[i]; }
        #pragma unroll
        for (int m=1;m<16;m<<=1){ sum += __shfl_xor(sum,m,64); sq += __shfl_xor(sq,m,64); }
        float mu = sum*(1.0f/128.0f);
        float rs = rsqrtf(sq*(1.0f/128.0f)-mu*mu + EPS_LN);
        float o0[4], o1[4];
        #pragma unroll
        for (int i=0;i<4;i++){
            int c0 = l*4+i, c1 = 64+l*4+i;
            o0[i] = (sa.f[i]-mu)*rs*e_ws[c0]+e_bs[c0];
            o1[i] = (sb.f[i]-mu)*rs*e_ws[c1]+e_bs[c1];
        }
        st_g4(Arow + l*4,      o0[0],o0[1],o0[2],o0[3]);
        st_g4(Arow + 64 + l*4, o1[0],o1[1],o1[2],o1[3]);
    }
    {   // edge vector LN + rotate (u 64..127)
        F4 va, vb, vc;
        va.v = *(const float4*)(ef + 128 + l*12);
        vb.v = *(const float4*)(ef + 128 + l*12 + 4);
        vc.v = *(const float4*)(ef + 128 + l*12 + 8);
        float vv[12];
        #pragma unroll
        for (int i=0;i<4;i++){ vv[i]=va.f[i]; vv[4+i]=vb.f[i]; vv[8+i]=vc.f[i]; }
        float sq=0.f;
        #pragma unroll
        for (int i=0;i<12;i++) sq += vv[i]*vv[i];
        #pragma unroll
        for (int m=1;m<16;m<<=1) sq += __shfl_xor(sq,m,64);
        float rv = rsqrtf(sq*(1.0f/192.0f) + EPS_LN);
        float f0[4], f1[4], f2[4];
        #pragma unroll
        for (int j=0;j<4;j++){
            int u = 4*l + j;
            float sc = rv * e_wv[u];
            float x = vv[3*j]*sc, y = vv[3*j+1]*sc, z = vv[3*j+2]*sc;
            f0[j] = ax*x+ay*y+az*z;
            f1[j] = bx*x+by*y+bz*z;
            f2[j] = cx*x+cy*y+cz*z;
        }
        st_g4(Arow + 128 + 64 + 4*l, f0[0],f0[1],f0[2],f0[3]);
        st_g4(V1r + 64 + 4*l, f1[0],f1[1],f1[2],f1[3]);
        st_g4(V2r + 64 + 4*l, f2[0],f2[1],f2[2],f2[3]);
    }
    {   // nv[ctr] (u 0..63)
        const float* pv = nv + (size_t)ct*192 + l*12;
        F4 va, vb, vc;
        va.v = *(const float4*)(pv);
        vb.v = *(const float4*)(pv+4);
        vc.v = *(const float4*)(pv+8);
        float vv[12];
        #pragma unroll
        for (int i=0;i<4;i++){ vv[i]=va.f[i]; vv[4+i]=vb.f[i]; vv[8+i]=vc.f[i]; }
        float f0[4], f1[4], f2[4];
        #pragma unroll
        for (int j=0;j<4;j++){
            float x = vv[3*j], y = vv[3*j+1], z = vv[3*j+2];
            f0[j] = ax*x+ay*y+az*z;
            f1[j] = bx*x+by*y+bz*z;
            f2[j] = cx*x+cy*y+cz*z;
        }
        st_g4(Arow + 128 + 4*l, f0[0],f0[1],f0[2],f0[3]);
        st_g4(V1r + 4*l, f1[0],f1[1],f1[2],f1[3]);
        st_g4(V2r + 4*l, f2[0],f2[1],f2[2],f2[3]);
    }
    {   // nv[nbr] (u 128..191)
        const float* pv = nv + (size_t)nb*192 + l*12;
        F4 va, vb, vc;
        va.v = *(const float4*)(pv);
        vb.v = *(const float4*)(pv+4);
        vc.v = *(const float4*)(pv+8);
        float vv[12];
        #pragma unroll
        for (int i=0;i<4;i++){ vv[i]=va.f[i]; vv[4+i]=vb.f[i]; vv[8+i]=vc.f[i]; }
        float f0[4], f1[4], f2[4];
        #pragma unroll
        for (int j=0;j<4;j++){
            float x = vv[3*j], y = vv[3*j+1], z = vv[3*j+2];
            f0[j] = ax*x+ay*y+az*z;
            f1[j] = bx*x+by*y+bz*z;
            f2[j] = cx*x+cy*y+cz*z;
        }
        st_g4(Arow + 128 + 128 + 4*l, f0[0],f0[1],f0[2],f0[3]);
        st_g4(V1r + 128 + 4*l, f1[0],f1[1],f1[2],f1[3]);
        st_g4(V2r + 128 + 4*l, f2[0],f2[1],f2[2],f2[3]);
    }
}

// ---------------- tiled MFMA GEMM, fragment-major B direct from global (L2-resident) ----
enum { EPI_PLAIN=0, EPI_LPS=1, EPI_LPV=2, EPI_MAINADD=3 };

template<int N, int K, int RT, int EPI, bool AGATHER>
__global__ __launch_bounds__((N/64)*RT*64)
void gemm_k(const __bf16* __restrict__ Ag, const float* __restrict__ Agf,
            const int* __restrict__ aidx,
            const __bf16* __restrict__ Bfm,
            unsigned short* __restrict__ outp,
            const unsigned short* __restrict__ wenv,
            const float* __restrict__ bias,
            const int2* __restrict__ ctnb, const __bf16* __restrict__ nodeCN,
            float scale, int M)
{
    constexpr int NT  = N/64;
    constexpr int BM  = RT*64;
    constexpr int T   = NT*RT*64;
    constexpr int NKT = K/32;
    constexpr int NK  = K/64;
    constexpr int CA  = (BM*8 + T - 1)/T;
    __shared__ __align__(16) char lA[2][BM*128];

    const int tid  = threadIdx.x;
    const int brow = blockIdx.x*BM;
    const int mpl  = blockIdx.y;
    const __bf16* A = AGATHER ? nullptr : (Ag + (size_t)mpl*M*K);

    uint4 ra[CA];
    auto loadA = [&](int ks){
        #pragma unroll
        for (int i=0;i<CA;i++){
            int c = tid + i*T;
            if (c < BM*8){
                int r = c>>3;
                int gr = brow + r; if (gr >= M) gr = M-1;
                if constexpr (AGATHER){
                    int ae = aidx[gr];
                    const float* base = Agf + (size_t)ae*K + ks*64 + (c&7)*8;
                    float4 f0 = *(const float4*)(base);
                    float4 f1 = *(const float4*)(base+4);
                    ra[i] = pack8(f0, f1);
                } else {
                    ra[i] = *(const uint4*)((const char*)(A + (size_t)gr*K + ks*64) + (c&7)*16);
                }
            }
        }
    };
    auto storeA = [&](int buf){
        #pragma unroll
        for (int i=0;i<CA;i++){
            int c = tid + i*T;
            if (c < BM*8){
                int r = c>>3, off = (c&7)*16;
                *(uint4*)(&lA[buf][r*128 + (off ^ ((r&7)<<4))]) = ra[i];
            }
        }
    };

    const int wid = tid>>6, ln = tid&63;
    const int cc = ln & 15, gq = ln >> 4;
    const int wn = wid % NT, wm = wid / NT;
    const __bf16* bbase = Bfm + ((size_t)wn*4*NKT)*512 + (size_t)ln*8;

    f32x4 acc[4][4];
    #pragma unroll
    for (int i=0;i<4;i++)
        #pragma unroll
        for (int j=0;j<4;j++) acc[i][j] = (f32x4){0,0,0,0};

    loadA(0); storeA(0);
    int cur = 0;
    for (int ks=0; ks<NK; ks++){
        __syncthreads();
        if (ks+1 < NK) loadA(ks+1);
        #pragma unroll
        for (int kt2=0;kt2<2;kt2++){
            const int kt = ks*2 + kt2;
            const int kb = kt2*64 + 16*gq;
            bf16x8 af[4];
            #pragma unroll
            for (int mf=0;mf<4;mf++){
                int r = wm*64 + mf*16 + cc;
                af[mf] = *(const bf16x8*)(&lA[cur][r*128 + (kb ^ ((r&7)<<4))]);
            }
            #pragma unroll
            for (int nf=0;nf<4;nf++){
                bf16x8 bfr = *(const bf16x8*)(bbase + ((size_t)nf*NKT + kt)*512);
                #pragma unroll
                for (int mf=0;mf<4;mf++)
                    acc[mf][nf] = __builtin_amdgcn_mfma_f32_16x16x32_bf16(af[mf], bfr, acc[mf][nf], 0,0,0);
            }
        }
        if (ks+1 < NK) storeA(cur^1);
        cur ^= 1;
    }

    const float inv_avg_ = 0.288675134595f;
    #pragma unroll
    for (int mf=0;mf<4;mf++){
        #pragma unroll
        for (int nf=0;nf<4;nf++){
            #pragma unroll
            for (int j=0;j<4;j++){
                int gr = brow + wm*64 + mf*16 + gq*4 + j;
                if (gr >= M) continue;
                int col = wn*64 + nf*16 + cc;
                float v = acc[mf][nf][j];
                if constexpr (EPI == EPI_PLAIN){
                    outp[(size_t)gr*N + col] = f2bf(v*scale);
                } else if constexpr (EPI == EPI_MAINADD){
                    int2 cn = ctnb[gr];
                    float add = (float)nodeCN[(size_t)cn.x*512 + col]
                              + (float)nodeCN[(size_t)cn.y*512 + 256 + col];
                    outp[(size_t)gr*N + col] = f2bf((v + add)*scale);
                } else if constexpr (EPI == EPI_LPS){
                    float val = (v*scale + bias[col]) * bf2f(wenv[(size_t)gr*192 + col]) * inv_avg_;
                    outp[(size_t)gr*320 + col] = f2bf(val);
                } else {
                    float val = v*0.125f * bf2f(wenv[(size_t)gr*192 + 128 + col]) * inv_avg_;
                    outp[(size_t)gr*320 + 128 + mpl*64 + col] = f2bf(val);
                }
            }
        }
    }
}

// ---------------- mid: gate + rotate-back + silu (elementwise) ----------------
__global__ void mid_kernel(const unsigned short* __restrict__ m0out,
                           const unsigned short* __restrict__ vpvm,
                           const float* __restrict__ Rg,
                           unsigned short* __restrict__ As,
                           unsigned short* __restrict__ MVp, int EA)
{
    int tid = blockIdx.x*256 + threadIdx.x;
    int e = tid>>6, u = tid&63;
    if (e >= EA) return;
    float rl = (u < 12) ? Rg[(size_t)e*12 + u] : 0.f;
    float R0=__shfl(rl,0,64), R1=__shfl(rl,1,64), R2=__shfl(rl,2,64);
    float R3=__shfl(rl,3,64), R4=__shfl(rl,4,64), R5=__shfl(rl,5,64);
    float R6=__shfl(rl,6,64), R7=__shfl(rl,7,64), R8=__shfl(rl,8,64);
    const unsigned short* mo = m0out + (size_t)e*256;
    float s0 = bf2f(mo[192 + u]);
    float gt = sigmoidf_(bf2f(mo[128 + u]));
    float p  = bf2f(vpvm[(size_t)e*128 + u]);
    float q  = bf2f(vpvm[(size_t)e*128 + 64 + u]);
    size_t eu = (size_t)e*64 + u;
    size_t P  = (size_t)EA*64;
    MVp[eu]       = f2bf(gt*(R0*s0 + R3*p + R6*q));
    MVp[P + eu]   = f2bf(gt*(R1*s0 + R4*p + R7*q));
    MVp[2*P + eu] = f2bf(gt*(R2*s0 + R5*p + R8*q));
    As[(size_t)e*128 + u]      = f2bf(siluf_(bf2f(mo[u])));
    As[(size_t)e*128 + 64 + u] = f2bf(siluf_(bf2f(mo[64 + u])));
}

// ---------------- fallback: fused edge kernel (round-3, plane-layout stores) ----------------
__launch_bounds__(256, 3)
__global__ void edge_kernel_fused(
    const float* __restrict__ latents,
    const float* __restrict__ ef_all,
    const int*   __restrict__ edge_index,
    const float* __restrict__ edge_vector,
    const int*   __restrict__ active_edges,
    const float* __restrict__ e_ws, const float* __restrict__ e_bs, const float* __restrict__ e_wv,
    const __bf16* __restrict__ Wt,
    const __bf16* __restrict__ w1rt,
    const __bf16* __restrict__ w1it,
    const float* __restrict__ env_w,
    const float* __restrict__ lp_ws, const float* __restrict__ lp_bs, const float* __restrict__ lp_wv,
    const float* __restrict__ ns, const float* __restrict__ nv,
    unsigned short* __restrict__ eout,
    int EA, int EF)
{
    __shared__ __align__(16) char smem[46592];
    char* sAbC = smem;
    char* sVFC = smem + 18432;
    float* sO  = (float*)smem;
    float* MV  = (float*)(smem + 16640);
    float* WE  = (float*)(smem + 33280);
    float* sR  = (float*)(smem + 45824);

    const int t = threadIdx.x;
    const int g = t >> 4, l = t & 15;
    const int e = blockIdx.x*16 + g;
    const bool act = (e < EA);

    int ct = 0, ae = 0;

    if (act) {
        ae = active_edges[e];
        ct = edge_index[ae];
        int nb = edge_index[EF + ae];
        float ex = edge_vector[(size_t)ae*3+0];
        float ey = edge_vector[(size_t)ae*3+1];
        float ez = edge_vector[(size_t)ae*3+2];
        float rn = rsqrtf(ex*ex+ey*ey+ez*ez + EPS_LN);
        float ax = ex*rn, ay = ey*rn, az = ez*rn;
        float rx, ry;
        if (fabsf(ax) < 0.9f) { rx = 1.0f; ry = 0.0f; } else { rx = 0.0f; ry = 1.0f; }
        float bx = -az*ry, by = az*rx, bz = ax*ry - ay*rx;
        float bn = rsqrtf(bx*bx+by*by+bz*bz + EPS_LN);
        bx*=bn; by*=bn; bz*=bn;
        float cx = ay*bz - az*by;
        float cy = az*bx - ax*bz;
        float cz = ax*by - ay*bx;
        if (l == 0){
            float* Rr = &sR[g*12];
            Rr[0]=ax; Rr[1]=ay; Rr[2]=az;
            Rr[3]=bx; Rr[4]=by; Rr[5]=bz;
            Rr[6]=cx; Rr[7]=cy; Rr[8]=cz;
        }
        {
            const float4* pc4 = (const float4*)(ns + (size_t)ct*128);
            const float4* pn4 = (const float4*)(ns + (size_t)nb*128);
            F4 a,b2,c,d;
            a.v = pc4[l]; b2.v = pc4[16+l]; c.v = pn4[l]; d.v = pn4[16+l];
            st_bf4(sAbC, g, 1152, l*4,       a.f[0],a.f[1],a.f[2],a.f[3]);
            st_bf4(sAbC, g, 1152, 64+l*4,    b2.f[0],b2.f[1],b2.f[2],b2.f[3]);
            st_bf4(sAbC, g, 1152, 256+l*4,   c.f[0],c.f[1],c.f[2],c.f[3]);
            st_bf4(sAbC, g, 1152, 320+l*4,   d.f[0],d.f[1],d.f[2],d.f[3]);
        }
        const float* ef = ef_all + (size_t)e*320;
        {
            F4 sa, sb;
            sa.v = *(const float4*)(ef + l*4);
            sb.v = *(const float4*)(ef + 64 + l*4);
            float sum=0.f, sq=0.f;
            #pragma unroll
            for (int i=0;i<4;i++){ sum += sa.f[i]+sb.f[i]; sq += sa.f[i]*sa.f[i]+sb.f[i]*sb.f[i]; }
            #pragma unroll
            for (int m=1;m<16;m<<=1){ sum += __shfl_xor(sum,m,64); sq += __shfl_xor(sq,m,64); }
            float mu = sum*(1.0f/128.0f);
            float rs = rsqrtf(sq*(1.0f/128.0f)-mu*mu + EPS_LN);
            float o0[4], o1[4];
            #pragma unroll
            for (int i=0;i<4;i++){
                int c0 = l*4+i, c1 = 64+l*4+i;
                o0[i] = (sa.f[i]-mu)*rs*e_ws[c0]+e_bs[c0];
                o1[i] = (sb.f[i]-mu)*rs*e_ws[c1]+e_bs[c1];
            }
            st_bf4(sAbC, g, 1152, 128+l*4, o0[0],o0[1],o0[2],o0[3]);
            st_bf4(sAbC, g, 1152, 192+l*4, o1[0],o1[1],o1[2],o1[3]);
        }
        {
            F4 va, vb, vc;
            va.v = *(const float4*)(ef + 128 + l*12);
            vb.v = *(const float4*)(ef + 128 + l*12 + 4);
            vc.v = *(const float4*)(ef + 128 + l*12 + 8);
            float vv[12];
            #pragma unroll
            for (int i=0;i<4;i++){ vv[i]=va.f[i]; vv[4+i]=vb.f[i]; vv[8+i]=vc.f[i]; }
            float sq=0.f;
            #pragma unroll
            for (int i=0;i<12;i++) sq += vv[i]*vv[i];
            #pragma unroll
            for (int m=1;m<16;m<<=1) sq += __shfl_xor(sq,m,64);
            float rv = rsqrtf(sq*(1.0f/192.0f) + EPS_LN);
            float f0[4], f1[4], f2[4];
            #pragma unroll
            for (int j=0;j<4;j++){
                int u = 4*l + j;
                float sc = rv * e_wv[u];
                float x = vv[3*j]*sc, y = vv[3*j+1]*sc, z = vv[3*j+2]*sc;
                f0[j] = ax*x+ay*y+az*z;
                f1[j] = bx*x+by*y+bz*z;
                f2[j] = cx*x+cy*y+cz*z;
            }
            st_bf4(sAbC, g, 1152, 384+64+4*l, f0[0],f0[1],f0[2],f0[3]);
            st_bf4(sVFC, g, 384, 64+4*l, f1[0],f1[1],f1[2],f1[3]);
            st_bf4(sVFC+6144, g, 384, 64+4*l, f2[0],f2[1],f2[2],f2[3]);
        }
        {
            const float* pv = nv + (size_t)ct*192 + l*12;
            F4 va, vb, vc;
            va.v = *(const float4*)(pv);
            vb.v = *(const float4*)(pv+4);
            vc.v = *(const float4*)(pv+8);
            float vv[12];
            #pragma unroll
            for (int i=0;i<4;i++){ vv[i]=va.f[i]; vv[4+i]=vb.f[i]; vv[8+i]=vc.f[i]; }
            float f0[4], f1[4], f2[4];
            #pragma unroll
            for (int j=0;j<4;j++){
                float x = vv[3*j], y = vv[3*j+1], z = vv[3*j+2];
                f0[j] = ax*x+ay*y+az*z;
                f1[j] = bx*x+by*y+bz*z;
                f2[j] = cx*x+cy*y+cz*z;
            }
            st_bf4(sAbC, g, 1152, 384+4*l, f0[0],f0[1],f0[2],f0[3]);
            st_bf4(sVFC, g, 384, 4*l, f1[0],f1[1],f1[2],f1[3]);
            st_bf4(sVFC+6144, g, 384, 4*l, f2[0],f2[1],f2[2],f2[3]);
        }
        {
            const float* pv = nv + (size_t)nb*192 + l*12;
            F4 va, vb, vc;
            va.v = *(const float4*)(pv);
            vb.v = *(const float4*)(pv+4);
            vc.v = *(const float4*)(pv+8);
            float vv[12];
            #pragma unroll
            for (int i=0;i<4;i++){ vv[i]=va.f[i]; vv[4+i]=vb.f[i]; vv[8+i]=vc.f[i]; }
            float f0[4], f1[4], f2[4];
            #pragma unroll
            for (int j=0;j<4;j++){
                float x = vv[3*j], y = vv[3*j+1], z = vv[3*j+2];
                f0[j] = ax*x+ay*y+az*z;
                f1[j] = bx*x+by*y+bz*z;
                f2[j] = cx*x+cy*y+cz*z;
            }
            st_bf4(sAbC, g, 1152, 384+128+4*l, f0[0],f0[1],f0[2],f0[3]);
            st_bf4(sVFC, g, 384, 128+4*l, f1[0],f1[1],f1[2],f1[3]);
            st_bf4(sVFC+6144, g, 384, 128+4*l, f2[0],f2[1],f2[2],f2[3]);
        }
    }
    __syncthreads();

    const int w  = t >> 6;
    const int ln = t & 63;
    const int cc = ln & 15;
    const int gq = ln >> 4;

    f32x4 accM[4] = {{0,0,0,0},{0,0,0,0},{0,0,0,0},{0,0,0,0}};
    {
        const __bf16* wb0 = Wt + (size_t)(64*w + 0  + cc)*576;
        const __bf16* wb1 = Wt + (size_t)(64*w + 16 + cc)*576;
        const __bf16* wb2 = Wt + (size_t)(64*w + 32 + cc)*576;
        const __bf16* wb3 = Wt + (size_t)(64*w + 48 + cc)*576;
        for (int ks=0; ks<18; ks++){
            bf16x8 a = ld_frag(sAbC, cc, 1152, ks*64 + 16*gq);
            int ko = ks*32 + 8*gq;
            bf16x8 b0 = *(const bf16x8*)(wb0 + ko);
            bf16x8 b1 = *(const bf16x8*)(wb1 + ko);
            bf16x8 b2 = *(const bf16x8*)(wb2 + ko);
            bf16x8 b3 = *(const bf16x8*)(wb3 + ko);
            accM[0] = __builtin_amdgcn_mfma_f32_16x16x32_bf16(a, b0, accM[0], 0,0,0);
            accM[1] = __builtin_amdgcn_mfma_f32_16x16x32_bf16(a, b1, accM[1], 0,0,0);
            accM[2] = __builtin_amdgcn_mfma_f32_16x16x32_bf16(a, b2, accM[2], 0,0,0);
            accM[3] = __builtin_amdgcn_mfma_f32_16x16x32_bf16(a, b3, accM[3], 0,0,0);
        }
    }
    f32x4 aP1={0,0,0,0}, aP2={0,0,0,0}, aM1={0,0,0,0}, aM2={0,0,0,0};
    {
        const __bf16* wr = w1rt + (size_t)(16*w + cc)*192;
        const __bf16* wi = w1it + (size_t)(16*w + cc)*192;
        for (int ks=0; ks<6; ks++){
            bf16x8 a1 = ld_frag(sVFC,        cc, 384, ks*64 + 16*gq);
            bf16x8 a2 = ld_frag(sVFC + 6144, cc, 384, ks*64 + 16*gq);
            int ko = ks*32 + 8*gq;
            bf16x8 br = *(const bf16x8*)(wr + ko);
            bf16x8 bi = *(const bf16x8*)(wi + ko);
            aP1 = __builtin_amdgcn_mfma_f32_16x16x32_bf16(a1, br, aP1, 0,0,0);
            aP2 = __builtin_amdgcn_mfma_f32_16x16x32_bf16(a2, bi, aP2, 0,0,0);
            aM1 = __builtin_amdgcn_mfma_f32_16x16x32_bf16(a1, bi, aM1, 0,0,0);
            aM2 = __builtin_amdgcn_mfma_f32_16x16x32_bf16(a2, br, aM2, 0,0,0);
        }
    }
    __syncthreads();

    {
        const float rn0 = 0.0416666666667f;
        #pragma unroll
        for (int jt=0;jt<4;jt++){
            #pragma unroll
            for (int j=0;j<4;j++){
                sO[(gq*4+j)*260 + 64*w + 16*jt + cc] = accM[jt][j]*rn0;
            }
        }
    }
    float vp[4], vm[4];
    {
        const float n1 = 0.0721687836487f;
        #pragma unroll
        for (int j=0;j<4;j++){ vp[j] = (aP1[j]-aP2[j])*n1; vm[j] = (aM1[j]+aM2[j])*n1; }
    }
    __syncthreads();

    {
        int u = w*16 + cc;
        #pragma unroll
        for (int j=0;j<4;j++){
            int er = gq*4 + j;
            if (blockIdx.x*16 + er < EA){
                const float* Rr = &sR[er*12];
                float s0 = sO[er*260 + 192 + u];
                float gt = sigmoidf_(sO[er*260 + 128 + u]);
                float p = vp[j], q = vm[j];
                float4 o;
                o.x = gt*(Rr[0]*s0 + Rr[3]*p + Rr[6]*q);
                o.y = gt*(Rr[1]*s0 + Rr[4]*p + Rr[7]*q);
                o.z = gt*(Rr[2]*s0 + Rr[5]*p + Rr[8]*q);
                o.w = 0.0f;
                *(float4*)&MV[er*260 + u*4] = o;
            }
        }
    }
    if (act) {
        {
            int i0 = l*8;
            F4 oa, ob;
            oa.v = *(const float4*)&sO[g*260 + i0];
            ob.v = *(const float4*)&sO[g*260 + i0 + 4];
            #pragma unroll
            for (int i=0;i<4;i++){ oa.f[i] = siluf_(oa.f[i]); ob.f[i] = siluf_(ob.f[i]); }
            *(float4*)&sO[g*260 + i0]     = oa.v;
            *(float4*)&sO[g*260 + i0 + 4] = ob.v;
        }
        {
            const int cc2 = l*12;
            float wacc[12];
            #pragma unroll
            for (int i=0;i<12;i++) wacc[i]=0.f;
            const float* lat = latents + (size_t)ae*128;
            for (int k=0;k<128;k+=4){
                F4 la;
                la.v = *(const float4*)(lat + k);
                #pragma unroll
                for (int kk=0;kk<4;kk++){
                    const float* er_ = env_w + (size_t)(k+kk)*192 + cc2;
                    F4 e0v,e1v,e2v;
                    e0v.v = *(const float4*)(er_);
                    e1v.v = *(const float4*)(er_+4);
                    e2v.v = *(const float4*)(er_+8);
                    #pragma unroll
                    for (int i=0;i<4;i++){
                        wacc[i]   += la.f[kk]*e0v.f[i];
                        wacc[4+i] += la.f[kk]*e1v.f[i];
                        wacc[8+i] += la.f[kk]*e2v.f[i];
                    }
                }
            }
            const float inv128 = 0.0883883476483f;
            #pragma unroll
            for (int i=0;i<12;i++) WE[g*196 + cc2 + i] = wacc[i]*inv128;
        }
    }
    __syncthreads();

    if (act) {
        const float inv_avg = 0.288675134595f;
        unsigned short* orow = eout + (size_t)e*320;
        {
            int c0 = l*8;
            float a8[8];
            #pragma unroll
            for (int i=0;i<8;i++) a8[i]=0.f;
            for (int k=0;k<128;k+=4){
                F4 av;
                av.v = *(const float4*)&sO[g*260 + k];
                #pragma unroll
                for (int kk=0;kk<4;kk++){
                    const float* wr = lp_ws + (size_t)(k+kk)*128 + c0;
                    F4 w0, w1_;
                    w0.v  = *(const float4*)(wr);
                    w1_.v = *(const float4*)(wr+4);
                    #pragma unroll
                    for (int i=0;i<4;i++){ a8[i] += av.f[kk]*w0.f[i]; a8[4+i] += av.f[kk]*w1_.f[i]; }
                }
            }
            const float s128 = 0.0883883476483f;
            union { unsigned short h[8]; uint4 u; } ps;
            #pragma unroll
            for (int i=0;i<8;i++){
                int c = c0+i;
                ps.h[i] = f2bf((a8[i]*s128 + lp_bs[c]) * WE[g*196 + c] * inv_avg);
            }
            *(uint4*)(orow + c0) = ps.u;
        }
        {
            int k0 = l*4;
            float av[4][3];
            #pragma unroll
            for (int j=0;j<4;j++)
                #pragma unroll
                for (int m2=0;m2<3;m2++) av[j][m2]=0.f;
            for (int u=0;u<64;u++){
                F4 wv4, mv4;
                wv4.v = *(const float4*)(lp_wv + (size_t)u*64 + k0);
                mv4.v = *(const float4*)&MV[g*260 + u*4];
                #pragma unroll
                for (int j=0;j<4;j++){
                    av[j][0] += wv4.f[j]*mv4.f[0];
                    av[j][1] += wv4.f[j]*mv4.f[1];
                    av[j][2] += wv4.f[j]*mv4.f[2];
                }
            }
            #pragma unroll
            for (int j=0;j<4;j++){
                int k = k0+j;
                float wk = WE[g*196 + 128 + k] * 0.125f * inv_avg;
                orow[128 +       k] = f2bf(av[j][0]*wk);
                orow[128 + 64  + k] = f2bf(av[j][1]*wk);
                orow[128 + 128 + k] = f2bf(av[j][2]*wk);
            }
        }
    }
}

// ---------------- node CSR aggregate + onehot path + output (ILP-restructured) ----------------
__global__ void node_out_kernel(
    const float* __restrict__ nf,
    const int* __restrict__ atom_type,
    const int* __restrict__ offs, const int* __restrict__ elist,
    const unsigned short* __restrict__ eout,
    const __bf16* __restrict__ ssT, const __bf16* __restrict__ sgT, const __bf16* __restrict__ vvT,
    const float* __restrict__ ohl_ws, const float* __restrict__ ohl_bs, const float* __restrict__ ohl_wv,
    const float* __restrict__ res_param,
    float* __restrict__ out, int N)
{
    __shared__ int   sE[64];
    __shared__ float AGS[128];
    __shared__ float AGV[192];
    __shared__ float TSs[128];
    __shared__ float SG[64];
    __shared__ float TV[192];
    const int n = blockIdx.x;
    const int t = threadIdx.x;
    const int at = atom_type[n];
    const int lo = offs[n], hi = offs[n+1];

    // gather-aggregate: threads 0..159 own cols {2t, 2t+1}; 4-stream ILP
    float aLo = 0.f, aHi = 0.f;
    for (int base = lo; base < hi; base += 64){
        int cnt = hi - base; if (cnt > 64) cnt = 64;
        __syncthreads();
        if (t < cnt) sE[t] = elist[base + t];
        __syncthreads();
        if (t < 160){
            int i = 0;
            for (; i+4 <= cnt; i += 4){
                unsigned x0 = *(const unsigned*)(eout + (size_t)sE[i  ]*320 + 2*t);
                unsigned x1 = *(const unsigned*)(eout + (size_t)sE[i+1]*320 + 2*t);
                unsigned x2 = *(const unsigned*)(eout + (size_t)sE[i+2]*320 + 2*t);
                unsigned x3 = *(const unsigned*)(eout + (size_t)sE[i+3]*320 + 2*t);
                aLo += bf2f((unsigned short)x0) + bf2f((unsigned short)x1)
                     + bf2f((unsigned short)x2) + bf2f((unsigned short)x3);
                aHi += bf2f((unsigned short)(x0>>16)) + bf2f((unsigned short)(x1>>16))
                     + bf2f((unsigned short)(x2>>16)) + bf2f((unsigned short)(x3>>16));
            }
            for (; i < cnt; i++){
                unsigned x = *(const unsigned*)(eout + (size_t)sE[i]*320 + 2*t);
                aLo += bf2f((unsigned short)x);
                aHi += bf2f((unsigned short)(x>>16));
            }
        }
    }
    if (t < 160){
        int c0 = 2*t, c1 = 2*t+1;
        if (c0 < 128) AGS[c0] = aLo; else { int d=c0-128; AGV[(d&63)*3 + (d>>6)] = aLo; }
        if (c1 < 128) AGS[c1] = aHi; else { int d=c1-128; AGV[(d&63)*3 + (d>>6)] = aHi; }
    }
    __syncthreads();
    const float n_ss = 0.0110485434560f;
    const float n_vv = 0.015625f;
    if (t < 128) {
        const __bf16* w = ssT + (size_t)at*16384 + t;
        float acc = 0.0f;
        #pragma unroll 8
        for (int u=0;u<128;u++) acc += AGS[u]*(float)w[(size_t)u*128];
        TSs[t] = siluf_(acc*n_ss);
    } else if (t < 192) {
        int k = t-128;
        const __bf16* w = sgT + (size_t)at*8192 + k;
        float acc = 0.0f;
        #pragma unroll 8
        for (int u=0;u<128;u++) acc += AGS[u]*(float)w[(size_t)u*64];
        SG[k] = sigmoidf_(acc*n_ss);
    } else {
        int k = t-192;
        const __bf16* w = vvT + (size_t)at*4096 + k;
        float a0=0,a1=0,a2=0;
        #pragma unroll 8
        for (int u=0;u<64;u++){
            float wv = (float)w[(size_t)u*64];
            a0 += AGV[u*3+0]*wv;
            a1 += AGV[u*3+1]*wv;
            a2 += AGV[u*3+2]*wv;
        }
        TV[k*3+0]=a0*n_vv; TV[k*3+1]=a1*n_vv; TV[k*3+2]=a2*n_vv;
    }
    __syncthreads();
    const float alpha = sigmoidf_(res_param[0]);
    const float beta  = 1.0f - alpha;
    if (t < 128) {
        float acc = 0.0f;
        #pragma unroll 8
        for (int k=0;k<128;k++) acc += TSs[k]*ohl_ws[(size_t)k*128 + t];
        float val = acc*0.0883883476483f + ohl_bs[t];
        out[(size_t)n*320 + t] = alpha*nf[(size_t)n*320 + t] + beta*val;
    } else if (t >= 192) {
        int k = t-192;
        float a0=0,a1=0,a2=0;
        #pragma unroll 8
        for (int u=0;u<64;u++){
            float w = ohl_wv[(size_t)u*64 + k]*SG[u];
            a0 += TV[u*3+0]*w; a1 += TV[u*3+1]*w; a2 += TV[u*3+2]*w;
        }
        size_t base = (size_t)n*320 + 128 + (size_t)k*3;
        out[base+0] = alpha*nf[base+0] + beta*(a0*0.125f);
        out[base+1] = alpha*nf[base+1] + beta*(a1*0.125f);
        out[base+2] = alpha*nf[base+2] + beta*(a2*0.125f);
    }
}

extern "C" void kernel_launch(void* const* d_in, const int* in_sizes, int n_in,
                              void* d_out, int out_size, void* d_ws, size_t ws_size,
                              hipStream_t stream)
{
    const float* latents       = (const float*)d_in[0];
    const float* node_features = (const float*)d_in[1];
    const float* edge_features = (const float*)d_in[2];
    const int*   atom_type     = (const int*)d_in[3];
    const int*   edge_index    = (const int*)d_in[5];
    const float* edge_vector   = (const float*)d_in[6];
    const int*   active_edges  = (const int*)d_in[7];
    const float* sln_n_ws = (const float*)d_in[8];
    const float* sln_n_bs = (const float*)d_in[9];
    const float* sln_n_wv = (const float*)d_in[10];
    const float* sln_e_ws = (const float*)d_in[11];
    const float* sln_e_bs = (const float*)d_in[12];
    const float* sln_e_wv = (const float*)d_in[13];
    const float* so2_w0   = (const float*)d_in[14];
    const float* so2_w1r  = (const float*)d_in[15];
    const float* so2_w1i  = (const float*)d_in[16];
    const float* env_w    = (const float*)d_in[17];
    const float* lp_ws    = (const float*)d_in[18];
    const float* lp_bs    = (const float*)d_in[19];
    const float* lp_wv    = (const float*)d_in[20];
    const float* oh_w_ss  = (const float*)d_in[21];
    const float* oh_w_sg  = (const float*)d_in[22];
    const float* oh_w_vv  = (const float*)d_in[23];
    const float* ohl_ws   = (const float*)d_in[24];
    const float* ohl_bs   = (const float*)d_in[25];
    const float* ohl_wv   = (const float*)d_in[26];
    const float* res_param= (const float*)d_in[27];
    float* out = (float*)d_out;

    const int N  = in_sizes[1] / 320;
    const int EF = in_sizes[5] / 2;
    const int EA = in_sizes[7];

    // workspace layout (256B-aligned chunks)
    char* p = (char*)d_ws;
    auto alloc = [&](size_t bytes) -> char* {
        char* r = p; p += (bytes + 255) & ~(size_t)255; return r;
    };
    float* ns      = (float*)alloc((size_t)N*128*4);
    float* nv      = (float*)alloc((size_t)N*192*4);
    __bf16* nsb    = (__bf16*)alloc((size_t)N*128*2);
    int*   cnt     = (int*)  alloc((size_t)N*4);
    int*   offs    = (int*)  alloc(((size_t)N+1)*4);
    int*   cursor  = (int*)  alloc((size_t)N*4);
    int*   elist   = (int*)  alloc((size_t)EA*4);
    __bf16* Wt     = (__bf16*)alloc((size_t)576*256*2);
    __bf16* w1rt   = (__bf16*)alloc((size_t)64*192*2);
    __bf16* w1it   = (__bf16*)alloc((size_t)64*192*2);
    __bf16* Wevfm  = (__bf16*)alloc((size_t)256*320*2);
    __bf16* Bnodefm= (__bf16*)alloc((size_t)512*128*2);
    __bf16* Bvfm   = (__bf16*)alloc((size_t)128*384*2);
    __bf16* envfm  = (__bf16*)alloc((size_t)192*128*2);
    __bf16* lpsfm  = (__bf16*)alloc((size_t)128*128*2);
    __bf16* lpvfm  = (__bf16*)alloc((size_t)64*64*2);
    __bf16* ssT    = (__bf16*)alloc((size_t)64*128*128*2);
    __bf16* sgT    = (__bf16*)alloc((size_t)64*128*64*2);
    __bf16* vvT    = (__bf16*)alloc((size_t)64*64*64*2);
    __bf16* nodeCN = (__bf16*)alloc((size_t)N*512*2);
    int2*  ctnb    = (int2*) alloc((size_t)EA*8);
    unsigned short* eout = (unsigned short*)alloc((size_t)EA*320*2);
    unsigned short* w_env= (unsigned short*)alloc((size_t)EA*192*2);
    float*  Rg    = (float*) alloc((size_t)EA*12*4);
    __bf16* m0in  = (__bf16*)alloc((size_t)EA*320*2);
    __bf16* vfg   = (__bf16*)alloc((size_t)EA*384*2);
    size_t split_need = (size_t)(p - (char*)d_ws);
    const bool use_split = (split_need <= ws_size);

    // aliases (split path only; all uses are stream-ordered)
    unsigned short* vpvm  = eout;                   // [EA][128], consumed by mid before eout written
    unsigned short* m0out = (unsigned short*)vfg;   // [EA][256], written after vfg consumed
    unsigned short* As    = (unsigned short*)m0in;  // [EA][128], after m0in consumed
    unsigned short* MVp   = As + (size_t)EA*128;    // 3 planes [EA][64]; 128+192=320 fits m0in width

    hipMemsetAsync(cnt, 0, (size_t)N*sizeof(int), stream);
    prep_all<<<4096, 256, 0, stream>>>(so2_w0, so2_w1r, so2_w1i, env_w, lp_ws, lp_wv,
                                       oh_w_ss, oh_w_sg, oh_w_vv,
                                       Wt, w1rt, w1it, Wevfm, Bnodefm, Bvfm,
                                       envfm, lpsfm, lpvfm, ssT, sgT, vvT);
    node_ln_kernel<<<(N+3)/4, 256, 0, stream>>>(node_features, sln_n_ws, sln_n_bs, sln_n_wv, ns, nv, nsb, N);
    csr_count<<<(EA+255)/256, 256, 0, stream>>>(edge_index, active_edges, cnt, EA);
    csr_scan<<<1, 256, 0, stream>>>(cnt, offs, cursor, N);
    csr_fill<<<(EA+255)/256, 256, 0, stream>>>(edge_index, active_edges, cursor, elist, EA);

    const float rn0    = 0.0416666666667f;   // 1/sqrt(576)
    const float n1     = 0.0721687836487f;   // 1/sqrt(192)
    const float inv128 = 0.0883883476483f;   // 1/sqrt(128)

    if (use_split){
        const int NB64  = (EA + 63) / 64;
        const int NB128 = (EA + 127) / 128;
        const int NBn   = (N + 63) / 64;
        // node-side contributions: nsb[N][128] x [512 cols] -> nodeCN[N][512]
        gemm_k<512,128,1,EPI_PLAIN,false><<<dim3(NBn,1), 512, 0, stream>>>(
            nsb, nullptr, nullptr, Bnodefm, (unsigned short*)nodeCN, nullptr, nullptr, nullptr, nullptr, 1.0f, N);
        stage_kernel<<<(EA+15)/16, 256, 0, stream>>>(edge_features, edge_index, edge_vector, active_edges,
            sln_e_ws, sln_e_bs, sln_e_wv, nv, m0in, vfg, Rg, ctnb, EA, EF);
        // vp/vm: [EA][384] x Bv -> vpvm[EA][128]  (before main so vfg dead when m0out overlays)
        gemm_k<128,384,2,EPI_PLAIN,false><<<dim3(NB128,1), 256, 0, stream>>>(
            vfg, nullptr, nullptr, Bvfm, vpvm, nullptr, nullptr, nullptr, nullptr, n1, EA);
        // main: [EA][320] x Wev + nodeCN gather-add -> m0out[EA][256]
        gemm_k<256,320,1,EPI_MAINADD,false><<<dim3(NB64,1), 256, 0, stream>>>(
            m0in, nullptr, nullptr, Wevfm, m0out, nullptr, nullptr, ctnb, nodeCN, rn0, EA);
        mid_kernel<<<(EA*64+255)/256, 256, 0, stream>>>(m0out, vpvm, Rg, As, MVp, EA);
        gemm_k<192,128,1,EPI_PLAIN,true><<<dim3(NB64,1), 192, 0, stream>>>(
            nullptr, latents, active_edges, envfm, w_env, nullptr, nullptr, nullptr, nullptr, inv128, EA);
        gemm_k<128,128,2,EPI_LPS,false><<<dim3(NB128,1), 256, 0, stream>>>(
            (const __bf16*)As, nullptr, nullptr, lpsfm, eout, w_env, lp_bs, nullptr, nullptr, inv128, EA);
        gemm_k<64,64,2,EPI_LPV,false><<<dim3(NB128,3), 128, 0, stream>>>(
            (const __bf16*)MVp, nullptr, nullptr, lpvfm, eout, w_env, nullptr, nullptr, nullptr, 0.125f, EA);
    } else {
        edge_kernel_fused<<<(EA+15)/16, 256, 0, stream>>>(latents, edge_features, edge_index, edge_vector, active_edges,
            sln_e_ws, sln_e_bs, sln_e_wv, Wt, w1rt, w1it, env_w, lp_ws, lp_bs, lp_wv,
            ns, nv, eout, EA, EF);
    }
    node_out_kernel<<<N, 256, 0, stream>>>(node_features, atom_type, offs, elist, eout,
        ssT, sgT, vvT, ohl_ws, ohl_bs, ohl_wv, res_param, out, N);
}

// Round 9
// 465.201 us; speedup vs baseline: 1.1265x; 1.1039x over previous
//
#include <hip/hip_runtime.h>

#define EPS_LN 1e-8f

typedef __bf16 bf16x8 __attribute__((ext_vector_type(8)));
typedef float  f32x4  __attribute__((ext_vector_type(4)));

__device__ __forceinline__ float sigmoidf_(float x){ return 1.0f/(1.0f+__expf(-x)); }
__device__ __forceinline__ float siluf_(float x){ return x*sigmoidf_(x); }
__device__ __forceinline__ unsigned short f2bf(float x){ union{ __bf16 b; unsigned short u;} c; c.b = (__bf16)x; return c.u; }
__device__ __forceinline__ float bf2f(unsigned short u){ return __uint_as_float(((unsigned)u)<<16); }

union F4 { float4 v; float f[4]; };

// swizzled bf16 LDS store (fused fallback path)
__device__ __forceinline__ void st_bf4(char* base, int row, int stride_bytes, int k,
                                       float x0, float x1, float x2, float x3){
    union { __bf16 h[4]; unsigned long long u; } p;
    p.h[0]=(__bf16)x0; p.h[1]=(__bf16)x1; p.h[2]=(__bf16)x2; p.h[3]=(__bf16)x3;
    *(unsigned long long*)(base + row*stride_bytes + ((2*k) ^ ((row&7)<<4))) = p.u;
}
__device__ __forceinline__ bf16x8 ld_frag(const char* base, int row, int stride_bytes, int kbyte){
    return *(const bf16x8*)(base + row*stride_bytes + (kbyte ^ ((row&7)<<4)));
}
__device__ __forceinline__ void st_g4(__bf16* p, float x0, float x1, float x2, float x3){
    union { __bf16 h[4]; unsigned long long u; } pk;
    pk.h[0]=(__bf16)x0; pk.h[1]=(__bf16)x1; pk.h[2]=(__bf16)x2; pk.h[3]=(__bf16)x3;
    *(unsigned long long*)p = pk.u;
}
__device__ __forceinline__ uint4 pack8(float4 a, float4 b){
    union { __bf16 h[8]; uint4 u; } p;
    p.h[0]=(__bf16)a.x; p.h[1]=(__bf16)a.y; p.h[2]=(__bf16)a.z; p.h[3]=(__bf16)a.w;
    p.h[4]=(__bf16)b.x; p.h[5]=(__bf16)b.y; p.h[6]=(__bf16)b.z; p.h[7]=(__bf16)b.w;
    return p.u;
}
// fragment-major dest index for B[n][k] tiles (16 cols x 32 k per fragment)
__device__ __forceinline__ int fm_idx(int n, int k, int NKT){
    return ((n>>4)*NKT + (k>>5))*512 + ((k>>3)&3)*128 + (n&15)*8 + (k&7);
}

// ---------------- weight prep (all packs in one kernel) ----------------
__global__ void prep_all(const float* __restrict__ w0,
                         const float* __restrict__ w1r, const float* __restrict__ w1i,
                         const float* __restrict__ env_w, const float* __restrict__ lp_ws,
                         const float* __restrict__ lp_wv,
                         const float* __restrict__ oh_ss, const float* __restrict__ oh_sg,
                         const float* __restrict__ oh_vv,
                         __bf16* __restrict__ Wt, __bf16* __restrict__ w1rt, __bf16* __restrict__ w1it,
                         __bf16* __restrict__ Wevfm, __bf16* __restrict__ Bnodefm,
                         __bf16* __restrict__ Bvfm,
                         __bf16* __restrict__ envfm, __bf16* __restrict__ lpsfm,
                         __bf16* __restrict__ lpvfm,
                         __bf16* __restrict__ ssT, __bf16* __restrict__ sgT, __bf16* __restrict__ vvT)
{
    int t = blockIdx.x*256 + threadIdx.x;
    if (t < 576*256){                          // fallback row-major Wt[256][576]
        int n = t/576, k = t%576;
        Wt[t] = (__bf16)w0[(size_t)k*256 + n];
    }
    if (t < 256*320){                          // edge GEMM weights: rows {128..255}U{384..575}
        int n = t/320, k = t%320;
        int src = (k<128) ? (128+k) : (384+(k-128));
        Wevfm[fm_idx(n,k,10)] = (__bf16)w0[(size_t)src*256 + n];
    }
    if (t < 512*128){                          // node GEMM: cols 0..255 = W rows 0..127; 256..511 = rows 256..383
        int n = t/128, k = t%128;
        float v = (n<256) ? w0[(size_t)k*256 + n] : w0[(size_t)(256+k)*256 + (n-256)];
        Bnodefm[fm_idx(n,k,4)] = (__bf16)v;
    }
    if (t < 64*192){
        int c = t/192, k = t%192;
        w1rt[t] = (__bf16)w1r[(size_t)k*64 + c];
        w1it[t] = (__bf16)w1i[(size_t)k*64 + c];
    }
    if (t < 128*384){
        int n = t/384, k = t%384;
        float v;
        if (n < 64) v = (k<192) ? w1r[(size_t)k*64+n] : -w1i[(size_t)(k-192)*64+n];
        else        v = (k<192) ? w1i[(size_t)k*64+(n-64)] : w1r[(size_t)(k-192)*64+(n-64)];
        Bvfm[fm_idx(n,k,12)] = (__bf16)v;
    }
    if (t < 192*128){ int n=t/128, k=t%128; envfm[fm_idx(n,k,4)] = (__bf16)env_w[(size_t)k*192+n]; }
    if (t < 128*128){ int n=t/128, k=t%128; lpsfm[fm_idx(n,k,4)] = (__bf16)lp_ws[(size_t)k*128+n]; }
    if (t < 64*64)  { int n=t/64,  k=t%64;  lpvfm[fm_idx(n,k,2)] = (__bf16)lp_wv[(size_t)k*64+n]; }
    if (t < 64*128*128){                       // ssT[at][u][k]
        int at = t / 16384; int r = t & 16383; int u = r >> 7, k = r & 127;
        ssT[t] = (__bf16)oh_ss[((size_t)u*64 + at)*128 + k];
    }
    if (t < 64*128*64){                        // sgT[at][u][k]
        int at = t / 8192; int r = t & 8191; int u = r >> 6, k = r & 63;
        sgT[t] = (__bf16)oh_sg[((size_t)u*64 + at)*64 + k];
    }
    if (t < 64*64*64){                         // vvT[at][u][k]
        int at = t / 4096; int r = t & 4095; int u = r >> 6, k = r & 63;
        vvT[t] = (__bf16)oh_vv[((size_t)u*64 + at)*64 + k];
    }
}

// ---------------- CSR build ----------------
__global__ void csr_count(const int* __restrict__ ei, const int* __restrict__ act,
                          int* __restrict__ cnt, int EA)
{
    int e = blockIdx.x*256 + threadIdx.x;
    if (e < EA) atomicAdd(&cnt[ei[act[e]]], 1);
}
__global__ void csr_scan(const int* __restrict__ cnt, int* __restrict__ offs,
                         int* __restrict__ cursor, int N)
{
    __shared__ int part[256];
    int t = threadIdx.x;
    int chunk = (N + 255) / 256;
    int lo = t*chunk, hi = lo+chunk; if (hi > N) hi = N; if (lo > N) lo = N;
    int s = 0;
    for (int i=lo;i<hi;i++) s += cnt[i];
    part[t] = s;
    __syncthreads();
    for (int d=1; d<256; d<<=1){
        int v = (t>=d) ? part[t-d] : 0;
        __syncthreads();
        part[t] += v;
        __syncthreads();
    }
    int run = (t==0) ? 0 : part[t-1];
    for (int i=lo;i<hi;i++){
        offs[i] = run; cursor[i] = run;
        run += cnt[i];
    }
    if (t==255) offs[N] = part[255];
}
__global__ void csr_fill(const int* __restrict__ ei, const int* __restrict__ act,
                         int* __restrict__ cursor, int* __restrict__ elist, int EA)
{
    int e = blockIdx.x*256 + threadIdx.x;
    if (e < EA){
        int n = ei[act[e]];
        int p = atomicAdd(&cursor[n], 1);
        elist[p] = e;
    }
}

// ---------------- node separable layernorm (+ bf16 scalar copy for node GEMM) ----------------
__global__ void node_ln_kernel(const float* __restrict__ nf,
                               const float* __restrict__ ws, const float* __restrict__ bs,
                               const float* __restrict__ wv,
                               float* __restrict__ ns, float* __restrict__ nv,
                               __bf16* __restrict__ nsb, int N)
{
    int t = threadIdx.x;
    int lane = t & 63;
    int n = blockIdx.x*4 + (t>>6);
    if (n >= N) return;
    const float* row = nf + (size_t)n*320;
    float s0 = row[lane], s1 = row[64+lane];
    float sum = s0+s1, sq = s0*s0+s1*s1;
    #pragma unroll
    for (int m=1;m<64;m<<=1){ sum += __shfl_xor(sum,m,64); sq += __shfl_xor(sq,m,64); }
    float mu = sum*(1.0f/128.0f);
    float rs = rsqrtf(sq*(1.0f/128.0f) - mu*mu + EPS_LN);
    float o0 = (s0-mu)*rs*ws[lane]    + bs[lane];
    float o1 = (s1-mu)*rs*ws[64+lane] + bs[64+lane];
    ns[(size_t)n*128+lane]    = o0;
    ns[(size_t)n*128+64+lane] = o1;
    nsb[(size_t)n*128+lane]    = (__bf16)o0;
    nsb[(size_t)n*128+64+lane] = (__bf16)o1;
    float v0 = row[128+lane], v1 = row[192+lane], v2 = row[256+lane];
    float vs = v0*v0+v1*v1+v2*v2;
    #pragma unroll
    for (int m=1;m<64;m<<=1) vs += __shfl_xor(vs,m,64);
    float rv = rsqrtf(vs*(1.0f/192.0f) + EPS_LN);
    nv[(size_t)n*192+lane]     = v0*rv*wv[lane/3];
    nv[(size_t)n*192+64+lane]  = v1*rv*wv[(64+lane)/3];
    nv[(size_t)n*192+128+lane] = v2*rv*wv[(128+lane)/3];
}

// ---------------- per-edge staging -> global bf16 (no node-scalar copies) ----------------
__global__ void stage_kernel(
    const float* __restrict__ ef_all,
    const int*   __restrict__ edge_index,
    const float* __restrict__ edge_vector,
    const int*   __restrict__ active_edges,
    const float* __restrict__ e_ws, const float* __restrict__ e_bs, const float* __restrict__ e_wv,
    const float* __restrict__ nv,
    __bf16* __restrict__ m0in,   // [EA][320]: [es(128) | vf0(192)]
    __bf16* __restrict__ vfg,    // [EA][384]: [vf1(192) | vf2(192)]
    float* __restrict__ Rg, int2* __restrict__ ctnb,
    int EA, int EF)
{
    int tid = blockIdx.x*256 + threadIdx.x;
    int e = tid >> 4, l = tid & 15;
    if (e >= EA) return;
    int ae = active_edges[e];
    int ct = edge_index[ae];
    int nb = edge_index[EF + ae];
    float ex = edge_vector[(size_t)ae*3+0];
    float ey = edge_vector[(size_t)ae*3+1];
    float ez = edge_vector[(size_t)ae*3+2];
    float rn = rsqrtf(ex*ex+ey*ey+ez*ez + EPS_LN);
    float ax = ex*rn, ay = ey*rn, az = ez*rn;
    float rx, ry;
    if (fabsf(ax) < 0.9f) { rx = 1.0f; ry = 0.0f; } else { rx = 0.0f; ry = 1.0f; }
    float bx = -az*ry, by = az*rx, bz = ax*ry - ay*rx;
    float bn = rsqrtf(bx*bx+by*by+bz*bz + EPS_LN);
    bx*=bn; by*=bn; bz*=bn;
    float cx = ay*bz - az*by;
    float cy = az*bx - ax*bz;
    float cz = ax*by - ay*bx;
    if (l == 0){
        float* Rr = Rg + (size_t)e*12;
        *(float4*)(Rr)   = make_float4(ax,ay,az,bx);
        *(float4*)(Rr+4) = make_float4(by,bz,cx,cy);
        *(float4*)(Rr+8) = make_float4(cz,0.f,0.f,0.f);
        ctnb[e] = make_int2(ct, nb);
    }
    __bf16* Arow = m0in + (size_t)e*320;
    __bf16* V1r  = vfg + (size_t)e*384;
    __bf16* V2r  = V1r + 192;
    const float* ef = ef_all + (size_t)e*320;
    {   // edge scalar LN -> Arow[0:128)
        F4 sa, sb;
        sa.v = *(const float4*)(ef + l*4);
        sb.v = *(const float4*)(ef + 64 + l*4);
        float sum=0.f, sq=0.f;
        #pragma unroll
        for (int i=0;i<4;i++){ sum += sa.f[i]+sb.f[i]; sq += sa.f[i]*sa.f[i]+sb.f[i]*sb.f[i]; }
        #pragma unroll
        for (int m=1;m<16;m<<=1){ sum += __shfl_xor(sum,m,64); sq += __shfl_xor(sq,m,64); }
        float mu = sum*(1.0f/128.0f);
        float rs = rsqrtf(sq*(1.0f/128.0f)-mu*mu + EPS_LN);
        float o0[4], o1[4];
        #pragma unroll
        for (int i=0;i<4;i++){
            int c0 = l*4+i, c1 = 64+l*4+i;
            o0[i] = (sa.f[i]-mu)*rs*e_ws[c0]+e_bs[c0];
            o1[i] = (sb.f[i]-mu)*rs*e_ws[c1]+e_bs[c1];
        }
        st_g4(Arow + l*4,      o0[0],o0[1],o0[2],o0[3]);
        st_g4(Arow + 64 + l*4, o1[0],o1[1],o1[2],o1[3]);
    }
    {   // edge vector LN + rotate (u 64..127)
        F4 va, vb, vc;
        va.v = *(const float4*)(ef + 128 + l*12);
        vb.v = *(const float4*)(ef + 128 + l*12 + 4);
        vc.v = *(const float4*)(ef + 128 + l*12 + 8);
        float vv[12];
        #pragma unroll
        for (int i=0;i<4;i++){ vv[i]=va.f[i]; vv[4+i]=vb.f[i]; vv[8+i]=vc.f[i]; }
        float sq=0.f;
        #pragma unroll
        for (int i=0;i<12;i++) sq += vv[i]*vv[i];
        #pragma unroll
        for (int m=1;m<16;m<<=1) sq += __shfl_xor(sq,m,64);
        float rv = rsqrtf(sq*(1.0f/192.0f) + EPS_LN);
        float f0[4], f1[4], f2[4];
        #pragma unroll
        for (int j=0;j<4;j++){
            int u = 4*l + j;
            float sc = rv * e_wv[u];
            float x = vv[3*j]*sc, y = vv[3*j+1]*sc, z = vv[3*j+2]*sc;
            f0[j] = ax*x+ay*y+az*z;
            f1[j] = bx*x+by*y+bz*z;
            f2[j] = cx*x+cy*y+cz*z;
        }
        st_g4(Arow + 128 + 64 + 4*l, f0[0],f0[1],f0[2],f0[3]);
        st_g4(V1r + 64 + 4*l, f1[0],f1[1],f1[2],f1[3]);
        st_g4(V2r + 64 + 4*l, f2[0],f2[1],f2[2],f2[3]);
    }
    {   // nv[ctr] (u 0..63)
        const float* pv = nv + (size_t)ct*192 + l*12;
        F4 va, vb, vc;
        va.v = *(const float4*)(pv);
        vb.v = *(const float4*)(pv+4);
        vc.v = *(const float4*)(pv+8);
        float vv[12];
        #pragma unroll
        for (int i=0;i<4;i++){ vv[i]=va.f[i]; vv[4+i]=vb.f[i]; vv[8+i]=vc.f[i]; }
        float f0[4], f1[4], f2[4];
        #pragma unroll
        for (int j=0;j<4;j++){
            float x = vv[3*j], y = vv[3*j+1], z = vv[3*j+2];
            f0[j] = ax*x+ay*y+az*z;
            f1[j] = bx*x+by*y+bz*z;
            f2[j] = cx*x+cy*y+cz*z;
        }
        st_g4(Arow + 128 + 4*l, f0[0],f0[1],f0[2],f0[3]);
        st_g4(V1r + 4*l, f1[0],f1[1],f1[2],f1[3]);
        st_g4(V2r + 4*l, f2[0],f2[1],f2[2],f2[3]);
    }
    {   // nv[nbr] (u 128..191)
        const float* pv = nv + (size_t)nb*192 + l*12;
        F4 va, vb, vc;
        va.v = *(const float4*)(pv);
        vb.v = *(const float4*)(pv+4);
        vc.v = *(const float4*)(pv+8);
        float vv[12];
        #pragma unroll
        for (int i=0;i<4;i++){ vv[i]=va.f[i]; vv[4+i]=vb.f[i]; vv[8+i]=vc.f[i]; }
        float f0[4], f1[4], f2[4];
        #pragma unroll
        for (int j=0;j<4;j++){
            float x = vv[3*j], y = vv[3*j+1], z = vv[3*j+2];
            f0[j] = ax*x+ay*y+az*z;
            f1[j] = bx*x+by*y+bz*z;
            f2[j] = cx*x+cy*y+cz*z;
        }
        st_g4(Arow + 128 + 128 + 4*l, f0[0],f0[1],f0[2],f0[3]);
        st_g4(V1r + 128 + 4*l, f1[0],f1[1],f1[2],f1[3]);
        st_g4(V2r + 128 + 4*l, f2[0],f2[1],f2[2],f2[3]);
    }
}

// ---------------- tiled MFMA GEMM, fragment-major B direct from global (L2-resident) ----
enum { EPI_PLAIN=0, EPI_LPS=1, EPI_LPV=2 };

template<int N, int K, int RT, int EPI, bool AGATHER>
__global__ __launch_bounds__((N/64)*RT*64)
void gemm_k(const __bf16* __restrict__ Ag, const float* __restrict__ Agf,
            const int* __restrict__ aidx,
            const __bf16* __restrict__ Bfm,
            unsigned short* __restrict__ outp,
            const unsigned short* __restrict__ wenv,
            const float* __restrict__ bias,
            float scale, int M)
{
    constexpr int NT  = N/64;
    constexpr int BM  = RT*64;
    constexpr int T   = NT*RT*64;
    constexpr int NKT = K/32;
    constexpr int NK  = K/64;
    constexpr int CA  = (BM*8 + T - 1)/T;
    __shared__ __align__(16) char lA[2][BM*128];

    const int tid  = threadIdx.x;
    const int brow = blockIdx.x*BM;
    const int mpl  = blockIdx.y;
    const __bf16* A = AGATHER ? nullptr : (Ag + (size_t)mpl*M*K);

    uint4 ra[CA];
    auto loadA = [&](int ks){
        #pragma unroll
        for (int i=0;i<CA;i++){
            int c = tid + i*T;
            if (c < BM*8){
                int r = c>>3;
                int gr = brow + r; if (gr >= M) gr = M-1;
                if constexpr (AGATHER){
                    int ae = aidx[gr];
                    const float* base = Agf + (size_t)ae*K + ks*64 + (c&7)*8;
                    float4 f0 = *(const float4*)(base);
                    float4 f1 = *(const float4*)(base+4);
                    ra[i] = pack8(f0, f1);
                } else {
                    ra[i] = *(const uint4*)((const char*)(A + (size_t)gr*K + ks*64) + (c&7)*16);
                }
            }
        }
    };
    auto storeA = [&](int buf){
        #pragma unroll
        for (int i=0;i<CA;i++){
            int c = tid + i*T;
            if (c < BM*8){
                int r = c>>3, off = (c&7)*16;
                *(uint4*)(&lA[buf][r*128 + (off ^ ((r&7)<<4))]) = ra[i];
            }
        }
    };

    const int wid = tid>>6, ln = tid&63;
    const int cc = ln & 15, gq = ln >> 4;
    const int wn = wid % NT, wm = wid / NT;
    const __bf16* bbase = Bfm + ((size_t)wn*4*NKT)*512 + (size_t)ln*8;

    f32x4 acc[4][4];
    #pragma unroll
    for (int i=0;i<4;i++)
        #pragma unroll
        for (int j=0;j<4;j++) acc[i][j] = (f32x4){0,0,0,0};

    loadA(0); storeA(0);
    int cur = 0;
    for (int ks=0; ks<NK; ks++){
        __syncthreads();
        if (ks+1 < NK) loadA(ks+1);
        #pragma unroll
        for (int kt2=0;kt2<2;kt2++){
            const int kt = ks*2 + kt2;
            const int kb = kt2*64 + 16*gq;
            bf16x8 af[4];
            #pragma unroll
            for (int mf=0;mf<4;mf++){
                int r = wm*64 + mf*16 + cc;
                af[mf] = *(const bf16x8*)(&lA[cur][r*128 + (kb ^ ((r&7)<<4))]);
            }
            #pragma unroll
            for (int nf=0;nf<4;nf++){
                bf16x8 bfr = *(const bf16x8*)(bbase + ((size_t)nf*NKT + kt)*512);
                #pragma unroll
                for (int mf=0;mf<4;mf++)
                    acc[mf][nf] = __builtin_amdgcn_mfma_f32_16x16x32_bf16(af[mf], bfr, acc[mf][nf], 0,0,0);
            }
        }
        if (ks+1 < NK) storeA(cur^1);
        cur ^= 1;
    }

    const float inv_avg_ = 0.288675134595f;
    #pragma unroll
    for (int mf=0;mf<4;mf++){
        #pragma unroll
        for (int nf=0;nf<4;nf++){
            #pragma unroll
            for (int j=0;j<4;j++){
                int gr = brow + wm*64 + mf*16 + gq*4 + j;
                if (gr >= M) continue;
                int col = wn*64 + nf*16 + cc;
                float v = acc[mf][nf][j];
                if constexpr (EPI == EPI_PLAIN){
                    outp[(size_t)gr*N + col] = f2bf(v*scale);
                } else if constexpr (EPI == EPI_LPS){
                    float val = (v*scale + bias[col]) * bf2f(wenv[(size_t)gr*192 + col]) * inv_avg_;
                    outp[(size_t)gr*320 + col] = f2bf(val);
                } else {
                    float val = v*0.125f * bf2f(wenv[(size_t)gr*192 + 128 + col]) * inv_avg_;
                    outp[(size_t)gr*320 + 128 + mpl*64 + col] = f2bf(val);
                }
            }
        }
    }
}

// ---------------- mid: nodeCN gather-add + gate + rotate-back + silu ----------------
__global__ void mid_kernel(const unsigned short* __restrict__ m0out,
                           const unsigned short* __restrict__ vpvm,
                           const float* __restrict__ Rg,
                           const int2* __restrict__ ctnb,
                           const __bf16* __restrict__ nodeCN,
                           unsigned short* __restrict__ As,
                           unsigned short* __restrict__ MVp, int EA)
{
    int tid = blockIdx.x*256 + threadIdx.x;
    int e = tid>>6, u = tid&63;
    if (e >= EA) return;
    float rl = (u < 12) ? Rg[(size_t)e*12 + u] : 0.f;
    float R0=__shfl(rl,0,64), R1=__shfl(rl,1,64), R2=__shfl(rl,2,64);
    float R3=__shfl(rl,3,64), R4=__shfl(rl,4,64), R5=__shfl(rl,5,64);
    float R6=__shfl(rl,6,64), R7=__shfl(rl,7,64), R8=__shfl(rl,8,64);
    int2 cn = ctnb[e];                                // wave-uniform
    const __bf16* nct = nodeCN + (size_t)cn.x*512;    // W rows 0..127 contribution
    const __bf16* nnb = nodeCN + (size_t)cn.y*512 + 256; // W rows 256..383 contribution
    const float rn0 = 0.0416666666667f;               // 1/sqrt(576)
    float a0 = ((float)nct[u]       + (float)nnb[u])       * rn0;
    float a1 = ((float)nct[64+u]    + (float)nnb[64+u])    * rn0;
    float a2 = ((float)nct[128+u]   + (float)nnb[128+u])   * rn0;
    float a3 = ((float)nct[192+u]   + (float)nnb[192+u])   * rn0;
    const unsigned short* mo = m0out + (size_t)e*256;
    float m0 = bf2f(mo[u])       + a0;
    float m1 = bf2f(mo[64 + u])  + a1;
    float gt = sigmoidf_(bf2f(mo[128 + u]) + a2);
    float s0 = bf2f(mo[192 + u]) + a3;
    float p  = bf2f(vpvm[(size_t)e*128 + u]);
    float q  = bf2f(vpvm[(size_t)e*128 + 64 + u]);
    size_t eu = (size_t)e*64 + u;
    size_t P  = (size_t)EA*64;
    MVp[eu]       = f2bf(gt*(R0*s0 + R3*p + R6*q));
    MVp[P + eu]   = f2bf(gt*(R1*s0 + R4*p + R7*q));
    MVp[2*P + eu] = f2bf(gt*(R2*s0 + R5*p + R8*q));
    As[(size_t)e*128 + u]      = f2bf(siluf_(m0));
    As[(size_t)e*128 + 64 + u] = f2bf(siluf_(m1));
}

// ---------------- fallback: fused edge kernel (round-3, plane-layout stores) ----------------
__launch_bounds__(256, 3)
__global__ void edge_kernel_fused(
    const float* __restrict__ latents,
    const float* __restrict__ ef_all,
    const int*   __restrict__ edge_index,
    const float* __restrict__ edge_vector,
    const int*   __restrict__ active_edges,
    const float* __restrict__ e_ws, const float* __restrict__ e_bs, const float* __restrict__ e_wv,
    const __bf16* __restrict__ Wt,
    const __bf16* __restrict__ w1rt,
    const __bf16* __restrict__ w1it,
    const float* __restrict__ env_w,
    const float* __restrict__ lp_ws, const float* __restrict__ lp_bs, const float* __restrict__ lp_wv,
    const float* __restrict__ ns, const float* __restrict__ nv,
    unsigned short* __restrict__ eout,
    int EA, int EF)
{
    __shared__ __align__(16) char smem[46592];
    char* sAbC = smem;
    char* sVFC = smem + 18432;
    float* sO  = (float*)smem;
    float* MV  = (float*)(smem + 16640);
    float* WE  = (float*)(smem + 33280);
    float* sR  = (float*)(smem + 45824);

    const int t = threadIdx.x;
    const int g = t >> 4, l = t & 15;
    const int e = blockIdx.x*16 + g;
    const bool act = (e < EA);

    int ct = 0, ae = 0;

    if (act) {
        ae = active_edges[e];
        ct = edge_index[ae];
        int nb = edge_index[EF + ae];
        float ex = edge_vector[(size_t)ae*3+0];
        float ey = edge_vector[(size_t)ae*3+1];
        float ez = edge_vector[(size_t)ae*3+2];
        float rn = rsqrtf(ex*ex+ey*ey+ez*ez + EPS_LN);
        float ax = ex*rn, ay = ey*rn, az = ez*rn;
        float rx, ry;
        if (fabsf(ax) < 0.9f) { rx = 1.0f; ry = 0.0f; } else { rx = 0.0f; ry = 1.0f; }
        float bx = -az*ry, by = az*rx, bz = ax*ry - ay*rx;
        float bn = rsqrtf(bx*bx+by*by+bz*bz + EPS_LN);
        bx*=bn; by*=bn; bz*=bn;
        float cx = ay*bz - az*by;
        float cy = az*bx - ax*bz;
        float cz = ax*by - ay*bx;
        if (l == 0){
            float* Rr = &sR[g*12];
            Rr[0]=ax; Rr[1]=ay; Rr[2]=az;
            Rr[3]=bx; Rr[4]=by; Rr[5]=bz;
            Rr[6]=cx; Rr[7]=cy; Rr[8]=cz;
        }
        {
            const float4* pc4 = (const float4*)(ns + (size_t)ct*128);
            const float4* pn4 = (const float4*)(ns + (size_t)nb*128);
            F4 a,b2,c,d;
            a.v = pc4[l]; b2.v = pc4[16+l]; c.v = pn4[l]; d.v = pn4[16+l];
            st_bf4(sAbC, g, 1152, l*4,       a.f[0],a.f[1],a.f[2],a.f[3]);
            st_bf4(sAbC, g, 1152, 64+l*4,    b2.f[0],b2.f[1],b2.f[2],b2.f[3]);
            st_bf4(sAbC, g, 1152, 256+l*4,   c.f[0],c.f[1],c.f[2],c.f[3]);
            st_bf4(sAbC, g, 1152, 320+l*4,   d.f[0],d.f[1],d.f[2],d.f[3]);
        }
        const float* ef = ef_all + (size_t)e*320;
        {
            F4 sa, sb;
            sa.v = *(const float4*)(ef + l*4);
            sb.v = *(const float4*)(ef + 64 + l*4);
            float sum=0.f, sq=0.f;
            #pragma unroll
            for (int i=0;i<4;i++){ sum += sa.f[i]+sb.f[i]; sq += sa.f[i]*sa.f[i]+sb.f[i]*sb.f[i]; }
            #pragma unroll
            for (int m=1;m<16;m<<=1){ sum += __shfl_xor(sum,m,64); sq += __shfl_xor(sq,m,64); }
            float mu = sum*(1.0f/128.0f);
            float rs = rsqrtf(sq*(1.0f/128.0f)-mu*mu + EPS_LN);
            float o0[4], o1[4];
            #pragma unroll
            for (int i=0;i<4;i++){
                int c0 = l*4+i, c1 = 64+l*4+i;
                o0[i] = (sa.f[i]-mu)*rs*e_ws[c0]+e_bs[c0];
                o1[i] = (sb.f[i]-mu)*rs*e_ws[c1]+e_bs[c1];
            }
            st_bf4(sAbC, g, 1152, 128+l*4, o0[0],o0[1],o0[2],o0[3]);
            st_bf4(sAbC, g, 1152, 192+l*4, o1[0],o1[1],o1[2],o1[3]);
        }
        {
            F4 va, vb, vc;
            va.v = *(const float4*)(ef + 128 + l*12);
            vb.v = *(const float4*)(ef + 128 + l*12 + 4);
            vc.v = *(const float4*)(ef + 128 + l*12 + 8);
            float vv[12];
            #pragma unroll
            for (int i=0;i<4;i++){ vv[i]=va.f[i]; vv[4+i]=vb.f[i]; vv[8+i]=vc.f[i]; }
            float sq=0.f;
            #pragma unroll
            for (int i=0;i<12;i++) sq += vv[i]*vv[i];
            #pragma unroll
            for (int m=1;m<16;m<<=1) sq += __shfl_xor(sq,m,64);
            float rv = rsqrtf(sq*(1.0f/192.0f) + EPS_LN);
            float f0[4], f1[4], f2[4];
            #pragma unroll
            for (int j=0;j<4;j++){
                int u = 4*l + j;
                float sc = rv * e_wv[u];
                float x = vv[3*j]*sc, y = vv[3*j+1]*sc, z = vv[3*j+2]*sc;
                f0[j] = ax*x+ay*y+az*z;
                f1[j] = bx*x+by*y+bz*z;
                f2[j] = cx*x+cy*y+cz*z;
            }
            st_bf4(sAbC, g, 1152, 384+64+4*l, f0[0],f0[1],f0[2],f0[3]);
            st_bf4(sVFC, g, 384, 64+4*l, f1[0],f1[1],f1[2],f1[3]);
            st_bf4(sVFC+6144, g, 384, 64+4*l, f2[0],f2[1],f2[2],f2[3]);
        }
        {
            const float* pv = nv + (size_t)ct*192 + l*12;
            F4 va, vb, vc;
            va.v = *(const float4*)(pv);
            vb.v = *(const float4*)(pv+4);
            vc.v = *(const float4*)(pv+8);
            float vv[12];
            #pragma unroll
            for (int i=0;i<4;i++){ vv[i]=va.f[i]; vv[4+i]=vb.f[i]; vv[8+i]=vc.f[i]; }
            float f0[4], f1[4], f2[4];
            #pragma unroll
            for (int j=0;j<4;j++){
                float x = vv[3*j], y = vv[3*j+1], z = vv[3*j+2];
                f0[j] = ax*x+ay*y+az*z;
                f1[j] = bx*x+by*y+bz*z;
                f2[j] = cx*x+cy*y+cz*z;
            }
            st_bf4(sAbC, g, 1152, 384+4*l, f0[0],f0[1],f0[2],f0[3]);
            st_bf4(sVFC, g, 384, 4*l, f1[0],f1[1],f1[2],f1[3]);
            st_bf4(sVFC+6144, g, 384, 4*l, f2[0],f2[1],f2[2],f2[3]);
        }
        {
            const float* pv = nv + (size_t)nb*192 + l*12;
            F4 va, vb, vc;
            va.v = *(const float4*)(pv);
            vb.v = *(const float4*)(pv+4);
            vc.v = *(const float4*)(pv+8);
            float vv[12];
            #pragma unroll
            for (int i=0;i<4;i++){ vv[i]=va.f[i]; vv[4+i]=vb.f[i]; vv[8+i]=vc.f[i]; }
            float f0[4], f1[4], f2[4];
            #pragma unroll
            for (int j=0;j<4;j++){
                float x = vv[3*j], y = vv[3*j+1], z = vv[3*j+2];
                f0[j] = ax*x+ay*y+az*z;
                f1[j] = bx*x+by*y+bz*z;
                f2[j] = cx*x+cy*y+cz*z;
            }
            st_bf4(sAbC, g, 1152, 384+128+4*l, f0[0],f0[1],f0[2],f0[3]);
            st_bf4(sVFC, g, 384, 128+4*l, f1[0],f1[1],f1[2],f1[3]);
            st_bf4(sVFC+6144, g, 384, 128+4*l, f2[0],f2[1],f2[2],f2[3]);
        }
    }
    __syncthreads();

    const int w  = t >> 6;
    const int ln = t & 63;
    const int cc = ln & 15;
    const int gq = ln >> 4;

    f32x4 accM[4] = {{0,0,0,0},{0,0,0,0},{0,0,0,0},{0,0,0,0}};
    {
        const __bf16* wb0 = Wt + (size_t)(64*w + 0  + cc)*576;
        const __bf16* wb1 = Wt + (size_t)(64*w + 16 + cc)*576;
        const __bf16* wb2 = Wt + (size_t)(64*w + 32 + cc)*576;
        const __bf16* wb3 = Wt + (size_t)(64*w + 48 + cc)*576;
        for (int ks=0; ks<18; ks++){
            bf16x8 a = ld_frag(sAbC, cc, 1152, ks*64 + 16*gq);
            int ko = ks*32 + 8*gq;
            bf16x8 b0 = *(const bf16x8*)(wb0 + ko);
            bf16x8 b1 = *(const bf16x8*)(wb1 + ko);
            bf16x8 b2 = *(const bf16x8*)(wb2 + ko);
            bf16x8 b3 = *(const bf16x8*)(wb3 + ko);
            accM[0] = __builtin_amdgcn_mfma_f32_16x16x32_bf16(a, b0, accM[0], 0,0,0);
            accM[1] = __builtin_amdgcn_mfma_f32_16x16x32_bf16(a, b1, accM[1], 0,0,0);
            accM[2] = __builtin_amdgcn_mfma_f32_16x16x32_bf16(a, b2, accM[2], 0,0,0);
            accM[3] = __builtin_amdgcn_mfma_f32_16x16x32_bf16(a, b3, accM[3], 0,0,0);
        }
    }
    f32x4 aP1={0,0,0,0}, aP2={0,0,0,0}, aM1={0,0,0,0}, aM2={0,0,0,0};
    {
        const __bf16* wr = w1rt + (size_t)(16*w + cc)*192;
        const __bf16* wi = w1it + (size_t)(16*w + cc)*192;
        for (int ks=0; ks<6; ks++){
            bf16x8 a1 = ld_frag(sVFC,        cc, 384, ks*64 + 16*gq);
            bf16x8 a2 = ld_frag(sVFC + 6144, cc, 384, ks*64 + 16*gq);
            int ko = ks*32 + 8*gq;
            bf16x8 br = *(const bf16x8*)(wr + ko);
            bf16x8 bi = *(const bf16x8*)(wi + ko);
            aP1 = __builtin_amdgcn_mfma_f32_16x16x32_bf16(a1, br, aP1, 0,0,0);
            aP2 = __builtin_amdgcn_mfma_f32_16x16x32_bf16(a2, bi, aP2, 0,0,0);
            aM1 = __builtin_amdgcn_mfma_f32_16x16x32_bf16(a1, bi, aM1, 0,0,0);
            aM2 = __builtin_amdgcn_mfma_f32_16x16x32_bf16(a2, br, aM2, 0,0,0);
        }
    }
    __syncthreads();

    {
        const float rn0 = 0.0416666666667f;
        #pragma unroll
        for (int jt=0;jt<4;jt++){
            #pragma unroll
            for (int j=0;j<4;j++){
                sO[(gq*4+j)*260 + 64*w + 16*jt + cc] = accM[jt][j]*rn0;
            }
        }
    }
    float vp[4], vm[4];
    {
        const float n1 = 0.0721687836487f;
        #pragma unroll
        for (int j=0;j<4;j++){ vp[j] = (aP1[j]-aP2[j])*n1; vm[j] = (aM1[j]+aM2[j])*n1; }
    }
    __syncthreads();

    {
        int u = w*16 + cc;
        #pragma unroll
        for (int j=0;j<4;j++){
            int er = gq*4 + j;
            if (blockIdx.x*16 + er < EA){
                const float* Rr = &sR[er*12];
                float s0 = sO[er*260 + 192 + u];
                float gt = sigmoidf_(sO[er*260 + 128 + u]);
                float p = vp[j], q = vm[j];
                float4 o;
                o.x = gt*(Rr[0]*s0 + Rr[3]*p + Rr[6]*q);
                o.y = gt*(Rr[1]*s0 + Rr[4]*p + Rr[7]*q);
                o.z = gt*(Rr[2]*s0 + Rr[5]*p + Rr[8]*q);
                o.w = 0.0f;
                *(float4*)&MV[er*260 + u*4] = o;
            }
        }
    }
    if (act) {
        {
            int i0 = l*8;
            F4 oa, ob;
            oa.v = *(const float4*)&sO[g*260 + i0];
            ob.v = *(const float4*)&sO[g*260 + i0 + 4];
            #pragma unroll
            for (int i=0;i<4;i++){ oa.f[i] = siluf_(oa.f[i]); ob.f[i] = siluf_(ob.f[i]); }
            *(float4*)&sO[g*260 + i0]     = oa.v;
            *(float4*)&sO[g*260 + i0 + 4] = ob.v;
        }
        {
            const int cc2 = l*12;
            float wacc[12];
            #pragma unroll
            for (int i=0;i<12;i++) wacc[i]=0.f;
            const float* lat = latents + (size_t)ae*128;
            for (int k=0;k<128;k+=4){
                F4 la;
                la.v = *(const float4*)(lat + k);
                #pragma unroll
                for (int kk=0;kk<4;kk++){
                    const float* er_ = env_w + (size_t)(k+kk)*192 + cc2;
                    F4 e0v,e1v,e2v;
                    e0v.v = *(const float4*)(er_);
                    e1v.v = *(const float4*)(er_+4);
                    e2v.v = *(const float4*)(er_+8);
                    #pragma unroll
                    for (int i=0;i<4;i++){
                        wacc[i]   += la.f[kk]*e0v.f[i];
                        wacc[4+i] += la.f[kk]*e1v.f[i];
                        wacc[8+i] += la.f[kk]*e2v.f[i];
                    }
                }
            }
            const float inv128 = 0.0883883476483f;
            #pragma unroll
            for (int i=0;i<12;i++) WE[g*196 + cc2 + i] = wacc[i]*inv128;
        }
    }
    __syncthreads();

    if (act) {
        const float inv_avg = 0.288675134595f;
        unsigned short* orow = eout + (size_t)e*320;
        {
            int c0 = l*8;
            float a8[8];
            #pragma unroll
            for (int i=0;i<8;i++) a8[i]=0.f;
            for (int k=0;k<128;k+=4){
                F4 av;
                av.v = *(const float4*)&sO[g*260 + k];
                #pragma unroll
                for (int kk=0;kk<4;kk++){
                    const float* wr = lp_ws + (size_t)(k+kk)*128 + c0;
                    F4 w0, w1_;
                    w0.v  = *(const float4*)(wr);
                    w1_.v = *(const float4*)(wr+4);
                    #pragma unroll
                    for (int i=0;i<4;i++){ a8[i] += av.f[kk]*w0.f[i]; a8[4+i] += av.f[kk]*w1_.f[i]; }
                }
            }
            const float s128 = 0.0883883476483f;
            union { unsigned short h[8]; uint4 u; } ps;
            #pragma unroll
            for (int i=0;i<8;i++){
                int c = c0+i;
                ps.h[i] = f2bf((a8[i]*s128 + lp_bs[c]) * WE[g*196 + c] * inv_avg);
            }
            *(uint4*)(orow + c0) = ps.u;
        }
        {
            int k0 = l*4;
            float av[4][3];
            #pragma unroll
            for (int j=0;j<4;j++)
                #pragma unroll
                for (int m2=0;m2<3;m2++) av[j][m2]=0.f;
            for (int u=0;u<64;u++){
                F4 wv4, mv4;
                wv4.v = *(const float4*)(lp_wv + (size_t)u*64 + k0);
                mv4.v = *(const float4*)&MV[g*260 + u*4];
                #pragma unroll
                for (int j=0;j<4;j++){
                    av[j][0] += wv4.f[j]*mv4.f[0];
                    av[j][1] += wv4.f[j]*mv4.f[1];
                    av[j][2] += wv4.f[j]*mv4.f[2];
                }
            }
            #pragma unroll
            for (int j=0;j<4;j++){
                int k = k0+j;
                float wk = WE[g*196 + 128 + k] * 0.125f * inv_avg;
                orow[128 +       k] = f2bf(av[j][0]*wk);
                orow[128 + 64  + k] = f2bf(av[j][1]*wk);
                orow[128 + 128 + k] = f2bf(av[j][2]*wk);
            }
        }
    }
}

// ---------------- node CSR aggregate + onehot path + output (ILP-restructured) ----------------
__global__ void node_out_kernel(
    const float* __restrict__ nf,
    const int* __restrict__ atom_type,
    const int* __restrict__ offs, const int* __restrict__ elist,
    const unsigned short* __restrict__ eout,
    const __bf16* __restrict__ ssT, const __bf16* __restrict__ sgT, const __bf16* __restrict__ vvT,
    const float* __restrict__ ohl_ws, const float* __restrict__ ohl_bs, const float* __restrict__ ohl_wv,
    const float* __restrict__ res_param,
    float* __restrict__ out, int N)
{
    __shared__ int   sE[64];
    __shared__ float AGS[128];
    __shared__ float AGV[192];
    __shared__ float TSs[128];
    __shared__ float SG[64];
    __shared__ float TV[192];
    const int n = blockIdx.x;
    const int t = threadIdx.x;
    const int at = atom_type[n];
    const int lo = offs[n], hi = offs[n+1];

    // gather-aggregate: threads 0..159 own cols {2t, 2t+1}; 4-stream ILP
    float aLo = 0.f, aHi = 0.f;
    for (int base = lo; base < hi; base += 64){
        int cnt = hi - base; if (cnt > 64) cnt = 64;
        __syncthreads();
        if (t < cnt) sE[t] = elist[base + t];
        __syncthreads();
        if (t < 160){
            int i = 0;
            for (; i+4 <= cnt; i += 4){
                unsigned x0 = *(const unsigned*)(eout + (size_t)sE[i  ]*320 + 2*t);
                unsigned x1 = *(const unsigned*)(eout + (size_t)sE[i+1]*320 + 2*t);
                unsigned x2 = *(const unsigned*)(eout + (size_t)sE[i+2]*320 + 2*t);
                unsigned x3 = *(const unsigned*)(eout + (size_t)sE[i+3]*320 + 2*t);
                aLo += bf2f((unsigned short)x0) + bf2f((unsigned short)x1)
                     + bf2f((unsigned short)x2) + bf2f((unsigned short)x3);
                aHi += bf2f((unsigned short)(x0>>16)) + bf2f((unsigned short)(x1>>16))
                     + bf2f((unsigned short)(x2>>16)) + bf2f((unsigned short)(x3>>16));
            }
            for (; i < cnt; i++){
                unsigned x = *(const unsigned*)(eout + (size_t)sE[i]*320 + 2*t);
                aLo += bf2f((unsigned short)x);
                aHi += bf2f((unsigned short)(x>>16));
            }
        }
    }
    if (t < 160){
        int c0 = 2*t, c1 = 2*t+1;
        if (c0 < 128) AGS[c0] = aLo; else { int d=c0-128; AGV[(d&63)*3 + (d>>6)] = aLo; }
        if (c1 < 128) AGS[c1] = aHi; else { int d=c1-128; AGV[(d&63)*3 + (d>>6)] = aHi; }
    }
    __syncthreads();
    const float n_ss = 0.0110485434560f;
    const float n_vv = 0.015625f;
    if (t < 128) {
        const __bf16* w = ssT + (size_t)at*16384 + t;
        float acc = 0.0f;
        #pragma unroll 8
        for (int u=0;u<128;u++) acc += AGS[u]*(float)w[(size_t)u*128];
        TSs[t] = siluf_(acc*n_ss);
    } else if (t < 192) {
        int k = t-128;
        const __bf16* w = sgT + (size_t)at*8192 + k;
        float acc = 0.0f;
        #pragma unroll 8
        for (int u=0;u<128;u++) acc += AGS[u]*(float)w[(size_t)u*64];
        SG[k] = sigmoidf_(acc*n_ss);
    } else {
        int k = t-192;
        const __bf16* w = vvT + (size_t)at*4096 + k;
        float a0=0,a1=0,a2=0;
        #pragma unroll 8
        for (int u=0;u<64;u++){
            float wv = (float)w[(size_t)u*64];
            a0 += AGV[u*3+0]*wv;
            a1 += AGV[u*3+1]*wv;
            a2 += AGV[u*3+2]*wv;
        }
        TV[k*3+0]=a0*n_vv; TV[k*3+1]=a1*n_vv; TV[k*3+2]=a2*n_vv;
    }
    __syncthreads();
    const float alpha = sigmoidf_(res_param[0]);
    const float beta  = 1.0f - alpha;
    if (t < 128) {
        float acc = 0.0f;
        #pragma unroll 8
        for (int k=0;k<128;k++) acc += TSs[k]*ohl_ws[(size_t)k*128 + t];
        float val = acc*0.0883883476483f + ohl_bs[t];
        out[(size_t)n*320 + t] = alpha*nf[(size_t)n*320 + t] + beta*val;
    } else if (t >= 192) {
        int k = t-192;
        float a0=0,a1=0,a2=0;
        #pragma unroll 8
        for (int u=0;u<64;u++){
            float w = ohl_wv[(size_t)u*64 + k]*SG[u];
            a0 += TV[u*3+0]*w; a1 += TV[u*3+1]*w; a2 += TV[u*3+2]*w;
        }
        size_t base = (size_t)n*320 + 128 + (size_t)k*3;
        out[base+0] = alpha*nf[base+0] + beta*(a0*0.125f);
        out[base+1] = alpha*nf[base+1] + beta*(a1*0.125f);
        out[base+2] = alpha*nf[base+2] + beta*(a2*0.125f);
    }
}

extern "C" void kernel_launch(void* const* d_in, const int* in_sizes, int n_in,
                              void* d_out, int out_size, void* d_ws, size_t ws_size,
                              hipStream_t stream)
{
    const float* latents       = (const float*)d_in[0];
    const float* node_features = (const float*)d_in[1];
    const float* edge_features = (const float*)d_in[2];
    const int*   atom_type     = (const int*)d_in[3];
    const int*   edge_index    = (const int*)d_in[5];
    const float* edge_vector   = (const float*)d_in[6];
    const int*   active_edges  = (const int*)d_in[7];
    const float* sln_n_ws = (const float*)d_in[8];
    const float* sln_n_bs = (const float*)d_in[9];
    const float* sln_n_wv = (const float*)d_in[10];
    const float* sln_e_ws = (const float*)d_in[11];
    const float* sln_e_bs = (const float*)d_in[12];
    const float* sln_e_wv = (const float*)d_in[13];
    const float* so2_w0   = (const float*)d_in[14];
    const float* so2_w1r  = (const float*)d_in[15];
    const float* so2_w1i  = (const float*)d_in[16];
    const float* env_w    = (const float*)d_in[17];
    const float* lp_ws    = (const float*)d_in[18];
    const float* lp_bs    = (const float*)d_in[19];
    const float* lp_wv    = (const float*)d_in[20];
    const float* oh_w_ss  = (const float*)d_in[21];
    const float* oh_w_sg  = (const float*)d_in[22];
    const float* oh_w_vv  = (const float*)d_in[23];
    const float* ohl_ws   = (const float*)d_in[24];
    const float* ohl_bs   = (const float*)d_in[25];
    const float* ohl_wv   = (const float*)d_in[26];
    const float* res_param= (const float*)d_in[27];
    float* out = (float*)d_out;

    const int N  = in_sizes[1] / 320;
    const int EF = in_sizes[5] / 2;
    const int EA = in_sizes[7];

    // workspace layout (256B-aligned chunks)
    char* p = (char*)d_ws;
    auto alloc = [&](size_t bytes) -> char* {
        char* r = p; p += (bytes + 255) & ~(size_t)255; return r;
    };
    float* ns      = (float*)alloc((size_t)N*128*4);
    float* nv      = (float*)alloc((size_t)N*192*4);
    __bf16* nsb    = (__bf16*)alloc((size_t)N*128*2);
    int*   cnt     = (int*)  alloc((size_t)N*4);
    int*   offs    = (int*)  alloc(((size_t)N+1)*4);
    int*   cursor  = (int*)  alloc((size_t)N*4);
    int*   elist   = (int*)  alloc((size_t)EA*4);
    __bf16* Wt     = (__bf16*)alloc((size_t)576*256*2);
    __bf16* w1rt   = (__bf16*)alloc((size_t)64*192*2);
    __bf16* w1it   = (__bf16*)alloc((size_t)64*192*2);
    __bf16* Wevfm  = (__bf16*)alloc((size_t)256*320*2);
    __bf16* Bnodefm= (__bf16*)alloc((size_t)512*128*2);
    __bf16* Bvfm   = (__bf16*)alloc((size_t)128*384*2);
    __bf16* envfm  = (__bf16*)alloc((size_t)192*128*2);
    __bf16* lpsfm  = (__bf16*)alloc((size_t)128*128*2);
    __bf16* lpvfm  = (__bf16*)alloc((size_t)64*64*2);
    __bf16* ssT    = (__bf16*)alloc((size_t)64*128*128*2);
    __bf16* sgT    = (__bf16*)alloc((size_t)64*128*64*2);
    __bf16* vvT    = (__bf16*)alloc((size_t)64*64*64*2);
    __bf16* nodeCN = (__bf16*)alloc((size_t)N*512*2);
    int2*  ctnb    = (int2*) alloc((size_t)EA*8);
    unsigned short* eout = (unsigned short*)alloc((size_t)EA*320*2);
    unsigned short* w_env= (unsigned short*)alloc((size_t)EA*192*2);
    float*  Rg    = (float*) alloc((size_t)EA*12*4);
    __bf16* m0in  = (__bf16*)alloc((size_t)EA*320*2);
    __bf16* vfg   = (__bf16*)alloc((size_t)EA*384*2);
    size_t split_need = (size_t)(p - (char*)d_ws);
    const bool use_split = (split_need <= ws_size);

    // aliases (split path only; all uses are stream-ordered)
    unsigned short* vpvm  = eout;                   // [EA][128], consumed by mid before eout written
    unsigned short* m0out = (unsigned short*)vfg;   // [EA][256], written after vfg consumed
    unsigned short* As    = (unsigned short*)m0in;  // [EA][128], after m0in consumed
    unsigned short* MVp   = As + (size_t)EA*128;    // 3 planes [EA][64]; 128+192=320 fits m0in width

    hipMemsetAsync(cnt, 0, (size_t)N*sizeof(int), stream);
    prep_all<<<4096, 256, 0, stream>>>(so2_w0, so2_w1r, so2_w1i, env_w, lp_ws, lp_wv,
                                       oh_w_ss, oh_w_sg, oh_w_vv,
                                       Wt, w1rt, w1it, Wevfm, Bnodefm, Bvfm,
                                       envfm, lpsfm, lpvfm, ssT, sgT, vvT);
    node_ln_kernel<<<(N+3)/4, 256, 0, stream>>>(node_features, sln_n_ws, sln_n_bs, sln_n_wv, ns, nv, nsb, N);
    csr_count<<<(EA+255)/256, 256, 0, stream>>>(edge_index, active_edges, cnt, EA);
    csr_scan<<<1, 256, 0, stream>>>(cnt, offs, cursor, N);
    csr_fill<<<(EA+255)/256, 256, 0, stream>>>(edge_index, active_edges, cursor, elist, EA);

    const float rn0    = 0.0416666666667f;   // 1/sqrt(576)
    const float n1     = 0.0721687836487f;   // 1/sqrt(192)
    const float inv128 = 0.0883883476483f;   // 1/sqrt(128)

    if (use_split){
        const int NB64  = (EA + 63) / 64;
        const int NB128 = (EA + 127) / 128;
        const int NBn   = (N + 63) / 64;
        // node-side contributions: nsb[N][128] x [512 cols] -> nodeCN[N][512] (raw scale)
        gemm_k<512,128,1,EPI_PLAIN,false><<<dim3(NBn,1), 512, 0, stream>>>(
            nsb, nullptr, nullptr, Bnodefm, (unsigned short*)nodeCN, nullptr, nullptr, 1.0f, N);
        stage_kernel<<<(EA+15)/16, 256, 0, stream>>>(edge_features, edge_index, edge_vector, active_edges,
            sln_e_ws, sln_e_bs, sln_e_wv, nv, m0in, vfg, Rg, ctnb, EA, EF);
        // vp/vm: [EA][384] x Bv -> vpvm[EA][128]  (before main so vfg dead when m0out overlays)
        gemm_k<128,384,2,EPI_PLAIN,false><<<dim3(NB128,1), 256, 0, stream>>>(
            vfg, nullptr, nullptr, Bvfm, vpvm, nullptr, nullptr, n1, EA);
        // main: [EA][320] x Wev -> m0out[EA][256] (partial; node terms added in mid)
        gemm_k<256,320,1,EPI_PLAIN,false><<<dim3(NB64,1), 256, 0, stream>>>(
            m0in, nullptr, nullptr, Wevfm, m0out, nullptr, nullptr, rn0, EA);
        // nodeCN gather-add + gate + rotate-back + silu
        mid_kernel<<<(EA*64+255)/256, 256, 0, stream>>>(m0out, vpvm, Rg, ctnb, nodeCN, As, MVp, EA);
        gemm_k<192,128,1,EPI_PLAIN,true><<<dim3(NB64,1), 192, 0, stream>>>(
            nullptr, latents, active_edges, envfm, w_env, nullptr, nullptr, inv128, EA);
        gemm_k<128,128,2,EPI_LPS,false><<<dim3(NB128,1), 256, 0, stream>>>(
            (const __bf16*)As, nullptr, nullptr, lpsfm, eout, w_env, lp_bs, inv128, EA);
        gemm_k<64,64,2,EPI_LPV,false><<<dim3(NB128,3), 128, 0, stream>>>(
            (const __bf16*)MVp, nullptr, nullptr, lpvfm, eout, w_env, nullptr, 0.125f, EA);
    } else {
        edge_kernel_fused<<<(EA+15)/16, 256, 0, stream>>>(latents, edge_features, edge_index, edge_vector, active_edges,
            sln_e_ws, sln_e_bs, sln_e_wv, Wt, w1rt, w1it, env_w, lp_ws, lp_bs, lp_wv,
            ns, nv, eout, EA, EF);
    }
    node_out_kernel<<<N, 256, 0, stream>>>(node_features, atom_type, offs, elist, eout,
        ssT, sgT, vvT, ohl_ws, ohl_bs, ohl_wv, res_param, out, N);
}

// Round 10
// 447.749 us; speedup vs baseline: 1.1704x; 1.0390x over previous
//
#include <hip/hip_runtime.h>

#define EPS_LN 1e-8f

typedef __bf16 bf16x8 __attribute__((ext_vector_type(8)));
typedef float  f32x4  __attribute__((ext_vector_type(4)));

__device__ __forceinline__ float sigmoidf_(float x){ return 1.0f/(1.0f+__expf(-x)); }
__device__ __forceinline__ float siluf_(float x){ return x*sigmoidf_(x); }
__device__ __forceinline__ unsigned short f2bf(float x){ union{ __bf16 b; unsigned short u;} c; c.b = (__bf16)x; return c.u; }
__device__ __forceinline__ float bf2f(unsigned short u){ return __uint_as_float(((unsigned)u)<<16); }

union F4 { float4 v; float f[4]; };

// swizzled bf16 LDS store (fused fallback path)
__device__ __forceinline__ void st_bf4(char* base, int row, int stride_bytes, int k,
                                       float x0, float x1, float x2, float x3){
    union { __bf16 h[4]; unsigned long long u; } p;
    p.h[0]=(__bf16)x0; p.h[1]=(__bf16)x1; p.h[2]=(__bf16)x2; p.h[3]=(__bf16)x3;
    *(unsigned long long*)(base + row*stride_bytes + ((2*k) ^ ((row&7)<<4))) = p.u;
}
__device__ __forceinline__ bf16x8 ld_frag(const char* base, int row, int stride_bytes, int kbyte){
    return *(const bf16x8*)(base + row*stride_bytes + (kbyte ^ ((row&7)<<4)));
}
__device__ __forceinline__ void st_g4(__bf16* p, float x0, float x1, float x2, float x3){
    union { __bf16 h[4]; unsigned long long u; } pk;
    pk.h[0]=(__bf16)x0; pk.h[1]=(__bf16)x1; pk.h[2]=(__bf16)x2; pk.h[3]=(__bf16)x3;
    *(unsigned long long*)p = pk.u;
}
__device__ __forceinline__ uint4 pack8(float4 a, float4 b){
    union { __bf16 h[8]; uint4 u; } p;
    p.h[0]=(__bf16)a.x; p.h[1]=(__bf16)a.y; p.h[2]=(__bf16)a.z; p.h[3]=(__bf16)a.w;
    p.h[4]=(__bf16)b.x; p.h[5]=(__bf16)b.y; p.h[6]=(__bf16)b.z; p.h[7]=(__bf16)b.w;
    return p.u;
}
// fragment-major dest index for B[n][k] tiles (16 cols x 32 k per fragment)
__device__ __forceinline__ int fm_idx(int n, int k, int NKT){
    return ((n>>4)*NKT + (k>>5))*512 + ((k>>3)&3)*128 + (n&15)*8 + (k&7);
}

// ---------------- weight prep (all packs in one kernel) ----------------
__global__ void prep_all(const float* __restrict__ w0,
                         const float* __restrict__ w1r, const float* __restrict__ w1i,
                         const float* __restrict__ env_w, const float* __restrict__ lp_ws,
                         const float* __restrict__ lp_wv,
                         const float* __restrict__ oh_ss, const float* __restrict__ oh_sg,
                         const float* __restrict__ oh_vv,
                         __bf16* __restrict__ Wt, __bf16* __restrict__ w1rt, __bf16* __restrict__ w1it,
                         __bf16* __restrict__ Wevfm, __bf16* __restrict__ Bnodefm,
                         __bf16* __restrict__ Bvfm,
                         __bf16* __restrict__ envfm, __bf16* __restrict__ lpsfm,
                         __bf16* __restrict__ lpvfm,
                         __bf16* __restrict__ ssT, __bf16* __restrict__ sgT, __bf16* __restrict__ vvT)
{
    int t = blockIdx.x*256 + threadIdx.x;
    if (t < 576*256){                          // fallback row-major Wt[256][576]
        int n = t/576, k = t%576;
        Wt[t] = (__bf16)w0[(size_t)k*256 + n];
    }
    if (t < 256*320){                          // edge GEMM weights: rows {128..255}U{384..575}
        int n = t/320, k = t%320;
        int src = (k<128) ? (128+k) : (384+(k-128));
        Wevfm[fm_idx(n,k,10)] = (__bf16)w0[(size_t)src*256 + n];
    }
    if (t < 512*128){                          // node GEMM: cols 0..255 = W rows 0..127; 256..511 = rows 256..383
        int n = t/128, k = t%128;
        float v = (n<256) ? w0[(size_t)k*256 + n] : w0[(size_t)(256+k)*256 + (n-256)];
        Bnodefm[fm_idx(n,k,4)] = (__bf16)v;
    }
    if (t < 64*192){
        int c = t/192, k = t%192;
        w1rt[t] = (__bf16)w1r[(size_t)k*64 + c];
        w1it[t] = (__bf16)w1i[(size_t)k*64 + c];
    }
    if (t < 128*384){
        int n = t/384, k = t%384;
        float v;
        if (n < 64) v = (k<192) ? w1r[(size_t)k*64+n] : -w1i[(size_t)(k-192)*64+n];
        else        v = (k<192) ? w1i[(size_t)k*64+(n-64)] : w1r[(size_t)(k-192)*64+(n-64)];
        Bvfm[fm_idx(n,k,12)] = (__bf16)v;
    }
    if (t < 192*128){ int n=t/128, k=t%128; envfm[fm_idx(n,k,4)] = (__bf16)env_w[(size_t)k*192+n]; }
    if (t < 128*128){ int n=t/128, k=t%128; lpsfm[fm_idx(n,k,4)] = (__bf16)lp_ws[(size_t)k*128+n]; }
    if (t < 64*64)  { int n=t/64,  k=t%64;  lpvfm[fm_idx(n,k,2)] = (__bf16)lp_wv[(size_t)k*64+n]; }
    if (t < 64*128*128){                       // ssT[at][u][k]
        int at = t / 16384; int r = t & 16383; int u = r >> 7, k = r & 127;
        ssT[t] = (__bf16)oh_ss[((size_t)u*64 + at)*128 + k];
    }
    if (t < 64*128*64){                        // sgT[at][u][k]
        int at = t / 8192; int r = t & 8191; int u = r >> 6, k = r & 63;
        sgT[t] = (__bf16)oh_sg[((size_t)u*64 + at)*64 + k];
    }
    if (t < 64*64*64){                         // vvT[at][u][k]
        int at = t / 4096; int r = t & 4095; int u = r >> 6, k = r & 63;
        vvT[t] = (__bf16)oh_vv[((size_t)u*64 + at)*64 + k];
    }
}

// ---------------- CSR build ----------------
__global__ void csr_count(const int* __restrict__ ei, const int* __restrict__ act,
                          int* __restrict__ cnt, int EA)
{
    int e = blockIdx.x*256 + threadIdx.x;
    if (e < EA) atomicAdd(&cnt[ei[act[e]]], 1);
}
__global__ void csr_scan(const int* __restrict__ cnt, int* __restrict__ offs,
                         int* __restrict__ cursor, int N)
{
    __shared__ int part[256];
    int t = threadIdx.x;
    int chunk = (N + 255) / 256;
    int lo = t*chunk, hi = lo+chunk; if (hi > N) hi = N; if (lo > N) lo = N;
    int s = 0;
    for (int i=lo;i<hi;i++) s += cnt[i];
    part[t] = s;
    __syncthreads();
    for (int d=1; d<256; d<<=1){
        int v = (t>=d) ? part[t-d] : 0;
        __syncthreads();
        part[t] += v;
        __syncthreads();
    }
    int run = (t==0) ? 0 : part[t-1];
    for (int i=lo;i<hi;i++){
        offs[i] = run; cursor[i] = run;
        run += cnt[i];
    }
    if (t==255) offs[N] = part[255];
}
__global__ void csr_fill(const int* __restrict__ ei, const int* __restrict__ act,
                         int* __restrict__ cursor, int* __restrict__ elist, int EA)
{
    int e = blockIdx.x*256 + threadIdx.x;
    if (e < EA){
        int n = ei[act[e]];
        int p = atomicAdd(&cursor[n], 1);
        elist[p] = e;
    }
}

// ---------------- node separable layernorm (+ bf16 scalar copy for node GEMM) ----------------
__global__ void node_ln_kernel(const float* __restrict__ nf,
                               const float* __restrict__ ws, const float* __restrict__ bs,
                               const float* __restrict__ wv,
                               float* __restrict__ ns, float* __restrict__ nv,
                               __bf16* __restrict__ nsb, int N)
{
    int t = threadIdx.x;
    int lane = t & 63;
    int n = blockIdx.x*4 + (t>>6);
    if (n >= N) return;
    const float* row = nf + (size_t)n*320;
    float s0 = row[lane], s1 = row[64+lane];
    float sum = s0+s1, sq = s0*s0+s1*s1;
    #pragma unroll
    for (int m=1;m<64;m<<=1){ sum += __shfl_xor(sum,m,64); sq += __shfl_xor(sq,m,64); }
    float mu = sum*(1.0f/128.0f);
    float rs = rsqrtf(sq*(1.0f/128.0f) - mu*mu + EPS_LN);
    float o0 = (s0-mu)*rs*ws[lane]    + bs[lane];
    float o1 = (s1-mu)*rs*ws[64+lane] + bs[64+lane];
    ns[(size_t)n*128+lane]    = o0;
    ns[(size_t)n*128+64+lane] = o1;
    nsb[(size_t)n*128+lane]    = (__bf16)o0;
    nsb[(size_t)n*128+64+lane] = (__bf16)o1;
    float v0 = row[128+lane], v1 = row[192+lane], v2 = row[256+lane];
    float vs = v0*v0+v1*v1+v2*v2;
    #pragma unroll
    for (int m=1;m<64;m<<=1) vs += __shfl_xor(vs,m,64);
    float rv = rsqrtf(vs*(1.0f/192.0f) + EPS_LN);
    nv[(size_t)n*192+lane]     = v0*rv*wv[lane/3];
    nv[(size_t)n*192+64+lane]  = v1*rv*wv[(64+lane)/3];
    nv[(size_t)n*192+128+lane] = v2*rv*wv[(128+lane)/3];
}

// ---------------- per-edge staging -> global bf16 (no node-scalar copies) ----------------
__global__ void stage_kernel(
    const float* __restrict__ ef_all,
    const int*   __restrict__ edge_index,
    const float* __restrict__ edge_vector,
    const int*   __restrict__ active_edges,
    const float* __restrict__ e_ws, const float* __restrict__ e_bs, const float* __restrict__ e_wv,
    const float* __restrict__ nv,
    __bf16* __restrict__ m0in,   // [EA][320]: [es(128) | vf0(192)]
    __bf16* __restrict__ vfg,    // [EA][384]: [vf1(192) | vf2(192)]
    float* __restrict__ Rg, int2* __restrict__ ctnb,
    int EA, int EF)
{
    int tid = blockIdx.x*256 + threadIdx.x;
    int e = tid >> 4, l = tid & 15;
    if (e >= EA) return;
    int ae = active_edges[e];
    int ct = edge_index[ae];
    int nb = edge_index[EF + ae];
    float ex = edge_vector[(size_t)ae*3+0];
    float ey = edge_vector[(size_t)ae*3+1];
    float ez = edge_vector[(size_t)ae*3+2];
    float rn = rsqrtf(ex*ex+ey*ey+ez*ez + EPS_LN);
    float ax = ex*rn, ay = ey*rn, az = ez*rn;
    float rx, ry;
    if (fabsf(ax) < 0.9f) { rx = 1.0f; ry = 0.0f; } else { rx = 0.0f; ry = 1.0f; }
    float bx = -az*ry, by = az*rx, bz = ax*ry - ay*rx;
    float bn = rsqrtf(bx*bx+by*by+bz*bz + EPS_LN);
    bx*=bn; by*=bn; bz*=bn;
    float cx = ay*bz - az*by;
    float cy = az*bx - ax*bz;
    float cz = ax*by - ay*bx;
    if (l == 0){
        float* Rr = Rg + (size_t)e*12;
        *(float4*)(Rr)   = make_float4(ax,ay,az,bx);
        *(float4*)(Rr+4) = make_float4(by,bz,cx,cy);
        *(float4*)(Rr+8) = make_float4(cz,0.f,0.f,0.f);
        ctnb[e] = make_int2(ct, nb);
    }
    __bf16* Arow = m0in + (size_t)e*320;
    __bf16* V1r  = vfg + (size_t)e*384;
    __bf16* V2r  = V1r + 192;
    const float* ef = ef_all + (size_t)e*320;
    {   // edge scalar LN -> Arow[0:128)
        F4 sa, sb;
        sa.v = *(const float4*)(ef + l*4);
        sb.v = *(const float4*)(ef + 64 + l*4);
        float sum=0.f, sq=0.f;
        #pragma unroll
        for (int i=0;i<4;i++){ sum += sa.f[i]+sb.f[i]; sq += sa.f[i]*sa.f[i]+sb.f[i]*sb.f[i]; }
        #pragma unroll
        for (int m=1;m<16;m<<=1){ sum += __shfl_xor(sum,m,64); sq += __shfl_xor(sq,m,64); }
        float mu = sum*(1.0f/128.0f);
        float rs = rsqrtf(sq*(1.0f/128.0f)-mu*mu + EPS_LN);
        float o0[4], o1[4];
        #pragma unroll
        for (int i=0;i<4;i++){
            int c0 = l*4+i, c1 = 64+l*4+i;
            o0[i] = (sa.f[i]-mu)*rs*e_ws[c0]+e_bs[c0];
            o1[i] = (sb.f[i]-mu)*rs*e_ws[c1]+e_bs[c1];
        }
        st_g4(Arow + l*4,      o0[0],o0[1],o0[2],o0[3]);
        st_g4(Arow + 64 + l*4, o1[0],o1[1],o1[2],o1[3]);
    }
    {   // edge vector LN + rotate (u 64..127)
        F4 va, vb, vc;
        va.v = *(const float4*)(ef + 128 + l*12);
        vb.v = *(const float4*)(ef + 128 + l*12 + 4);
        vc.v = *(const float4*)(ef + 128 + l*12 + 8);
        float vv[12];
        #pragma unroll
        for (int i=0;i<4;i++){ vv[i]=va.f[i]; vv[4+i]=vb.f[i]; vv[8+i]=vc.f[i]; }
        float sq=0.f;
        #pragma unroll
        for (int i=0;i<12;i++) sq += vv[i]*vv[i];
        #pragma unroll
        for (int m=1;m<16;m<<=1) sq += __shfl_xor(sq,m,64);
        float rv = rsqrtf(sq*(1.0f/192.0f) + EPS_LN);
        float f0[4], f1[4], f2[4];
        #pragma unroll
        for (int j=0;j<4;j++){
            int u = 4*l + j;
            float sc = rv * e_wv[u];
            float x = vv[3*j]*sc, y = vv[3*j+1]*sc, z = vv[3*j+2]*sc;
            f0[j] = ax*x+ay*y+az*z;
            f1[j] = bx*x+by*y+bz*z;
            f2[j] = cx*x+cy*y+cz*z;
        }
        st_g4(Arow + 128 + 64 + 4*l, f0[0],f0[1],f0[2],f0[3]);
        st_g4(V1r + 64 + 4*l, f1[0],f1[1],f1[2],f1[3]);
        st_g4(V2r + 64 + 4*l, f2[0],f2[1],f2[2],f2[3]);
    }
    {   // nv[ctr] (u 0..63)
        const float* pv = nv + (size_t)ct*192 + l*12;
        F4 va, vb, vc;
        va.v = *(const float4*)(pv);
        vb.v = *(const float4*)(pv+4);
        vc.v = *(const float4*)(pv+8);
        float vv[12];
        #pragma unroll
        for (int i=0;i<4;i++){ vv[i]=va.f[i]; vv[4+i]=vb.f[i]; vv[8+i]=vc.f[i]; }
        float f0[4], f1[4], f2[4];
        #pragma unroll
        for (int j=0;j<4;j++){
            float x = vv[3*j], y = vv[3*j+1], z = vv[3*j+2];
            f0[j] = ax*x+ay*y+az*z;
            f1[j] = bx*x+by*y+bz*z;
            f2[j] = cx*x+cy*y+cz*z;
        }
        st_g4(Arow + 128 + 4*l, f0[0],f0[1],f0[2],f0[3]);
        st_g4(V1r + 4*l, f1[0],f1[1],f1[2],f1[3]);
        st_g4(V2r + 4*l, f2[0],f2[1],f2[2],f2[3]);
    }
    {   // nv[nbr] (u 128..191)
        const float* pv = nv + (size_t)nb*192 + l*12;
        F4 va, vb, vc;
        va.v = *(const float4*)(pv);
        vb.v = *(const float4*)(pv+4);
        vc.v = *(const float4*)(pv+8);
        float vv[12];
        #pragma unroll
        for (int i=0;i<4;i++){ vv[i]=va.f[i]; vv[4+i]=vb.f[i]; vv[8+i]=vc.f[i]; }
        float f0[4], f1[4], f2[4];
        #pragma unroll
        for (int j=0;j<4;j++){
            float x = vv[3*j], y = vv[3*j+1], z = vv[3*j+2];
            f0[j] = ax*x+ay*y+az*z;
            f1[j] = bx*x+by*y+bz*z;
            f2[j] = cx*x+cy*y+cz*z;
        }
        st_g4(Arow + 128 + 128 + 4*l, f0[0],f0[1],f0[2],f0[3]);
        st_g4(V1r + 128 + 4*l, f1[0],f1[1],f1[2],f1[3]);
        st_g4(V2r + 128 + 4*l, f2[0],f2[1],f2[2],f2[3]);
    }
}

// ---------------- tiled MFMA GEMM, fragment-major B direct from global (L2-resident) ----
enum { EPI_PLAIN=0, EPI_LPS=1, EPI_LPV=2 };

template<int N, int K, int RT, int EPI, bool AGATHER>
__global__ __launch_bounds__((N/64)*RT*64)
void gemm_k(const __bf16* __restrict__ Ag, const float* __restrict__ Agf,
            const int* __restrict__ aidx,
            const __bf16* __restrict__ Bfm,
            unsigned short* __restrict__ outp,
            const unsigned short* __restrict__ wenv,
            const float* __restrict__ bias,
            float scale, int M)
{
    constexpr int NT  = N/64;
    constexpr int BM  = RT*64;
    constexpr int T   = NT*RT*64;
    constexpr int NKT = K/32;
    constexpr int NK  = K/64;
    constexpr int NBUF= (NK>1) ? 2 : 1;
    constexpr int CA  = (BM*8 + T - 1)/T;
    __shared__ __align__(16) char lA[NBUF][BM*128];

    const int tid  = threadIdx.x;
    const int brow = blockIdx.x*BM;
    const int mpl  = blockIdx.y;
    const __bf16* A = AGATHER ? nullptr : (Ag + (size_t)mpl*M*K);

    uint4 ra[CA];
    auto loadA = [&](int ks){
        #pragma unroll
        for (int i=0;i<CA;i++){
            int c = tid + i*T;
            if (c < BM*8){
                int r = c>>3;
                int gr = brow + r; if (gr >= M) gr = M-1;
                if constexpr (AGATHER){
                    int ae = aidx[gr];
                    const float* base = Agf + (size_t)ae*K + ks*64 + (c&7)*8;
                    float4 f0 = *(const float4*)(base);
                    float4 f1 = *(const float4*)(base+4);
                    ra[i] = pack8(f0, f1);
                } else {
                    ra[i] = *(const uint4*)((const char*)(A + (size_t)gr*K + ks*64) + (c&7)*16);
                }
            }
        }
    };
    auto storeA = [&](int buf){
        #pragma unroll
        for (int i=0;i<CA;i++){
            int c = tid + i*T;
            if (c < BM*8){
                int r = c>>3, off = (c&7)*16;
                *(uint4*)(&lA[buf][r*128 + (off ^ ((r&7)<<4))]) = ra[i];
            }
        }
    };

    const int wid = tid>>6, ln = tid&63;
    const int cc = ln & 15, gq = ln >> 4;
    const int wn = wid % NT, wm = wid / NT;
    const __bf16* bbase = Bfm + ((size_t)wn*4*NKT)*512 + (size_t)ln*8;

    f32x4 acc[4][4];
    #pragma unroll
    for (int i=0;i<4;i++)
        #pragma unroll
        for (int j=0;j<4;j++) acc[i][j] = (f32x4){0,0,0,0};

    loadA(0); storeA(0);
    int cur = 0;
    for (int ks=0; ks<NK; ks++){
        __syncthreads();
        if (ks+1 < NK) loadA(ks+1);
        #pragma unroll
        for (int kt2=0;kt2<2;kt2++){
            const int kt = ks*2 + kt2;
            const int kb = kt2*64 + 16*gq;
            bf16x8 af[4];
            #pragma unroll
            for (int mf=0;mf<4;mf++){
                int r = wm*64 + mf*16 + cc;
                af[mf] = *(const bf16x8*)(&lA[cur][r*128 + (kb ^ ((r&7)<<4))]);
            }
            #pragma unroll
            for (int nf=0;nf<4;nf++){
                bf16x8 bfr = *(const bf16x8*)(bbase + ((size_t)nf*NKT + kt)*512);
                #pragma unroll
                for (int mf=0;mf<4;mf++)
                    acc[mf][nf] = __builtin_amdgcn_mfma_f32_16x16x32_bf16(af[mf], bfr, acc[mf][nf], 0,0,0);
            }
        }
        if (ks+1 < NK) storeA(cur^1);
        cur ^= (NBUF-1);
    }

    const float inv_avg_ = 0.288675134595f;
    #pragma unroll
    for (int mf=0;mf<4;mf++){
        #pragma unroll
        for (int nf=0;nf<4;nf++){
            #pragma unroll
            for (int j=0;j<4;j++){
                int gr = brow + wm*64 + mf*16 + gq*4 + j;
                if (gr >= M) continue;
                int col = wn*64 + nf*16 + cc;
                float v = acc[mf][nf][j];
                if constexpr (EPI == EPI_PLAIN){
                    outp[(size_t)gr*N + col] = f2bf(v*scale);
                } else if constexpr (EPI == EPI_LPS){
                    float val = (v*scale + bias[col]) * bf2f(wenv[(size_t)gr*192 + col]) * inv_avg_;
                    outp[(size_t)gr*320 + col] = f2bf(val);
                } else {
                    float val = v*0.125f * bf2f(wenv[(size_t)gr*192 + 128 + col]) * inv_avg_;
                    outp[(size_t)gr*320 + 128 + mpl*64 + col] = f2bf(val);
                }
            }
        }
    }
}

// ---------------- lp_v: 3 planes in one block, B in registers, single LDS buffer ----
__global__ __launch_bounds__(128)
void gemm_lpv(const __bf16* __restrict__ Ag,          // 3 planes of [M][64]
              const __bf16* __restrict__ Bfm,         // lp_wv fragment-major, N=64,K=64
              unsigned short* __restrict__ outp,
              const unsigned short* __restrict__ wenv,
              int M)
{
    constexpr int BM = 128;
    __shared__ __align__(16) char lA[BM*128];

    const int tid  = threadIdx.x;
    const int brow = blockIdx.x*BM;

    uint4 ra[8];
    auto loadA = [&](int pl){
        const __bf16* A = Ag + (size_t)pl*M*64;
        #pragma unroll
        for (int i=0;i<8;i++){
            int c = tid + i*128;
            int r = c>>3;
            int gr = brow + r; if (gr >= M) gr = M-1;
            ra[i] = *(const uint4*)((const char*)(A + (size_t)gr*64) + (c&7)*16);
        }
    };
    auto storeA = [&](){
        #pragma unroll
        for (int i=0;i<8;i++){
            int c = tid + i*128;
            int r = c>>3, off = (c&7)*16;
            *(uint4*)(&lA[r*128 + (off ^ ((r&7)<<4))]) = ra[i];
        }
    };

    const int wid = tid>>6, ln = tid&63;
    const int cc = ln & 15, gq = ln >> 4;
    const int wm = wid;             // 2 waves, rows wm*64..+63; cols 0..63

    // preload B fragments (shared by all planes): nf 0..3, kt 0..1
    bf16x8 bf_[4][2];
    {
        const __bf16* bbase = Bfm + (size_t)ln*8;
        #pragma unroll
        for (int nf=0;nf<4;nf++)
            #pragma unroll
            for (int kt=0;kt<2;kt++)
                bf_[nf][kt] = *(const bf16x8*)(bbase + ((size_t)nf*2 + kt)*512);
    }

    loadA(0); storeA();
    const float inv_avg_ = 0.288675134595f;
    for (int pl=0; pl<3; pl++){
        __syncthreads();                        // lA ready / prior reads done
        if (pl < 2) loadA(pl+1);                // prefetch next plane into regs
        f32x4 acc[4][4];
        #pragma unroll
        for (int i=0;i<4;i++)
            #pragma unroll
            for (int j=0;j<4;j++) acc[i][j] = (f32x4){0,0,0,0};
        #pragma unroll
        for (int kt=0;kt<2;kt++){
            const int kb = kt*64 + 16*gq;
            bf16x8 af[4];
            #pragma unroll
            for (int mf=0;mf<4;mf++){
                int r = wm*64 + mf*16 + cc;
                af[mf] = *(const bf16x8*)(&lA[r*128 + (kb ^ ((r&7)<<4))]);
            }
            #pragma unroll
            for (int nf=0;nf<4;nf++)
                #pragma unroll
                for (int mf=0;mf<4;mf++)
                    acc[mf][nf] = __builtin_amdgcn_mfma_f32_16x16x32_bf16(af[mf], bf_[nf][kt], acc[mf][nf], 0,0,0);
        }
        __syncthreads();                        // all lA reads done before overwrite
        if (pl < 2) storeA();
        // epilogue for this plane
        #pragma unroll
        for (int mf=0;mf<4;mf++){
            #pragma unroll
            for (int nf=0;nf<4;nf++){
                #pragma unroll
                for (int j=0;j<4;j++){
                    int gr = brow + wm*64 + mf*16 + gq*4 + j;
                    if (gr >= M) continue;
                    int col = nf*16 + cc;
                    float val = acc[mf][nf][j]*0.125f * bf2f(wenv[(size_t)gr*192 + 128 + col]) * inv_avg_;
                    outp[(size_t)gr*320 + 128 + pl*64 + col] = f2bf(val);
                }
            }
        }
    }
}

// ---------------- mid: nodeCN gather-add + gate + rotate-back + silu ----------------
__global__ void mid_kernel(const unsigned short* __restrict__ m0out,
                           const unsigned short* __restrict__ vpvm,
                           const float* __restrict__ Rg,
                           const int2* __restrict__ ctnb,
                           const __bf16* __restrict__ nodeCN,
                           unsigned short* __restrict__ As,
                           unsigned short* __restrict__ MVp, int EA)
{
    int tid = blockIdx.x*256 + threadIdx.x;
    int e = tid>>6, u = tid&63;
    if (e >= EA) return;
    float rl = (u < 12) ? Rg[(size_t)e*12 + u] : 0.f;
    float R0=__shfl(rl,0,64), R1=__shfl(rl,1,64), R2=__shfl(rl,2,64);
    float R3=__shfl(rl,3,64), R4=__shfl(rl,4,64), R5=__shfl(rl,5,64);
    float R6=__shfl(rl,6,64), R7=__shfl(rl,7,64), R8=__shfl(rl,8,64);
    int2 cn = ctnb[e];                                // wave-uniform
    const __bf16* nct = nodeCN + (size_t)cn.x*512;    // W rows 0..127 contribution
    const __bf16* nnb = nodeCN + (size_t)cn.y*512 + 256; // W rows 256..383 contribution
    const float rn0 = 0.0416666666667f;               // 1/sqrt(576)
    float a0 = ((float)nct[u]       + (float)nnb[u])       * rn0;
    float a1 = ((float)nct[64+u]    + (float)nnb[64+u])    * rn0;
    float a2 = ((float)nct[128+u]   + (float)nnb[128+u])   * rn0;
    float a3 = ((float)nct[192+u]   + (float)nnb[192+u])   * rn0;
    const unsigned short* mo = m0out + (size_t)e*256;
    float m0 = bf2f(mo[u])       + a0;
    float m1 = bf2f(mo[64 + u])  + a1;
    float gt = sigmoidf_(bf2f(mo[128 + u]) + a2);
    float s0 = bf2f(mo[192 + u]) + a3;
    float p  = bf2f(vpvm[(size_t)e*128 + u]);
    float q  = bf2f(vpvm[(size_t)e*128 + 64 + u]);
    size_t eu = (size_t)e*64 + u;
    size_t P  = (size_t)EA*64;
    MVp[eu]       = f2bf(gt*(R0*s0 + R3*p + R6*q));
    MVp[P + eu]   = f2bf(gt*(R1*s0 + R4*p + R7*q));
    MVp[2*P + eu] = f2bf(gt*(R2*s0 + R5*p + R8*q));
    As[(size_t)e*128 + u]      = f2bf(siluf_(m0));
    As[(size_t)e*128 + 64 + u] = f2bf(siluf_(m1));
}

// ---------------- fallback: fused edge kernel (round-3, plane-layout stores) ----------------
__launch_bounds__(256, 3)
__global__ void edge_kernel_fused(
    const float* __restrict__ latents,
    const float* __restrict__ ef_all,
    const int*   __restrict__ edge_index,
    const float* __restrict__ edge_vector,
    const int*   __restrict__ active_edges,
    const float* __restrict__ e_ws, const float* __restrict__ e_bs, const float* __restrict__ e_wv,
    const __bf16* __restrict__ Wt,
    const __bf16* __restrict__ w1rt,
    const __bf16* __restrict__ w1it,
    const float* __restrict__ env_w,
    const float* __restrict__ lp_ws, const float* __restrict__ lp_bs, const float* __restrict__ lp_wv,
    const float* __restrict__ ns, const float* __restrict__ nv,
    unsigned short* __restrict__ eout,
    int EA, int EF)
{
    __shared__ __align__(16) char smem[46592];
    char* sAbC = smem;
    char* sVFC = smem + 18432;
    float* sO  = (float*)smem;
    float* MV  = (float*)(smem + 16640);
    float* WE  = (float*)(smem + 33280);
    float* sR  = (float*)(smem + 45824);

    const int t = threadIdx.x;
    const int g = t >> 4, l = t & 15;
    const int e = blockIdx.x*16 + g;
    const bool act = (e < EA);

    int ct = 0, ae = 0;

    if (act) {
        ae = active_edges[e];
        ct = edge_index[ae];
        int nb = edge_index[EF + ae];
        float ex = edge_vector[(size_t)ae*3+0];
        float ey = edge_vector[(size_t)ae*3+1];
        float ez = edge_vector[(size_t)ae*3+2];
        float rn = rsqrtf(ex*ex+ey*ey+ez*ez + EPS_LN);
        float ax = ex*rn, ay = ey*rn, az = ez*rn;
        float rx, ry;
        if (fabsf(ax) < 0.9f) { rx = 1.0f; ry = 0.0f; } else { rx = 0.0f; ry = 1.0f; }
        float bx = -az*ry, by = az*rx, bz = ax*ry - ay*rx;
        float bn = rsqrtf(bx*bx+by*by+bz*bz + EPS_LN);
        bx*=bn; by*=bn; bz*=bn;
        float cx = ay*bz - az*by;
        float cy = az*bx - ax*bz;
        float cz = ax*by - ay*bx;
        if (l == 0){
            float* Rr = &sR[g*12];
            Rr[0]=ax; Rr[1]=ay; Rr[2]=az;
            Rr[3]=bx; Rr[4]=by; Rr[5]=bz;
            Rr[6]=cx; Rr[7]=cy; Rr[8]=cz;
        }
        {
            const float4* pc4 = (const float4*)(ns + (size_t)ct*128);
            const float4* pn4 = (const float4*)(ns + (size_t)nb*128);
            F4 a,b2,c,d;
            a.v = pc4[l]; b2.v = pc4[16+l]; c.v = pn4[l]; d.v = pn4[16+l];
            st_bf4(sAbC, g, 1152, l*4,       a.f[0],a.f[1],a.f[2],a.f[3]);
            st_bf4(sAbC, g, 1152, 64+l*4,    b2.f[0],b2.f[1],b2.f[2],b2.f[3]);
            st_bf4(sAbC, g, 1152, 256+l*4,   c.f[0],c.f[1],c.f[2],c.f[3]);
            st_bf4(sAbC, g, 1152, 320+l*4,   d.f[0],d.f[1],d.f[2],d.f[3]);
        }
        const float* ef = ef_all + (size_t)e*320;
        {
            F4 sa, sb;
            sa.v = *(const float4*)(ef + l*4);
            sb.v = *(const float4*)(ef + 64 + l*4);
            float sum=0.f, sq=0.f;
            #pragma unroll
            for (int i=0;i<4;i++){ sum += sa.f[i]+sb.f[i]; sq += sa.f[i]*sa.f[i]+sb.f[i]*sb.f[i]; }
            #pragma unroll
            for (int m=1;m<16;m<<=1){ sum += __shfl_xor(sum,m,64); sq += __shfl_xor(sq,m,64); }
            float mu = sum*(1.0f/128.0f);
            float rs = rsqrtf(sq*(1.0f/128.0f)-mu*mu + EPS_LN);
            float o0[4], o1[4];
            #pragma unroll
            for (int i=0;i<4;i++){
                int c0 = l*4+i, c1 = 64+l*4+i;
                o0[i] = (sa.f[i]-mu)*rs*e_ws[c0]+e_bs[c0];
                o1[i] = (sb.f[i]-mu)*rs*e_ws[c1]+e_bs[c1];
            }
            st_bf4(sAbC, g, 1152, 128+l*4, o0[0],o0[1],o0[2],o0[3]);
            st_bf4(sAbC, g, 1152, 192+l*4, o1[0],o1[1],o1[2],o1[3]);
        }
        {
            F4 va, vb, vc;
            va.v = *(const float4*)(ef + 128 + l*12);
            vb.v = *(const float4*)(ef + 128 + l*12 + 4);
            vc.v = *(const float4*)(ef + 128 + l*12 + 8);
            float vv[12];
            #pragma unroll
            for (int i=0;i<4;i++){ vv[i]=va.f[i]; vv[4+i]=vb.f[i]; vv[8+i]=vc.f[i]; }
            float sq=0.f;
            #pragma unroll
            for (int i=0;i<12;i++) sq += vv[i]*vv[i];
            #pragma unroll
            for (int m=1;m<16;m<<=1) sq += __shfl_xor(sq,m,64);
            float rv = rsqrtf(sq*(1.0f/192.0f) + EPS_LN);
            float f0[4], f1[4], f2[4];
            #pragma unroll
            for (int j=0;j<4;j++){
                int u = 4*l + j;
                float sc = rv * e_wv[u];
                float x = vv[3*j]*sc, y = vv[3*j+1]*sc, z = vv[3*j+2]*sc;
                f0[j] = ax*x+ay*y+az*z;
                f1[j] = bx*x+by*y+bz*z;
                f2[j] = cx*x+cy*y+cz*z;
            }
            st_bf4(sAbC, g, 1152, 384+64+4*l, f0[0],f0[1],f0[2],f0[3]);
            st_bf4(sVFC, g, 384, 64+4*l, f1[0],f1[1],f1[2],f1[3]);
            st_bf4(sVFC+6144, g, 384, 64+4*l, f2[0],f2[1],f2[2],f2[3]);
        }
        {
            const float* pv = nv + (size_t)ct*192 + l*12;
            F4 va, vb, vc;
            va.v = *(const float4*)(pv);
            vb.v = *(const float4*)(pv+4);
            vc.v = *(const float4*)(pv+8);
            float vv[12];
            #pragma unroll
            for (int i=0;i<4;i++){ vv[i]=va.f[i]; vv[4+i]=vb.f[i]; vv[8+i]=vc.f[i]; }
            float f0[4], f1[4], f2[4];
            #pragma unroll
            for (int j=0;j<4;j++){
                float x = vv[3*j], y = vv[3*j+1], z = vv[3*j+2];
                f0[j] = ax*x+ay*y+az*z;
                f1[j] = bx*x+by*y+bz*z;
                f2[j] = cx*x+cy*y+cz*z;
            }
            st_bf4(sAbC, g, 1152, 384+4*l, f0[0],f0[1],f0[2],f0[3]);
            st_bf4(sVFC, g, 384, 4*l, f1[0],f1[1],f1[2],f1[3]);
            st_bf4(sVFC+6144, g, 384, 4*l, f2[0],f2[1],f2[2],f2[3]);
        }
        {
            const float* pv = nv + (size_t)nb*192 + l*12;
            F4 va, vb, vc;
            va.v = *(const float4*)(pv);
            vb.v = *(const float4*)(pv+4);
            vc.v = *(const float4*)(pv+8);
            float vv[12];
            #pragma unroll
            for (int i=0;i<4;i++){ vv[i]=va.f[i]; vv[4+i]=vb.f[i]; vv[8+i]=vc.f[i]; }
            float f0[4], f1[4], f2[4];
            #pragma unroll
            for (int j=0;j<4;j++){
                float x = vv[3*j], y = vv[3*j+1], z = vv[3*j+2];
                f0[j] = ax*x+ay*y+az*z;
                f1[j] = bx*x+by*y+bz*z;
                f2[j] = cx*x+cy*y+cz*z;
            }
            st_bf4(sAbC, g, 1152, 384+128+4*l, f0[0],f0[1],f0[2],f0[3]);
            st_bf4(sVFC, g, 384, 128+4*l, f1[0],f1[1],f1[2],f1[3]);
            st_bf4(sVFC+6144, g, 384, 128+4*l, f2[0],f2[1],f2[2],f2[3]);
        }
    }
    __syncthreads();

    const int w  = t >> 6;
    const int ln = t & 63;
    const int cc = ln & 15;
    const int gq = ln >> 4;

    f32x4 accM[4] = {{0,0,0,0},{0,0,0,0},{0,0,0,0},{0,0,0,0}};
    {
        const __bf16* wb0 = Wt + (size_t)(64*w + 0  + cc)*576;
        const __bf16* wb1 = Wt + (size_t)(64*w + 16 + cc)*576;
        const __bf16* wb2 = Wt + (size_t)(64*w + 32 + cc)*576;
        const __bf16* wb3 = Wt + (size_t)(64*w + 48 + cc)*576;
        for (int ks=0; ks<18; ks++){
            bf16x8 a = ld_frag(sAbC, cc, 1152, ks*64 + 16*gq);
            int ko = ks*32 + 8*gq;
            bf16x8 b0 = *(const bf16x8*)(wb0 + ko);
            bf16x8 b1 = *(const bf16x8*)(wb1 + ko);
            bf16x8 b2 = *(const bf16x8*)(wb2 + ko);
            bf16x8 b3 = *(const bf16x8*)(wb3 + ko);
            accM[0] = __builtin_amdgcn_mfma_f32_16x16x32_bf16(a, b0, accM[0], 0,0,0);
            accM[1] = __builtin_amdgcn_mfma_f32_16x16x32_bf16(a, b1, accM[1], 0,0,0);
            accM[2] = __builtin_amdgcn_mfma_f32_16x16x32_bf16(a, b2, accM[2], 0,0,0);
            accM[3] = __builtin_amdgcn_mfma_f32_16x16x32_bf16(a, b3, accM[3], 0,0,0);
        }
    }
    f32x4 aP1={0,0,0,0}, aP2={0,0,0,0}, aM1={0,0,0,0}, aM2={0,0,0,0};
    {
        const __bf16* wr = w1rt + (size_t)(16*w + cc)*192;
        const __bf16* wi = w1it + (size_t)(16*w + cc)*192;
        for (int ks=0; ks<6; ks++){
            bf16x8 a1 = ld_frag(sVFC,        cc, 384, ks*64 + 16*gq);
            bf16x8 a2 = ld_frag(sVFC + 6144, cc, 384, ks*64 + 16*gq);
            int ko = ks*32 + 8*gq;
            bf16x8 br = *(const bf16x8*)(wr + ko);
            bf16x8 bi = *(const bf16x8*)(wi + ko);
            aP1 = __builtin_amdgcn_mfma_f32_16x16x32_bf16(a1, br, aP1, 0,0,0);
            aP2 = __builtin_amdgcn_mfma_f32_16x16x32_bf16(a2, bi, aP2, 0,0,0);
            aM1 = __builtin_amdgcn_mfma_f32_16x16x32_bf16(a1, bi, aM1, 0,0,0);
            aM2 = __builtin_amdgcn_mfma_f32_16x16x32_bf16(a2, br, aM2, 0,0,0);
        }
    }
    __syncthreads();

    {
        const float rn0 = 0.0416666666667f;
        #pragma unroll
        for (int jt=0;jt<4;jt++){
            #pragma unroll
            for (int j=0;j<4;j++){
                sO[(gq*4+j)*260 + 64*w + 16*jt + cc] = accM[jt][j]*rn0;
            }
        }
    }
    float vp[4], vm[4];
    {
        const float n1 = 0.0721687836487f;
        #pragma unroll
        for (int j=0;j<4;j++){ vp[j] = (aP1[j]-aP2[j])*n1; vm[j] = (aM1[j]+aM2[j])*n1; }
    }
    __syncthreads();

    {
        int u = w*16 + cc;
        #pragma unroll
        for (int j=0;j<4;j++){
            int er = gq*4 + j;
            if (blockIdx.x*16 + er < EA){
                const float* Rr = &sR[er*12];
                float s0 = sO[er*260 + 192 + u];
                float gt = sigmoidf_(sO[er*260 + 128 + u]);
                float p = vp[j], q = vm[j];
                float4 o;
                o.x = gt*(Rr[0]*s0 + Rr[3]*p + Rr[6]*q);
                o.y = gt*(Rr[1]*s0 + Rr[4]*p + Rr[7]*q);
                o.z = gt*(Rr[2]*s0 + Rr[5]*p + Rr[8]*q);
                o.w = 0.0f;
                *(float4*)&MV[er*260 + u*4] = o;
            }
        }
    }
    if (act) {
        {
            int i0 = l*8;
            F4 oa, ob;
            oa.v = *(const float4*)&sO[g*260 + i0];
            ob.v = *(const float4*)&sO[g*260 + i0 + 4];
            #pragma unroll
            for (int i=0;i<4;i++){ oa.f[i] = siluf_(oa.f[i]); ob.f[i] = siluf_(ob.f[i]); }
            *(float4*)&sO[g*260 + i0]     = oa.v;
            *(float4*)&sO[g*260 + i0 + 4] = ob.v;
        }
        {
            const int cc2 = l*12;
            float wacc[12];
            #pragma unroll
            for (int i=0;i<12;i++) wacc[i]=0.f;
            const float* lat = latents + (size_t)ae*128;
            for (int k=0;k<128;k+=4){
                F4 la;
                la.v = *(const float4*)(lat + k);
                #pragma unroll
                for (int kk=0;kk<4;kk++){
                    const float* er_ = env_w + (size_t)(k+kk)*192 + cc2;
                    F4 e0v,e1v,e2v;
                    e0v.v = *(const float4*)(er_);
                    e1v.v = *(const float4*)(er_+4);
                    e2v.v = *(const float4*)(er_+8);
                    #pragma unroll
                    for (int i=0;i<4;i++){
                        wacc[i]   += la.f[kk]*e0v.f[i];
                        wacc[4+i] += la.f[kk]*e1v.f[i];
                        wacc[8+i] += la.f[kk]*e2v.f[i];
                    }
                }
            }
            const float inv128 = 0.0883883476483f;
            #pragma unroll
            for (int i=0;i<12;i++) WE[g*196 + cc2 + i] = wacc[i]*inv128;
        }
    }
    __syncthreads();

    if (act) {
        const float inv_avg = 0.288675134595f;
        unsigned short* orow = eout + (size_t)e*320;
        {
            int c0 = l*8;
            float a8[8];
            #pragma unroll
            for (int i=0;i<8;i++) a8[i]=0.f;
            for (int k=0;k<128;k+=4){
                F4 av;
                av.v = *(const float4*)&sO[g*260 + k];
                #pragma unroll
                for (int kk=0;kk<4;kk++){
                    const float* wr = lp_ws + (size_t)(k+kk)*128 + c0;
                    F4 w0, w1_;
                    w0.v  = *(const float4*)(wr);
                    w1_.v = *(const float4*)(wr+4);
                    #pragma unroll
                    for (int i=0;i<4;i++){ a8[i] += av.f[kk]*w0.f[i]; a8[4+i] += av.f[kk]*w1_.f[i]; }
                }
            }
            const float s128 = 0.0883883476483f;
            union { unsigned short h[8]; uint4 u; } ps;
            #pragma unroll
            for (int i=0;i<8;i++){
                int c = c0+i;
                ps.h[i] = f2bf((a8[i]*s128 + lp_bs[c]) * WE[g*196 + c] * inv_avg);
            }
            *(uint4*)(orow + c0) = ps.u;
        }
        {
            int k0 = l*4;
            float av[4][3];
            #pragma unroll
            for (int j=0;j<4;j++)
                #pragma unroll
                for (int m2=0;m2<3;m2++) av[j][m2]=0.f;
            for (int u=0;u<64;u++){
                F4 wv4, mv4;
                wv4.v = *(const float4*)(lp_wv + (size_t)u*64 + k0);
                mv4.v = *(const float4*)&MV[g*260 + u*4];
                #pragma unroll
                for (int j=0;j<4;j++){
                    av[j][0] += wv4.f[j]*mv4.f[0];
                    av[j][1] += wv4.f[j]*mv4.f[1];
                    av[j][2] += wv4.f[j]*mv4.f[2];
                }
            }
            #pragma unroll
            for (int j=0;j<4;j++){
                int k = k0+j;
                float wk = WE[g*196 + 128 + k] * 0.125f * inv_avg;
                orow[128 +       k] = f2bf(av[j][0]*wk);
                orow[128 + 64  + k] = f2bf(av[j][1]*wk);
                orow[128 + 128 + k] = f2bf(av[j][2]*wk);
            }
        }
    }
}

// ---------------- node CSR aggregate + onehot path + output (ILP-restructured) ----------------
__global__ void node_out_kernel(
    const float* __restrict__ nf,
    const int* __restrict__ atom_type,
    const int* __restrict__ offs, const int* __restrict__ elist,
    const unsigned short* __restrict__ eout,
    const __bf16* __restrict__ ssT, const __bf16* __restrict__ sgT, const __bf16* __restrict__ vvT,
    const float* __restrict__ ohl_ws, const float* __restrict__ ohl_bs, const float* __restrict__ ohl_wv,
    const float* __restrict__ res_param,
    float* __restrict__ out, int N)
{
    __shared__ int   sE[64];
    __shared__ float AGS[128];
    __shared__ float AGV[192];
    __shared__ float TSs[128];
    __shared__ float SG[64];
    __shared__ float TV[192];
    const int n = blockIdx.x;
    const int t = threadIdx.x;
    const int at = atom_type[n];
    const int lo = offs[n], hi = offs[n+1];

    // gather-aggregate: threads 0..159 own cols {2t, 2t+1}; 4-stream ILP
    float aLo = 0.f, aHi = 0.f;
    for (int base = lo; base < hi; base += 64){
        int cnt = hi - base; if (cnt > 64) cnt = 64;
        __syncthreads();
        if (t < cnt) sE[t] = elist[base + t];
        __syncthreads();
        if (t < 160){
            int i = 0;
            for (; i+4 <= cnt; i += 4){
                unsigned x0 = *(const unsigned*)(eout + (size_t)sE[i  ]*320 + 2*t);
                unsigned x1 = *(const unsigned*)(eout + (size_t)sE[i+1]*320 + 2*t);
                unsigned x2 = *(const unsigned*)(eout + (size_t)sE[i+2]*320 + 2*t);
                unsigned x3 = *(const unsigned*)(eout + (size_t)sE[i+3]*320 + 2*t);
                aLo += bf2f((unsigned short)x0) + bf2f((unsigned short)x1)
                     + bf2f((unsigned short)x2) + bf2f((unsigned short)x3);
                aHi += bf2f((unsigned short)(x0>>16)) + bf2f((unsigned short)(x1>>16))
                     + bf2f((unsigned short)(x2>>16)) + bf2f((unsigned short)(x3>>16));
            }
            for (; i < cnt; i++){
                unsigned x = *(const unsigned*)(eout + (size_t)sE[i]*320 + 2*t);
                aLo += bf2f((unsigned short)x);
                aHi += bf2f((unsigned short)(x>>16));
            }
        }
    }
    if (t < 160){
        int c0 = 2*t, c1 = 2*t+1;
        if (c0 < 128) AGS[c0] = aLo; else { int d=c0-128; AGV[(d&63)*3 + (d>>6)] = aLo; }
        if (c1 < 128) AGS[c1] = aHi; else { int d=c1-128; AGV[(d&63)*3 + (d>>6)] = aHi; }
    }
    __syncthreads();
    const float n_ss = 0.0110485434560f;
    const float n_vv = 0.015625f;
    if (t < 128) {
        const __bf16* w = ssT + (size_t)at*16384 + t;
        float acc = 0.0f;
        #pragma unroll 8
        for (int u=0;u<128;u++) acc += AGS[u]*(float)w[(size_t)u*128];
        TSs[t] = siluf_(acc*n_ss);
    } else if (t < 192) {
        int k = t-128;
        const __bf16* w = sgT + (size_t)at*8192 + k;
        float acc = 0.0f;
        #pragma unroll 8
        for (int u=0;u<128;u++) acc += AGS[u]*(float)w[(size_t)u*64];
        SG[k] = sigmoidf_(acc*n_ss);
    } else {
        int k = t-192;
        const __bf16* w = vvT + (size_t)at*4096 + k;
        float a0=0,a1=0,a2=0;
        #pragma unroll 8
        for (int u=0;u<64;u++){
            float wv = (float)w[(size_t)u*64];
            a0 += AGV[u*3+0]*wv;
            a1 += AGV[u*3+1]*wv;
            a2 += AGV[u*3+2]*wv;
        }
        TV[k*3+0]=a0*n_vv; TV[k*3+1]=a1*n_vv; TV[k*3+2]=a2*n_vv;
    }
    __syncthreads();
    const float alpha = sigmoidf_(res_param[0]);
    const float beta  = 1.0f - alpha;
    if (t < 128) {
        float acc = 0.0f;
        #pragma unroll 8
        for (int k=0;k<128;k++) acc += TSs[k]*ohl_ws[(size_t)k*128 + t];
        float val = acc*0.0883883476483f + ohl_bs[t];
        out[(size_t)n*320 + t] = alpha*nf[(size_t)n*320 + t] + beta*val;
    } else if (t >= 192) {
        int k = t-192;
        float a0=0,a1=0,a2=0;
        #pragma unroll 8
        for (int u=0;u<64;u++){
            float w = ohl_wv[(size_t)u*64 + k]*SG[u];
            a0 += TV[u*3+0]*w; a1 += TV[u*3+1]*w; a2 += TV[u*3+2]*w;
        }
        size_t base = (size_t)n*320 + 128 + (size_t)k*3;
        out[base+0] = alpha*nf[base+0] + beta*(a0*0.125f);
        out[base+1] = alpha*nf[base+1] + beta*(a1*0.125f);
        out[base+2] = alpha*nf[base+2] + beta*(a2*0.125f);
    }
}

extern "C" void kernel_launch(void* const* d_in, const int* in_sizes, int n_in,
                              void* d_out, int out_size, void* d_ws, size_t ws_size,
                              hipStream_t stream)
{
    const float* latents       = (const float*)d_in[0];
    const float* node_features = (const float*)d_in[1];
    const float* edge_features = (const float*)d_in[2];
    const int*   atom_type     = (const int*)d_in[3];
    const int*   edge_index    = (const int*)d_in[5];
    const float* edge_vector   = (const float*)d_in[6];
    const int*   active_edges  = (const int*)d_in[7];
    const float* sln_n_ws = (const float*)d_in[8];
    const float* sln_n_bs = (const float*)d_in[9];
    const float* sln_n_wv = (const float*)d_in[10];
    const float* sln_e_ws = (const float*)d_in[11];
    const float* sln_e_bs = (const float*)d_in[12];
    const float* sln_e_wv = (const float*)d_in[13];
    const float* so2_w0   = (const float*)d_in[14];
    const float* so2_w1r  = (const float*)d_in[15];
    const float* so2_w1i  = (const float*)d_in[16];
    const float* env_w    = (const float*)d_in[17];
    const float* lp_ws    = (const float*)d_in[18];
    const float* lp_bs    = (const float*)d_in[19];
    const float* lp_wv    = (const float*)d_in[20];
    const float* oh_w_ss  = (const float*)d_in[21];
    const float* oh_w_sg  = (const float*)d_in[22];
    const float* oh_w_vv  = (const float*)d_in[23];
    const float* ohl_ws   = (const float*)d_in[24];
    const float* ohl_bs   = (const float*)d_in[25];
    const float* ohl_wv   = (const float*)d_in[26];
    const float* res_param= (const float*)d_in[27];
    float* out = (float*)d_out;

    const int N  = in_sizes[1] / 320;
    const int EF = in_sizes[5] / 2;
    const int EA = in_sizes[7];

    // workspace layout (256B-aligned chunks)
    char* p = (char*)d_ws;
    auto alloc = [&](size_t bytes) -> char* {
        char* r = p; p += (bytes + 255) & ~(size_t)255; return r;
    };
    float* ns      = (float*)alloc((size_t)N*128*4);
    float* nv      = (float*)alloc((size_t)N*192*4);
    __bf16* nsb    = (__bf16*)alloc((size_t)N*128*2);
    int*   cnt     = (int*)  alloc((size_t)N*4);
    int*   offs    = (int*)  alloc(((size_t)N+1)*4);
    int*   cursor  = (int*)  alloc((size_t)N*4);
    int*   elist   = (int*)  alloc((size_t)EA*4);
    __bf16* Wt     = (__bf16*)alloc((size_t)576*256*2);
    __bf16* w1rt   = (__bf16*)alloc((size_t)64*192*2);
    __bf16* w1it   = (__bf16*)alloc((size_t)64*192*2);
    __bf16* Wevfm  = (__bf16*)alloc((size_t)256*320*2);
    __bf16* Bnodefm= (__bf16*)alloc((size_t)512*128*2);
    __bf16* Bvfm   = (__bf16*)alloc((size_t)128*384*2);
    __bf16* envfm  = (__bf16*)alloc((size_t)192*128*2);
    __bf16* lpsfm  = (__bf16*)alloc((size_t)128*128*2);
    __bf16* lpvfm  = (__bf16*)alloc((size_t)64*64*2);
    __bf16* ssT    = (__bf16*)alloc((size_t)64*128*128*2);
    __bf16* sgT    = (__bf16*)alloc((size_t)64*128*64*2);
    __bf16* vvT    = (__bf16*)alloc((size_t)64*64*64*2);
    __bf16* nodeCN = (__bf16*)alloc((size_t)N*512*2);
    int2*  ctnb    = (int2*) alloc((size_t)EA*8);
    unsigned short* eout = (unsigned short*)alloc((size_t)EA*320*2);
    unsigned short* w_env= (unsigned short*)alloc((size_t)EA*192*2);
    float*  Rg    = (float*) alloc((size_t)EA*12*4);
    __bf16* m0in  = (__bf16*)alloc((size_t)EA*320*2);
    __bf16* vfg   = (__bf16*)alloc((size_t)EA*384*2);
    size_t split_need = (size_t)(p - (char*)d_ws);
    const bool use_split = (split_need <= ws_size);

    // aliases (split path only; all uses are stream-ordered)
    unsigned short* vpvm  = eout;                   // [EA][128], consumed by mid before eout written
    unsigned short* m0out = (unsigned short*)vfg;   // [EA][256], written after vfg consumed
    unsigned short* As    = (unsigned short*)m0in;  // [EA][128], after m0in consumed
    unsigned short* MVp   = As + (size_t)EA*128;    // 3 planes [EA][64]; 128+192=320 fits m0in width

    hipMemsetAsync(cnt, 0, (size_t)N*sizeof(int), stream);
    prep_all<<<4096, 256, 0, stream>>>(so2_w0, so2_w1r, so2_w1i, env_w, lp_ws, lp_wv,
                                       oh_w_ss, oh_w_sg, oh_w_vv,
                                       Wt, w1rt, w1it, Wevfm, Bnodefm, Bvfm,
                                       envfm, lpsfm, lpvfm, ssT, sgT, vvT);
    node_ln_kernel<<<(N+3)/4, 256, 0, stream>>>(node_features, sln_n_ws, sln_n_bs, sln_n_wv, ns, nv, nsb, N);
    csr_count<<<(EA+255)/256, 256, 0, stream>>>(edge_index, active_edges, cnt, EA);
    csr_scan<<<1, 256, 0, stream>>>(cnt, offs, cursor, N);
    csr_fill<<<(EA+255)/256, 256, 0, stream>>>(edge_index, active_edges, cursor, elist, EA);

    const float rn0    = 0.0416666666667f;   // 1/sqrt(576)
    const float n1     = 0.0721687836487f;   // 1/sqrt(192)
    const float inv128 = 0.0883883476483f;   // 1/sqrt(128)

    if (use_split){
        const int NB64  = (EA + 63) / 64;
        const int NB128 = (EA + 127) / 128;
        const int NBn   = (N + 63) / 64;
        // node-side contributions: nsb[N][128] x [512 cols] -> nodeCN[N][512] (raw scale)
        gemm_k<512,128,1,EPI_PLAIN,false><<<dim3(NBn,1), 512, 0, stream>>>(
            nsb, nullptr, nullptr, Bnodefm, (unsigned short*)nodeCN, nullptr, nullptr, 1.0f, N);
        stage_kernel<<<(EA+15)/16, 256, 0, stream>>>(edge_features, edge_index, edge_vector, active_edges,
            sln_e_ws, sln_e_bs, sln_e_wv, nv, m0in, vfg, Rg, ctnb, EA, EF);
        // vp/vm: [EA][384] x Bv -> vpvm[EA][128]  (before main so vfg dead when m0out overlays)
        gemm_k<128,384,2,EPI_PLAIN,false><<<dim3(NB128,1), 256, 0, stream>>>(
            vfg, nullptr, nullptr, Bvfm, vpvm, nullptr, nullptr, n1, EA);
        // main: [EA][320] x Wev -> m0out[EA][256] (partial; node terms added in mid)
        gemm_k<256,320,1,EPI_PLAIN,false><<<dim3(NB64,1), 256, 0, stream>>>(
            m0in, nullptr, nullptr, Wevfm, m0out, nullptr, nullptr, rn0, EA);
        // nodeCN gather-add + gate + rotate-back + silu
        mid_kernel<<<(EA*64+255)/256, 256, 0, stream>>>(m0out, vpvm, Rg, ctnb, nodeCN, As, MVp, EA);
        gemm_k<192,128,1,EPI_PLAIN,true><<<dim3(NB64,1), 192, 0, stream>>>(
            nullptr, latents, active_edges, envfm, w_env, nullptr, nullptr, inv128, EA);
        gemm_k<128,128,2,EPI_LPS,false><<<dim3(NB128,1), 256, 0, stream>>>(
            (const __bf16*)As, nullptr, nullptr, lpsfm, eout, w_env, lp_bs, inv128, EA);
        // lp vector: all 3 planes in one kernel
        gemm_lpv<<<NB128, 128, 0, stream>>>(
            (const __bf16*)MVp, lpvfm, eout, w_env, EA);
    } else {
        edge_kernel_fused<<<(EA+15)/16, 256, 0, stream>>>(latents, edge_features, edge_index, edge_vector, active_edges,
            sln_e_ws, sln_e_bs, sln_e_wv, Wt, w1rt, w1it, env_w, lp_ws, lp_bs, lp_wv,
            ns, nv, eout, EA, EF);
    }
    node_out_kernel<<<N, 256, 0, stream>>>(node_features, atom_type, offs, elist, eout,
        ssT, sgT, vvT, ohl_ws, ohl_bs, ohl_wv, res_param, out, N);
}

// Round 11
// 443.729 us; speedup vs baseline: 1.1810x; 1.0091x over previous
//
#include <hip/hip_runtime.h>

#define EPS_LN 1e-8f

typedef __bf16 bf16x8 __attribute__((ext_vector_type(8)));
typedef float  f32x4  __attribute__((ext_vector_type(4)));

__device__ __forceinline__ float sigmoidf_(float x){ return 1.0f/(1.0f+__expf(-x)); }
__device__ __forceinline__ float siluf_(float x){ return x*sigmoidf_(x); }
__device__ __forceinline__ unsigned short f2bf(float x){ union{ __bf16 b; unsigned short u;} c; c.b = (__bf16)x; return c.u; }
__device__ __forceinline__ float bf2f(unsigned short u){ return __uint_as_float(((unsigned)u)<<16); }

union F4 { float4 v; float f[4]; };

// swizzled bf16 LDS store (fused fallback path)
__device__ __forceinline__ void st_bf4(char* base, int row, int stride_bytes, int k,
                                       float x0, float x1, float x2, float x3){
    union { __bf16 h[4]; unsigned long long u; } p;
    p.h[0]=(__bf16)x0; p.h[1]=(__bf16)x1; p.h[2]=(__bf16)x2; p.h[3]=(__bf16)x3;
    *(unsigned long long*)(base + row*stride_bytes + ((2*k) ^ ((row&7)<<4))) = p.u;
}
__device__ __forceinline__ bf16x8 ld_frag(const char* base, int row, int stride_bytes, int kbyte){
    return *(const bf16x8*)(base + row*stride_bytes + (kbyte ^ ((row&7)<<4)));
}
__device__ __forceinline__ void st_g4(__bf16* p, float x0, float x1, float x2, float x3){
    union { __bf16 h[4]; unsigned long long u; } pk;
    pk.h[0]=(__bf16)x0; pk.h[1]=(__bf16)x1; pk.h[2]=(__bf16)x2; pk.h[3]=(__bf16)x3;
    *(unsigned long long*)p = pk.u;
}
__device__ __forceinline__ void ld_bf12(const __bf16* p, float* vv){
    union { __bf16 h[4]; uint2 u; } a,b,c;
    a.u = *(const uint2*)(p);
    b.u = *(const uint2*)(p+4);
    c.u = *(const uint2*)(p+8);
    #pragma unroll
    for (int i=0;i<4;i++){ vv[i]=(float)a.h[i]; vv[4+i]=(float)b.h[i]; vv[8+i]=(float)c.h[i]; }
}
__device__ __forceinline__ uint4 pack8(float4 a, float4 b){
    union { __bf16 h[8]; uint4 u; } p;
    p.h[0]=(__bf16)a.x; p.h[1]=(__bf16)a.y; p.h[2]=(__bf16)a.z; p.h[3]=(__bf16)a.w;
    p.h[4]=(__bf16)b.x; p.h[5]=(__bf16)b.y; p.h[6]=(__bf16)b.z; p.h[7]=(__bf16)b.w;
    return p.u;
}
// fragment-major dest index for B[n][k] tiles (16 cols x 32 k per fragment)
__device__ __forceinline__ int fm_idx(int n, int k, int NKT){
    return ((n>>4)*NKT + (k>>5))*512 + ((k>>3)&3)*128 + (n&15)*8 + (k&7);
}

// ---------------- weight prep (all packs in one kernel) ----------------
__global__ void prep_all(const float* __restrict__ w0,
                         const float* __restrict__ w1r, const float* __restrict__ w1i,
                         const float* __restrict__ env_w, const float* __restrict__ lp_ws,
                         const float* __restrict__ lp_wv,
                         const float* __restrict__ oh_ss, const float* __restrict__ oh_sg,
                         const float* __restrict__ oh_vv,
                         __bf16* __restrict__ Wt, __bf16* __restrict__ w1rt, __bf16* __restrict__ w1it,
                         __bf16* __restrict__ Wevfm, __bf16* __restrict__ Bnodefm,
                         __bf16* __restrict__ Bvfm,
                         __bf16* __restrict__ envfm, __bf16* __restrict__ lpsfm,
                         __bf16* __restrict__ lpvfm,
                         __bf16* __restrict__ ssT, __bf16* __restrict__ sgT, __bf16* __restrict__ vvT)
{
    int t = blockIdx.x*256 + threadIdx.x;
    if (t < 576*256){                          // fallback row-major Wt[256][576]
        int n = t/576, k = t%576;
        Wt[t] = (__bf16)w0[(size_t)k*256 + n];
    }
    if (t < 256*320){                          // edge GEMM weights: rows {128..255}U{384..575}
        int n = t/320, k = t%320;
        int src = (k<128) ? (128+k) : (384+(k-128));
        Wevfm[fm_idx(n,k,10)] = (__bf16)w0[(size_t)src*256 + n];
    }
    if (t < 512*128){                          // node GEMM: cols 0..255 = W rows 0..127; 256..511 = rows 256..383
        int n = t/128, k = t%128;
        float v = (n<256) ? w0[(size_t)k*256 + n] : w0[(size_t)(256+k)*256 + (n-256)];
        Bnodefm[fm_idx(n,k,4)] = (__bf16)v;
    }
    if (t < 64*192){
        int c = t/192, k = t%192;
        w1rt[t] = (__bf16)w1r[(size_t)k*64 + c];
        w1it[t] = (__bf16)w1i[(size_t)k*64 + c];
    }
    if (t < 128*384){
        int n = t/384, k = t%384;
        float v;
        if (n < 64) v = (k<192) ? w1r[(size_t)k*64+n] : -w1i[(size_t)(k-192)*64+n];
        else        v = (k<192) ? w1i[(size_t)k*64+(n-64)] : w1r[(size_t)(k-192)*64+(n-64)];
        Bvfm[fm_idx(n,k,12)] = (__bf16)v;
    }
    if (t < 192*128){ int n=t/128, k=t%128; envfm[fm_idx(n,k,4)] = (__bf16)env_w[(size_t)k*192+n]; }
    if (t < 128*128){ int n=t/128, k=t%128; lpsfm[fm_idx(n,k,4)] = (__bf16)lp_ws[(size_t)k*128+n]; }
    if (t < 64*64)  { int n=t/64,  k=t%64;  lpvfm[fm_idx(n,k,2)] = (__bf16)lp_wv[(size_t)k*64+n]; }
    if (t < 64*128*128){                       // ssT[at][u][k]
        int at = t / 16384; int r = t & 16383; int u = r >> 7, k = r & 127;
        ssT[t] = (__bf16)oh_ss[((size_t)u*64 + at)*128 + k];
    }
    if (t < 64*128*64){                        // sgT[at][u][k]
        int at = t / 8192; int r = t & 8191; int u = r >> 6, k = r & 63;
        sgT[t] = (__bf16)oh_sg[((size_t)u*64 + at)*64 + k];
    }
    if (t < 64*64*64){                         // vvT[at][u][k]
        int at = t / 4096; int r = t & 4095; int u = r >> 6, k = r & 63;
        vvT[t] = (__bf16)oh_vv[((size_t)u*64 + at)*64 + k];
    }
}

// ---------------- CSR build ----------------
__global__ void csr_count(const int* __restrict__ ei, const int* __restrict__ act,
                          int* __restrict__ cnt, int EA)
{
    int e = blockIdx.x*256 + threadIdx.x;
    if (e < EA) atomicAdd(&cnt[ei[act[e]]], 1);
}
__global__ void csr_scan(const int* __restrict__ cnt, int* __restrict__ offs,
                         int* __restrict__ cursor, int N)
{
    __shared__ int part[256];
    int t = threadIdx.x;
    int chunk = (N + 255) / 256;
    int lo = t*chunk, hi = lo+chunk; if (hi > N) hi = N; if (lo > N) lo = N;
    int s = 0;
    for (int i=lo;i<hi;i++) s += cnt[i];
    part[t] = s;
    __syncthreads();
    for (int d=1; d<256; d<<=1){
        int v = (t>=d) ? part[t-d] : 0;
        __syncthreads();
        part[t] += v;
        __syncthreads();
    }
    int run = (t==0) ? 0 : part[t-1];
    for (int i=lo;i<hi;i++){
        offs[i] = run; cursor[i] = run;
        run += cnt[i];
    }
    if (t==255) offs[N] = part[255];
}
__global__ void csr_fill(const int* __restrict__ ei, const int* __restrict__ act,
                         int* __restrict__ cursor, int* __restrict__ elist, int EA)
{
    int e = blockIdx.x*256 + threadIdx.x;
    if (e < EA){
        int n = ei[act[e]];
        int p = atomicAdd(&cursor[n], 1);
        elist[p] = e;
    }
}

// ---------------- node separable layernorm (+ bf16 copies) ----------------
__global__ void node_ln_kernel(const float* __restrict__ nf,
                               const float* __restrict__ ws, const float* __restrict__ bs,
                               const float* __restrict__ wv,
                               float* __restrict__ ns, float* __restrict__ nv,
                               __bf16* __restrict__ nsb, __bf16* __restrict__ nvb, int N)
{
    int t = threadIdx.x;
    int lane = t & 63;
    int n = blockIdx.x*4 + (t>>6);
    if (n >= N) return;
    const float* row = nf + (size_t)n*320;
    float s0 = row[lane], s1 = row[64+lane];
    float sum = s0+s1, sq = s0*s0+s1*s1;
    #pragma unroll
    for (int m=1;m<64;m<<=1){ sum += __shfl_xor(sum,m,64); sq += __shfl_xor(sq,m,64); }
    float mu = sum*(1.0f/128.0f);
    float rs = rsqrtf(sq*(1.0f/128.0f) - mu*mu + EPS_LN);
    float o0 = (s0-mu)*rs*ws[lane]    + bs[lane];
    float o1 = (s1-mu)*rs*ws[64+lane] + bs[64+lane];
    ns[(size_t)n*128+lane]    = o0;
    ns[(size_t)n*128+64+lane] = o1;
    nsb[(size_t)n*128+lane]    = (__bf16)o0;
    nsb[(size_t)n*128+64+lane] = (__bf16)o1;
    float v0 = row[128+lane], v1 = row[192+lane], v2 = row[256+lane];
    float vs = v0*v0+v1*v1+v2*v2;
    #pragma unroll
    for (int m=1;m<64;m<<=1) vs += __shfl_xor(vs,m,64);
    float rv = rsqrtf(vs*(1.0f/192.0f) + EPS_LN);
    float nv0 = v0*rv*wv[lane/3];
    float nv1 = v1*rv*wv[(64+lane)/3];
    float nv2 = v2*rv*wv[(128+lane)/3];
    nv[(size_t)n*192+lane]     = nv0;
    nv[(size_t)n*192+64+lane]  = nv1;
    nv[(size_t)n*192+128+lane] = nv2;
    nvb[(size_t)n*192+lane]     = (__bf16)nv0;
    nvb[(size_t)n*192+64+lane]  = (__bf16)nv1;
    nvb[(size_t)n*192+128+lane] = (__bf16)nv2;
}

// ---------------- per-edge staging -> global bf16 (bf16 nv gathers) ----------------
__global__ void stage_kernel(
    const float* __restrict__ ef_all,
    const int*   __restrict__ edge_index,
    const float* __restrict__ edge_vector,
    const int*   __restrict__ active_edges,
    const float* __restrict__ e_ws, const float* __restrict__ e_bs, const float* __restrict__ e_wv,
    const __bf16* __restrict__ nvb,
    __bf16* __restrict__ m0in,   // [EA][320]: [es(128) | vf0(192)]
    __bf16* __restrict__ vfg,    // [EA][384]: [vf1(192) | vf2(192)]
    float* __restrict__ Rg, int2* __restrict__ ctnb,
    int EA, int EF)
{
    int tid = blockIdx.x*256 + threadIdx.x;
    int e = tid >> 4, l = tid & 15;
    if (e >= EA) return;
    int ae = active_edges[e];
    int ct = edge_index[ae];
    int nb = edge_index[EF + ae];
    float ex = edge_vector[(size_t)ae*3+0];
    float ey = edge_vector[(size_t)ae*3+1];
    float ez = edge_vector[(size_t)ae*3+2];
    float rn = rsqrtf(ex*ex+ey*ey+ez*ez + EPS_LN);
    float ax = ex*rn, ay = ey*rn, az = ez*rn;
    float rx, ry;
    if (fabsf(ax) < 0.9f) { rx = 1.0f; ry = 0.0f; } else { rx = 0.0f; ry = 1.0f; }
    float bx = -az*ry, by = az*rx, bz = ax*ry - ay*rx;
    float bn = rsqrtf(bx*bx+by*by+bz*bz + EPS_LN);
    bx*=bn; by*=bn; bz*=bn;
    float cx = ay*bz - az*by;
    float cy = az*bx - ax*bz;
    float cz = ax*by - ay*bx;
    if (l == 0){
        float* Rr = Rg + (size_t)e*12;
        *(float4*)(Rr)   = make_float4(ax,ay,az,bx);
        *(float4*)(Rr+4) = make_float4(by,bz,cx,cy);
        *(float4*)(Rr+8) = make_float4(cz,0.f,0.f,0.f);
        ctnb[e] = make_int2(ct, nb);
    }
    __bf16* Arow = m0in + (size_t)e*320;
    __bf16* V1r  = vfg + (size_t)e*384;
    __bf16* V2r  = V1r + 192;
    const float* ef = ef_all + (size_t)e*320;
    {   // edge scalar LN -> Arow[0:128)
        F4 sa, sb;
        sa.v = *(const float4*)(ef + l*4);
        sb.v = *(const float4*)(ef + 64 + l*4);
        float sum=0.f, sq=0.f;
        #pragma unroll
        for (int i=0;i<4;i++){ sum += sa.f[i]+sb.f[i]; sq += sa.f[i]*sa.f[i]+sb.f[i]*sb.f[i]; }
        #pragma unroll
        for (int m=1;m<16;m<<=1){ sum += __shfl_xor(sum,m,64); sq += __shfl_xor(sq,m,64); }
        float mu = sum*(1.0f/128.0f);
        float rs = rsqrtf(sq*(1.0f/128.0f)-mu*mu + EPS_LN);
        float o0[4], o1[4];
        #pragma unroll
        for (int i=0;i<4;i++){
            int c0 = l*4+i, c1 = 64+l*4+i;
            o0[i] = (sa.f[i]-mu)*rs*e_ws[c0]+e_bs[c0];
            o1[i] = (sb.f[i]-mu)*rs*e_ws[c1]+e_bs[c1];
        }
        st_g4(Arow + l*4,      o0[0],o0[1],o0[2],o0[3]);
        st_g4(Arow + 64 + l*4, o1[0],o1[1],o1[2],o1[3]);
    }
    {   // edge vector LN + rotate (u 64..127)
        F4 va, vb, vc;
        va.v = *(const float4*)(ef + 128 + l*12);
        vb.v = *(const float4*)(ef + 128 + l*12 + 4);
        vc.v = *(const float4*)(ef + 128 + l*12 + 8);
        float vv[12];
        #pragma unroll
        for (int i=0;i<4;i++){ vv[i]=va.f[i]; vv[4+i]=vb.f[i]; vv[8+i]=vc.f[i]; }
        float sq=0.f;
        #pragma unroll
        for (int i=0;i<12;i++) sq += vv[i]*vv[i];
        #pragma unroll
        for (int m=1;m<16;m<<=1) sq += __shfl_xor(sq,m,64);
        float rv = rsqrtf(sq*(1.0f/192.0f) + EPS_LN);
        float f0[4], f1[4], f2[4];
        #pragma unroll
        for (int j=0;j<4;j++){
            int u = 4*l + j;
            float sc = rv * e_wv[u];
            float x = vv[3*j]*sc, y = vv[3*j+1]*sc, z = vv[3*j+2]*sc;
            f0[j] = ax*x+ay*y+az*z;
            f1[j] = bx*x+by*y+bz*z;
            f2[j] = cx*x+cy*y+cz*z;
        }
        st_g4(Arow + 128 + 64 + 4*l, f0[0],f0[1],f0[2],f0[3]);
        st_g4(V1r + 64 + 4*l, f1[0],f1[1],f1[2],f1[3]);
        st_g4(V2r + 64 + 4*l, f2[0],f2[1],f2[2],f2[3]);
    }
    {   // nv[ctr] (u 0..63), bf16 gather
        float vv[12];
        ld_bf12(nvb + (size_t)ct*192 + l*12, vv);
        float f0[4], f1[4], f2[4];
        #pragma unroll
        for (int j=0;j<4;j++){
            float x = vv[3*j], y = vv[3*j+1], z = vv[3*j+2];
            f0[j] = ax*x+ay*y+az*z;
            f1[j] = bx*x+by*y+bz*z;
            f2[j] = cx*x+cy*y+cz*z;
        }
        st_g4(Arow + 128 + 4*l, f0[0],f0[1],f0[2],f0[3]);
        st_g4(V1r + 4*l, f1[0],f1[1],f1[2],f1[3]);
        st_g4(V2r + 4*l, f2[0],f2[1],f2[2],f2[3]);
    }
    {   // nv[nbr] (u 128..191), bf16 gather
        float vv[12];
        ld_bf12(nvb + (size_t)nb*192 + l*12, vv);
        float f0[4], f1[4], f2[4];
        #pragma unroll
        for (int j=0;j<4;j++){
            float x = vv[3*j], y = vv[3*j+1], z = vv[3*j+2];
            f0[j] = ax*x+ay*y+az*z;
            f1[j] = bx*x+by*y+bz*z;
            f2[j] = cx*x+cy*y+cz*z;
        }
        st_g4(Arow + 128 + 128 + 4*l, f0[0],f0[1],f0[2],f0[3]);
        st_g4(V1r + 128 + 4*l, f1[0],f1[1],f1[2],f1[3]);
        st_g4(V2r + 128 + 4*l, f2[0],f2[1],f2[2],f2[3]);
    }
}

// ---------------- tiled MFMA GEMM, fragment-major B direct from global (L2-resident) ----
enum { EPI_PLAIN=0, EPI_LPS=1, EPI_LPV=2 };

template<int N, int K, int RT, int EPI, bool AGATHER>
__global__ __launch_bounds__((N/64)*RT*64)
void gemm_k(const __bf16* __restrict__ Ag, const float* __restrict__ Agf,
            const int* __restrict__ aidx,
            const __bf16* __restrict__ Bfm,
            unsigned short* __restrict__ outp,
            const unsigned short* __restrict__ wenv,
            const float* __restrict__ bias,
            float scale, int M)
{
    constexpr int NT  = N/64;
    constexpr int BM  = RT*64;
    constexpr int T   = NT*RT*64;
    constexpr int NKT = K/32;
    constexpr int NK  = K/64;
    constexpr int NBUF= (NK>1) ? 2 : 1;
    constexpr int CA  = (BM*8 + T - 1)/T;
    __shared__ __align__(16) char lA[NBUF][BM*128];

    const int tid  = threadIdx.x;
    const int brow = blockIdx.x*BM;
    const int mpl  = blockIdx.y;
    const __bf16* A = AGATHER ? nullptr : (Ag + (size_t)mpl*M*K);

    uint4 ra[CA];
    auto loadA = [&](int ks){
        #pragma unroll
        for (int i=0;i<CA;i++){
            int c = tid + i*T;
            if (c < BM*8){
                int r = c>>3;
                int gr = brow + r; if (gr >= M) gr = M-1;
                if constexpr (AGATHER){
                    int ae = aidx[gr];
                    const float* base = Agf + (size_t)ae*K + ks*64 + (c&7)*8;
                    float4 f0 = *(const float4*)(base);
                    float4 f1 = *(const float4*)(base+4);
                    ra[i] = pack8(f0, f1);
                } else {
                    ra[i] = *(const uint4*)((const char*)(A + (size_t)gr*K + ks*64) + (c&7)*16);
                }
            }
        }
    };
    auto storeA = [&](int buf){
        #pragma unroll
        for (int i=0;i<CA;i++){
            int c = tid + i*T;
            if (c < BM*8){
                int r = c>>3, off = (c&7)*16;
                *(uint4*)(&lA[buf][r*128 + (off ^ ((r&7)<<4))]) = ra[i];
            }
        }
    };

    const int wid = tid>>6, ln = tid&63;
    const int cc = ln & 15, gq = ln >> 4;
    const int wn = wid % NT, wm = wid / NT;
    const __bf16* bbase = Bfm + ((size_t)wn*4*NKT)*512 + (size_t)ln*8;

    f32x4 acc[4][4];
    #pragma unroll
    for (int i=0;i<4;i++)
        #pragma unroll
        for (int j=0;j<4;j++) acc[i][j] = (f32x4){0,0,0,0};

    loadA(0); storeA(0);
    int cur = 0;
    for (int ks=0; ks<NK; ks++){
        __syncthreads();
        if (ks+1 < NK) loadA(ks+1);
        #pragma unroll
        for (int kt2=0;kt2<2;kt2++){
            const int kt = ks*2 + kt2;
            const int kb = kt2*64 + 16*gq;
            bf16x8 af[4];
            #pragma unroll
            for (int mf=0;mf<4;mf++){
                int r = wm*64 + mf*16 + cc;
                af[mf] = *(const bf16x8*)(&lA[cur][r*128 + (kb ^ ((r&7)<<4))]);
            }
            #pragma unroll
            for (int nf=0;nf<4;nf++){
                bf16x8 bfr = *(const bf16x8*)(bbase + ((size_t)nf*NKT + kt)*512);
                #pragma unroll
                for (int mf=0;mf<4;mf++)
                    acc[mf][nf] = __builtin_amdgcn_mfma_f32_16x16x32_bf16(af[mf], bfr, acc[mf][nf], 0,0,0);
            }
        }
        if (ks+1 < NK) storeA(cur^1);
        cur ^= (NBUF-1);
    }

    const float inv_avg_ = 0.288675134595f;
    #pragma unroll
    for (int mf=0;mf<4;mf++){
        #pragma unroll
        for (int nf=0;nf<4;nf++){
            #pragma unroll
            for (int j=0;j<4;j++){
                int gr = brow + wm*64 + mf*16 + gq*4 + j;
                if (gr >= M) continue;
                int col = wn*64 + nf*16 + cc;
                float v = acc[mf][nf][j];
                if constexpr (EPI == EPI_PLAIN){
                    outp[(size_t)gr*N + col] = f2bf(v*scale);
                } else if constexpr (EPI == EPI_LPS){
                    float val = (v*scale + bias[col]) * bf2f(wenv[(size_t)gr*192 + col]) * inv_avg_;
                    outp[(size_t)gr*320 + col] = f2bf(val);
                } else {
                    float val = v*0.125f * bf2f(wenv[(size_t)gr*192 + 128 + col]) * inv_avg_;
                    outp[(size_t)gr*320 + 128 + mpl*64 + col] = f2bf(val);
                }
            }
        }
    }
}

// ---------------- lp_v: 3 planes in one block, B in registers, single LDS buffer ----
__global__ __launch_bounds__(128)
void gemm_lpv(const __bf16* __restrict__ Ag,          // 3 planes of [M][64]
              const __bf16* __restrict__ Bfm,         // lp_wv fragment-major, N=64,K=64
              unsigned short* __restrict__ outp,
              const unsigned short* __restrict__ wenv,
              int M)
{
    constexpr int BM = 128;
    __shared__ __align__(16) char lA[BM*128];

    const int tid  = threadIdx.x;
    const int brow = blockIdx.x*BM;

    uint4 ra[8];
    auto loadA = [&](int pl){
        const __bf16* A = Ag + (size_t)pl*M*64;
        #pragma unroll
        for (int i=0;i<8;i++){
            int c = tid + i*128;
            int r = c>>3;
            int gr = brow + r; if (gr >= M) gr = M-1;
            ra[i] = *(const uint4*)((const char*)(A + (size_t)gr*64) + (c&7)*16);
        }
    };
    auto storeA = [&](){
        #pragma unroll
        for (int i=0;i<8;i++){
            int c = tid + i*128;
            int r = c>>3, off = (c&7)*16;
            *(uint4*)(&lA[r*128 + (off ^ ((r&7)<<4))]) = ra[i];
        }
    };

    const int wid = tid>>6, ln = tid&63;
    const int cc = ln & 15, gq = ln >> 4;
    const int wm = wid;

    bf16x8 bf_[4][2];
    {
        const __bf16* bbase = Bfm + (size_t)ln*8;
        #pragma unroll
        for (int nf=0;nf<4;nf++)
            #pragma unroll
            for (int kt=0;kt<2;kt++)
                bf_[nf][kt] = *(const bf16x8*)(bbase + ((size_t)nf*2 + kt)*512);
    }

    loadA(0); storeA();
    const float inv_avg_ = 0.288675134595f;
    for (int pl=0; pl<3; pl++){
        __syncthreads();
        if (pl < 2) loadA(pl+1);
        f32x4 acc[4][4];
        #pragma unroll
        for (int i=0;i<4;i++)
            #pragma unroll
            for (int j=0;j<4;j++) acc[i][j] = (f32x4){0,0,0,0};
        #pragma unroll
        for (int kt=0;kt<2;kt++){
            const int kb = kt*64 + 16*gq;
            bf16x8 af[4];
            #pragma unroll
            for (int mf=0;mf<4;mf++){
                int r = wm*64 + mf*16 + cc;
                af[mf] = *(const bf16x8*)(&lA[r*128 + (kb ^ ((r&7)<<4))]);
            }
            #pragma unroll
            for (int nf=0;nf<4;nf++)
                #pragma unroll
                for (int mf=0;mf<4;mf++)
                    acc[mf][nf] = __builtin_amdgcn_mfma_f32_16x16x32_bf16(af[mf], bf_[nf][kt], acc[mf][nf], 0,0,0);
        }
        __syncthreads();
        if (pl < 2) storeA();
        #pragma unroll
        for (int mf=0;mf<4;mf++){
            #pragma unroll
            for (int nf=0;nf<4;nf++){
                #pragma unroll
                for (int j=0;j<4;j++){
                    int gr = brow + wm*64 + mf*16 + gq*4 + j;
                    if (gr >= M) continue;
                    int col = nf*16 + cc;
                    float val = acc[mf][nf][j]*0.125f * bf2f(wenv[(size_t)gr*192 + 128 + col]) * inv_avg_;
                    outp[(size_t)gr*320 + 128 + pl*64 + col] = f2bf(val);
                }
            }
        }
    }
}

// ---------------- mid: nodeCN gather-add + gate + rotate-back + silu ----------------
__global__ void mid_kernel(const unsigned short* __restrict__ m0out,
                           const unsigned short* __restrict__ vpvm,
                           const float* __restrict__ Rg,
                           const int2* __restrict__ ctnb,
                           const __bf16* __restrict__ nodeCN,
                           unsigned short* __restrict__ As,
                           unsigned short* __restrict__ MVp, int EA)
{
    int tid = blockIdx.x*256 + threadIdx.x;
    int e = tid>>6, u = tid&63;
    if (e >= EA) return;
    float rl = (u < 12) ? Rg[(size_t)e*12 + u] : 0.f;
    float R0=__shfl(rl,0,64), R1=__shfl(rl,1,64), R2=__shfl(rl,2,64);
    float R3=__shfl(rl,3,64), R4=__shfl(rl,4,64), R5=__shfl(rl,5,64);
    float R6=__shfl(rl,6,64), R7=__shfl(rl,7,64), R8=__shfl(rl,8,64);
    int2 cn = ctnb[e];
    const __bf16* nct = nodeCN + (size_t)cn.x*512;
    const __bf16* nnb = nodeCN + (size_t)cn.y*512 + 256;
    const float rn0 = 0.0416666666667f;
    float a0 = ((float)nct[u]       + (float)nnb[u])       * rn0;
    float a1 = ((float)nct[64+u]    + (float)nnb[64+u])    * rn0;
    float a2 = ((float)nct[128+u]   + (float)nnb[128+u])   * rn0;
    float a3 = ((float)nct[192+u]   + (float)nnb[192+u])   * rn0;
    const unsigned short* mo = m0out + (size_t)e*256;
    float m0 = bf2f(mo[u])       + a0;
    float m1 = bf2f(mo[64 + u])  + a1;
    float gt = sigmoidf_(bf2f(mo[128 + u]) + a2);
    float s0 = bf2f(mo[192 + u]) + a3;
    float p  = bf2f(vpvm[(size_t)e*128 + u]);
    float q  = bf2f(vpvm[(size_t)e*128 + 64 + u]);
    size_t eu = (size_t)e*64 + u;
    size_t P  = (size_t)EA*64;
    MVp[eu]       = f2bf(gt*(R0*s0 + R3*p + R6*q));
    MVp[P + eu]   = f2bf(gt*(R1*s0 + R4*p + R7*q));
    MVp[2*P + eu] = f2bf(gt*(R2*s0 + R5*p + R8*q));
    As[(size_t)e*128 + u]      = f2bf(siluf_(m0));
    As[(size_t)e*128 + 64 + u] = f2bf(siluf_(m1));
}

// ---------------- fallback: fused edge kernel (round-3, plane-layout stores) ----------------
__launch_bounds__(256, 3)
__global__ void edge_kernel_fused(
    const float* __restrict__ latents,
    const float* __restrict__ ef_all,
    const int*   __restrict__ edge_index,
    const float* __restrict__ edge_vector,
    const int*   __restrict__ active_edges,
    const float* __restrict__ e_ws, const float* __restrict__ e_bs, const float* __restrict__ e_wv,
    const __bf16* __restrict__ Wt,
    const __bf16* __restrict__ w1rt,
    const __bf16* __restrict__ w1it,
    const float* __restrict__ env_w,
    const float* __restrict__ lp_ws, const float* __restrict__ lp_bs, const float* __restrict__ lp_wv,
    const float* __restrict__ ns, const float* __restrict__ nv,
    unsigned short* __restrict__ eout,
    int EA, int EF)
{
    __shared__ __align__(16) char smem[46592];
    char* sAbC = smem;
    char* sVFC = smem + 18432;
    float* sO  = (float*)smem;
    float* MV  = (float*)(smem + 16640);
    float* WE  = (float*)(smem + 33280);
    float* sR  = (float*)(smem + 45824);

    const int t = threadIdx.x;
    const int g = t >> 4, l = t & 15;
    const int e = blockIdx.x*16 + g;
    const bool act = (e < EA);

    int ct = 0, ae = 0;

    if (act) {
        ae = active_edges[e];
        ct = edge_index[ae];
        int nb = edge_index[EF + ae];
        float ex = edge_vector[(size_t)ae*3+0];
        float ey = edge_vector[(size_t)ae*3+1];
        float ez = edge_vector[(size_t)ae*3+2];
        float rn = rsqrtf(ex*ex+ey*ey+ez*ez + EPS_LN);
        float ax = ex*rn, ay = ey*rn, az = ez*rn;
        float rx, ry;
        if (fabsf(ax) < 0.9f) { rx = 1.0f; ry = 0.0f; } else { rx = 0.0f; ry = 1.0f; }
        float bx = -az*ry, by = az*rx, bz = ax*ry - ay*rx;
        float bn = rsqrtf(bx*bx+by*by+bz*bz + EPS_LN);
        bx*=bn; by*=bn; bz*=bn;
        float cx = ay*bz - az*by;
        float cy = az*bx - ax*bz;
        float cz = ax*by - ay*bx;
        if (l == 0){
            float* Rr = &sR[g*12];
            Rr[0]=ax; Rr[1]=ay; Rr[2]=az;
            Rr[3]=bx; Rr[4]=by; Rr[5]=bz;
            Rr[6]=cx; Rr[7]=cy; Rr[8]=cz;
        }
        {
            const float4* pc4 = (const float4*)(ns + (size_t)ct*128);
            const float4* pn4 = (const float4*)(ns + (size_t)nb*128);
            F4 a,b2,c,d;
            a.v = pc4[l]; b2.v = pc4[16+l]; c.v = pn4[l]; d.v = pn4[16+l];
            st_bf4(sAbC, g, 1152, l*4,       a.f[0],a.f[1],a.f[2],a.f[3]);
            st_bf4(sAbC, g, 1152, 64+l*4,    b2.f[0],b2.f[1],b2.f[2],b2.f[3]);
            st_bf4(sAbC, g, 1152, 256+l*4,   c.f[0],c.f[1],c.f[2],c.f[3]);
            st_bf4(sAbC, g, 1152, 320+l*4,   d.f[0],d.f[1],d.f[2],d.f[3]);
        }
        const float* ef = ef_all + (size_t)e*320;
        {
            F4 sa, sb;
            sa.v = *(const float4*)(ef + l*4);
            sb.v = *(const float4*)(ef + 64 + l*4);
            float sum=0.f, sq=0.f;
            #pragma unroll
            for (int i=0;i<4;i++){ sum += sa.f[i]+sb.f[i]; sq += sa.f[i]*sa.f[i]+sb.f[i]*sb.f[i]; }
            #pragma unroll
            for (int m=1;m<16;m<<=1){ sum += __shfl_xor(sum,m,64); sq += __shfl_xor(sq,m,64); }
            float mu = sum*(1.0f/128.0f);
            float rs = rsqrtf(sq*(1.0f/128.0f)-mu*mu + EPS_LN);
            float o0[4], o1[4];
            #pragma unroll
            for (int i=0;i<4;i++){
                int c0 = l*4+i, c1 = 64+l*4+i;
                o0[i] = (sa.f[i]-mu)*rs*e_ws[c0]+e_bs[c0];
                o1[i] = (sb.f[i]-mu)*rs*e_ws[c1]+e_bs[c1];
            }
            st_bf4(sAbC, g, 1152, 128+l*4, o0[0],o0[1],o0[2],o0[3]);
            st_bf4(sAbC, g, 1152, 192+l*4, o1[0],o1[1],o1[2],o1[3]);
        }
        {
            F4 va, vb, vc;
            va.v = *(const float4*)(ef + 128 + l*12);
            vb.v = *(const float4*)(ef + 128 + l*12 + 4);
            vc.v = *(const float4*)(ef + 128 + l*12 + 8);
            float vv[12];
            #pragma unroll
            for (int i=0;i<4;i++){ vv[i]=va.f[i]; vv[4+i]=vb.f[i]; vv[8+i]=vc.f[i]; }
            float sq=0.f;
            #pragma unroll
            for (int i=0;i<12;i++) sq += vv[i]*vv[i];
            #pragma unroll
            for (int m=1;m<16;m<<=1) sq += __shfl_xor(sq,m,64);
            float rv = rsqrtf(sq*(1.0f/192.0f) + EPS_LN);
            float f0[4], f1[4], f2[4];
            #pragma unroll
            for (int j=0;j<4;j++){
                int u = 4*l + j;
                float sc = rv * e_wv[u];
                float x = vv[3*j]*sc, y = vv[3*j+1]*sc, z = vv[3*j+2]*sc;
                f0[j] = ax*x+ay*y+az*z;
                f1[j] = bx*x+by*y+bz*z;
                f2[j] = cx*x+cy*y+cz*z;
            }
            st_bf4(sAbC, g, 1152, 384+64+4*l, f0[0],f0[1],f0[2],f0[3]);
            st_bf4(sVFC, g, 384, 64+4*l, f1[0],f1[1],f1[2],f1[3]);
            st_bf4(sVFC+6144, g, 384, 64+4*l, f2[0],f2[1],f2[2],f2[3]);
        }
        {
            const float* pv = nv + (size_t)ct*192 + l*12;
            F4 va, vb, vc;
            va.v = *(const float4*)(pv);
            vb.v = *(const float4*)(pv+4);
            vc.v = *(const float4*)(pv+8);
            float vv[12];
            #pragma unroll
            for (int i=0;i<4;i++){ vv[i]=va.f[i]; vv[4+i]=vb.f[i]; vv[8+i]=vc.f[i]; }
            float f0[4], f1[4], f2[4];
            #pragma unroll
            for (int j=0;j<4;j++){
                float x = vv[3*j], y = vv[3*j+1], z = vv[3*j+2];
                f0[j] = ax*x+ay*y+az*z;
                f1[j] = bx*x+by*y+bz*z;
                f2[j] = cx*x+cy*y+cz*z;
            }
            st_bf4(sAbC, g, 1152, 384+4*l, f0[0],f0[1],f0[2],f0[3]);
            st_bf4(sVFC, g, 384, 4*l, f1[0],f1[1],f1[2],f1[3]);
            st_bf4(sVFC+6144, g, 384, 4*l, f2[0],f2[1],f2[2],f2[3]);
        }
        {
            const float* pv = nv + (size_t)nb*192 + l*12;
            F4 va, vb, vc;
            va.v = *(const float4*)(pv);
            vb.v = *(const float4*)(pv+4);
            vc.v = *(const float4*)(pv+8);
            float vv[12];
            #pragma unroll
            for (int i=0;i<4;i++){ vv[i]=va.f[i]; vv[4+i]=vb.f[i]; vv[8+i]=vc.f[i]; }
            float f0[4], f1[4], f2[4];
            #pragma unroll
            for (int j=0;j<4;j++){
                float x = vv[3*j], y = vv[3*j+1], z = vv[3*j+2];
                f0[j] = ax*x+ay*y+az*z;
                f1[j] = bx*x+by*y+bz*z;
                f2[j] = cx*x+cy*y+cz*z;
            }
            st_bf4(sAbC, g, 1152, 384+128+4*l, f0[0],f0[1],f0[2],f0[3]);
            st_bf4(sVFC, g, 384, 128+4*l, f1[0],f1[1],f1[2],f1[3]);
            st_bf4(sVFC+6144, g, 384, 128+4*l, f2[0],f2[1],f2[2],f2[3]);
        }
    }
    __syncthreads();

    const int w  = t >> 6;
    const int ln = t & 63;
    const int cc = ln & 15;
    const int gq = ln >> 4;

    f32x4 accM[4] = {{0,0,0,0},{0,0,0,0},{0,0,0,0},{0,0,0,0}};
    {
        const __bf16* wb0 = Wt + (size_t)(64*w + 0  + cc)*576;
        const __bf16* wb1 = Wt + (size_t)(64*w + 16 + cc)*576;
        const __bf16* wb2 = Wt + (size_t)(64*w + 32 + cc)*576;
        const __bf16* wb3 = Wt + (size_t)(64*w + 48 + cc)*576;
        for (int ks=0; ks<18; ks++){
            bf16x8 a = ld_frag(sAbC, cc, 1152, ks*64 + 16*gq);
            int ko = ks*32 + 8*gq;
            bf16x8 b0 = *(const bf16x8*)(wb0 + ko);
            bf16x8 b1 = *(const bf16x8*)(wb1 + ko);
            bf16x8 b2 = *(const bf16x8*)(wb2 + ko);
            bf16x8 b3 = *(const bf16x8*)(wb3 + ko);
            accM[0] = __builtin_amdgcn_mfma_f32_16x16x32_bf16(a, b0, accM[0], 0,0,0);
            accM[1] = __builtin_amdgcn_mfma_f32_16x16x32_bf16(a, b1, accM[1], 0,0,0);
            accM[2] = __builtin_amdgcn_mfma_f32_16x16x32_bf16(a, b2, accM[2], 0,0,0);
            accM[3] = __builtin_amdgcn_mfma_f32_16x16x32_bf16(a, b3, accM[3], 0,0,0);
        }
    }
    f32x4 aP1={0,0,0,0}, aP2={0,0,0,0}, aM1={0,0,0,0}, aM2={0,0,0,0};
    {
        const __bf16* wr = w1rt + (size_t)(16*w + cc)*192;
        const __bf16* wi = w1it + (size_t)(16*w + cc)*192;
        for (int ks=0; ks<6; ks++){
            bf16x8 a1 = ld_frag(sVFC,        cc, 384, ks*64 + 16*gq);
            bf16x8 a2 = ld_frag(sVFC + 6144, cc, 384, ks*64 + 16*gq);
            int ko = ks*32 + 8*gq;
            bf16x8 br = *(const bf16x8*)(wr + ko);
            bf16x8 bi = *(const bf16x8*)(wi + ko);
            aP1 = __builtin_amdgcn_mfma_f32_16x16x32_bf16(a1, br, aP1, 0,0,0);
            aP2 = __builtin_amdgcn_mfma_f32_16x16x32_bf16(a2, bi, aP2, 0,0,0);
            aM1 = __builtin_amdgcn_mfma_f32_16x16x32_bf16(a1, bi, aM1, 0,0,0);
            aM2 = __builtin_amdgcn_mfma_f32_16x16x32_bf16(a2, br, aM2, 0,0,0);
        }
    }
    __syncthreads();

    {
        const float rn0 = 0.0416666666667f;
        #pragma unroll
        for (int jt=0;jt<4;jt++){
            #pragma unroll
            for (int j=0;j<4;j++){
                sO[(gq*4+j)*260 + 64*w + 16*jt + cc] = accM[jt][j]*rn0;
            }
        }
    }
    float vp[4], vm[4];
    {
        const float n1 = 0.0721687836487f;
        #pragma unroll
        for (int j=0;j<4;j++){ vp[j] = (aP1[j]-aP2[j])*n1; vm[j] = (aM1[j]+aM2[j])*n1; }
    }
    __syncthreads();

    {
        int u = w*16 + cc;
        #pragma unroll
        for (int j=0;j<4;j++){
            int er = gq*4 + j;
            if (blockIdx.x*16 + er < EA){
                const float* Rr = &sR[er*12];
                float s0 = sO[er*260 + 192 + u];
                float gt = sigmoidf_(sO[er*260 + 128 + u]);
                float p = vp[j], q = vm[j];
                float4 o;
                o.x = gt*(Rr[0]*s0 + Rr[3]*p + Rr[6]*q);
                o.y = gt*(Rr[1]*s0 + Rr[4]*p + Rr[7]*q);
                o.z = gt*(Rr[2]*s0 + Rr[5]*p + Rr[8]*q);
                o.w = 0.0f;
                *(float4*)&MV[er*260 + u*4] = o;
            }
        }
    }
    if (act) {
        {
            int i0 = l*8;
            F4 oa, ob;
            oa.v = *(const float4*)&sO[g*260 + i0];
            ob.v = *(const float4*)&sO[g*260 + i0 + 4];
            #pragma unroll
            for (int i=0;i<4;i++){ oa.f[i] = siluf_(oa.f[i]); ob.f[i] = siluf_(ob.f[i]); }
            *(float4*)&sO[g*260 + i0]     = oa.v;
            *(float4*)&sO[g*260 + i0 + 4] = ob.v;
        }
        {
            const int cc2 = l*12;
            float wacc[12];
            #pragma unroll
            for (int i=0;i<12;i++) wacc[i]=0.f;
            const float* lat = latents + (size_t)ae*128;
            for (int k=0;k<128;k+=4){
                F4 la;
                la.v = *(const float4*)(lat + k);
                #pragma unroll
                for (int kk=0;kk<4;kk++){
                    const float* er_ = env_w + (size_t)(k+kk)*192 + cc2;
                    F4 e0v,e1v,e2v;
                    e0v.v = *(const float4*)(er_);
                    e1v.v = *(const float4*)(er_+4);
                    e2v.v = *(const float4*)(er_+8);
                    #pragma unroll
                    for (int i=0;i<4;i++){
                        wacc[i]   += la.f[kk]*e0v.f[i];
                        wacc[4+i] += la.f[kk]*e1v.f[i];
                        wacc[8+i] += la.f[kk]*e2v.f[i];
                    }
                }
            }
            const float inv128 = 0.0883883476483f;
            #pragma unroll
            for (int i=0;i<12;i++) WE[g*196 + cc2 + i] = wacc[i]*inv128;
        }
    }
    __syncthreads();

    if (act) {
        const float inv_avg = 0.288675134595f;
        unsigned short* orow = eout + (size_t)e*320;
        {
            int c0 = l*8;
            float a8[8];
            #pragma unroll
            for (int i=0;i<8;i++) a8[i]=0.f;
            for (int k=0;k<128;k+=4){
                F4 av;
                av.v = *(const float4*)&sO[g*260 + k];
                #pragma unroll
                for (int kk=0;kk<4;kk++){
                    const float* wr = lp_ws + (size_t)(k+kk)*128 + c0;
                    F4 w0, w1_;
                    w0.v  = *(const float4*)(wr);
                    w1_.v = *(const float4*)(wr+4);
                    #pragma unroll
                    for (int i=0;i<4;i++){ a8[i] += av.f[kk]*w0.f[i]; a8[4+i] += av.f[kk]*w1_.f[i]; }
                }
            }
            const float s128 = 0.0883883476483f;
            union { unsigned short h[8]; uint4 u; } ps;
            #pragma unroll
            for (int i=0;i<8;i++){
                int c = c0+i;
                ps.h[i] = f2bf((a8[i]*s128 + lp_bs[c]) * WE[g*196 + c] * inv_avg);
            }
            *(uint4*)(orow + c0) = ps.u;
        }
        {
            int k0 = l*4;
            float av[4][3];
            #pragma unroll
            for (int j=0;j<4;j++)
                #pragma unroll
                for (int m2=0;m2<3;m2++) av[j][m2]=0.f;
            for (int u=0;u<64;u++){
                F4 wv4, mv4;
                wv4.v = *(const float4*)(lp_wv + (size_t)u*64 + k0);
                mv4.v = *(const float4*)&MV[g*260 + u*4];
                #pragma unroll
                for (int j=0;j<4;j++){
                    av[j][0] += wv4.f[j]*mv4.f[0];
                    av[j][1] += wv4.f[j]*mv4.f[1];
                    av[j][2] += wv4.f[j]*mv4.f[2];
                }
            }
            #pragma unroll
            for (int j=0;j<4;j++){
                int k = k0+j;
                float wk = WE[g*196 + 128 + k] * 0.125f * inv_avg;
                orow[128 +       k] = f2bf(av[j][0]*wk);
                orow[128 + 64  + k] = f2bf(av[j][1]*wk);
                orow[128 + 128 + k] = f2bf(av[j][2]*wk);
            }
        }
    }
}

// ---------------- node CSR aggregate + onehot path + output (cooperative einsums) ----------------
__global__ void node_out_kernel(
    const float* __restrict__ nf,
    const int* __restrict__ atom_type,
    const int* __restrict__ offs, const int* __restrict__ elist,
    const unsigned short* __restrict__ eout,
    const __bf16* __restrict__ ssT, const __bf16* __restrict__ sgT, const __bf16* __restrict__ vvT,
    const float* __restrict__ ohl_ws, const float* __restrict__ ohl_bs, const float* __restrict__ ohl_wv,
    const float* __restrict__ res_param,
    float* __restrict__ out, int N)
{
    __shared__ int   sE[64];
    __shared__ float AGS[128];
    __shared__ float AGV[192];
    __shared__ float TSs[128];
    __shared__ float SG[64];
    __shared__ float TV[192];
    __shared__ float PS[2560];     // partials: ss [4][128] | sg [8][64] | vv [8][192]
    const int n = blockIdx.x;
    const int t = threadIdx.x;
    const int at = atom_type[n];
    const int lo = offs[n], hi = offs[n+1];

    // gather-aggregate: threads 0..159 own cols {2t, 2t+1}; 4-stream ILP
    float aLo = 0.f, aHi = 0.f;
    for (int base = lo; base < hi; base += 64){
        int cnt = hi - base; if (cnt > 64) cnt = 64;
        __syncthreads();
        if (t < cnt) sE[t] = elist[base + t];
        __syncthreads();
        if (t < 160){
            int i = 0;
            for (; i+4 <= cnt; i += 4){
                unsigned x0 = *(const unsigned*)(eout + (size_t)sE[i  ]*320 + 2*t);
                unsigned x1 = *(const unsigned*)(eout + (size_t)sE[i+1]*320 + 2*t);
                unsigned x2 = *(const unsigned*)(eout + (size_t)sE[i+2]*320 + 2*t);
                unsigned x3 = *(const unsigned*)(eout + (size_t)sE[i+3]*320 + 2*t);
                aLo += bf2f((unsigned short)x0) + bf2f((unsigned short)x1)
                     + bf2f((unsigned short)x2) + bf2f((unsigned short)x3);
                aHi += bf2f((unsigned short)(x0>>16)) + bf2f((unsigned short)(x1>>16))
                     + bf2f((unsigned short)(x2>>16)) + bf2f((unsigned short)(x3>>16));
            }
            for (; i < cnt; i++){
                unsigned x = *(const unsigned*)(eout + (size_t)sE[i]*320 + 2*t);
                aLo += bf2f((unsigned short)x);
                aHi += bf2f((unsigned short)(x>>16));
            }
        }
    }
    if (t < 160){
        int c0 = 2*t, c1 = 2*t+1;
        if (c0 < 128) AGS[c0] = aLo; else { int d=c0-128; AGV[(d&63)*3 + (d>>6)] = aLo; }
        if (c1 < 128) AGS[c1] = aHi; else { int d=c1-128; AGV[(d&63)*3 + (d>>6)] = aHi; }
    }
    __syncthreads();
    const float n_ss = 0.0110485434560f;
    const float n_vv = 0.015625f;

    // ---- cooperative partial einsums (all 256 threads, uint loads) ----
    {   // ss: 4 u-streams x 64 k-pairs
        int us = t >> 6, kp = t & 63;
        float aclo = 0.f, achi = 0.f;
        const __bf16* w = ssT + (size_t)at*16384 + 2*kp;
        #pragma unroll 4
        for (int u = us; u < 128; u += 4){
            unsigned w2 = *(const unsigned*)(w + (size_t)u*128);
            float a = AGS[u];
            aclo += a * bf2f((unsigned short)w2);
            achi += a * bf2f((unsigned short)(w2>>16));
        }
        PS[us*128 + 2*kp]   = aclo;
        PS[us*128 + 2*kp+1] = achi;
    }
    {   // sg: 8 u-streams x 32 k-pairs
        int us = t >> 5, kp = t & 31;
        float aclo = 0.f, achi = 0.f;
        const __bf16* w = sgT + (size_t)at*8192 + 2*kp;
        #pragma unroll 4
        for (int u = us; u < 128; u += 8){
            unsigned w2 = *(const unsigned*)(w + (size_t)u*64);
            float a = AGS[u];
            aclo += a * bf2f((unsigned short)w2);
            achi += a * bf2f((unsigned short)(w2>>16));
        }
        PS[512 + us*64 + 2*kp]   = aclo;
        PS[512 + us*64 + 2*kp+1] = achi;
    }
    {   // vv: 8 u-streams x 32 k-pairs x 3 m
        int us = t >> 5, kp = t & 31;
        float ac00=0,ac01=0,ac02=0, ac10=0,ac11=0,ac12=0;
        const __bf16* w = vvT + (size_t)at*4096 + 2*kp;
        #pragma unroll 2
        for (int u = us; u < 64; u += 8){
            unsigned w2 = *(const unsigned*)(w + (size_t)u*64);
            float w0 = bf2f((unsigned short)w2), w1 = bf2f((unsigned short)(w2>>16));
            float a0 = AGV[u*3+0], a1 = AGV[u*3+1], a2 = AGV[u*3+2];
            ac00 += a0*w0; ac01 += a1*w0; ac02 += a2*w0;
            ac10 += a0*w1; ac11 += a1*w1; ac12 += a2*w1;
        }
        float* pv = &PS[1024 + us*192];
        pv[(2*kp)*3+0]=ac00; pv[(2*kp)*3+1]=ac01; pv[(2*kp)*3+2]=ac02;
        pv[(2*kp+1)*3+0]=ac10; pv[(2*kp+1)*3+1]=ac11; pv[(2*kp+1)*3+2]=ac12;
    }
    __syncthreads();
    if (t < 128){
        float s = PS[t] + PS[128+t] + PS[256+t] + PS[384+t];
        TSs[t] = siluf_(s*n_ss);
    } else if (t < 192){
        int k = t-128;
        float s = 0.f;
        #pragma unroll
        for (int us=0; us<8; us++) s += PS[512 + us*64 + k];
        SG[k] = sigmoidf_(s*n_ss);
    } else {
        int k = t-192;
        float s0=0,s1=0,s2=0;
        #pragma unroll
        for (int us=0; us<8; us++){
            const float* pv = &PS[1024 + us*192 + k*3];
            s0 += pv[0]; s1 += pv[1]; s2 += pv[2];
        }
        TV[k*3+0]=s0*n_vv; TV[k*3+1]=s1*n_vv; TV[k*3+2]=s2*n_vv;
    }
    __syncthreads();
    const float alpha = sigmoidf_(res_param[0]);
    const float beta  = 1.0f - alpha;
    if (t < 128) {
        float acc = 0.0f;
        #pragma unroll 8
        for (int k=0;k<128;k++) acc += TSs[k]*ohl_ws[(size_t)k*128 + t];
        float val = acc*0.0883883476483f + ohl_bs[t];
        out[(size_t)n*320 + t] = alpha*nf[(size_t)n*320 + t] + beta*val;
    } else if (t >= 192) {
        int k = t-192;
        float a0=0,a1=0,a2=0;
        #pragma unroll 8
        for (int u=0;u<64;u++){
            float w = ohl_wv[(size_t)u*64 + k]*SG[u];
            a0 += TV[u*3+0]*w; a1 += TV[u*3+1]*w; a2 += TV[u*3+2]*w;
        }
        size_t base = (size_t)n*320 + 128 + (size_t)k*3;
        out[base+0] = alpha*nf[base+0] + beta*(a0*0.125f);
        out[base+1] = alpha*nf[base+1] + beta*(a1*0.125f);
        out[base+2] = alpha*nf[base+2] + beta*(a2*0.125f);
    }
}

extern "C" void kernel_launch(void* const* d_in, const int* in_sizes, int n_in,
                              void* d_out, int out_size, void* d_ws, size_t ws_size,
                              hipStream_t stream)
{
    const float* latents       = (const float*)d_in[0];
    const float* node_features = (const float*)d_in[1];
    const float* edge_features = (const float*)d_in[2];
    const int*   atom_type     = (const int*)d_in[3];
    const int*   edge_index    = (const int*)d_in[5];
    const float* edge_vector   = (const float*)d_in[6];
    const int*   active_edges  = (const int*)d_in[7];
    const float* sln_n_ws = (const float*)d_in[8];
    const float* sln_n_bs = (const float*)d_in[9];
    const float* sln_n_wv = (const float*)d_in[10];
    const float* sln_e_ws = (const float*)d_in[11];
    const float* sln_e_bs = (const float*)d_in[12];
    const float* sln_e_wv = (const float*)d_in[13];
    const float* so2_w0   = (const float*)d_in[14];
    const float* so2_w1r  = (const float*)d_in[15];
    const float* so2_w1i  = (const float*)d_in[16];
    const float* env_w    = (const float*)d_in[17];
    const float* lp_ws    = (const float*)d_in[18];
    const float* lp_bs    = (const float*)d_in[19];
    const float* lp_wv    = (const float*)d_in[20];
    const float* oh_w_ss  = (const float*)d_in[21];
    const float* oh_w_sg  = (const float*)d_in[22];
    const float* oh_w_vv  = (const float*)d_in[23];
    const float* ohl_ws   = (const float*)d_in[24];
    const float* ohl_bs   = (const float*)d_in[25];
    const float* ohl_wv   = (const float*)d_in[26];
    const float* res_param= (const float*)d_in[27];
    float* out = (float*)d_out;

    const int N  = in_sizes[1] / 320;
    const int EF = in_sizes[5] / 2;
    const int EA = in_sizes[7];

    // workspace layout (256B-aligned chunks)
    char* p = (char*)d_ws;
    auto alloc = [&](size_t bytes) -> char* {
        char* r = p; p += (bytes + 255) & ~(size_t)255; return r;
    };
    float* ns      = (float*)alloc((size_t)N*128*4);
    float* nv      = (float*)alloc((size_t)N*192*4);
    __bf16* nsb    = (__bf16*)alloc((size_t)N*128*2);
    __bf16* nvb    = (__bf16*)alloc((size_t)N*192*2);
    int*   cnt     = (int*)  alloc((size_t)N*4);
    int*   offs    = (int*)  alloc(((size_t)N+1)*4);
    int*   cursor  = (int*)  alloc((size_t)N*4);
    int*   elist   = (int*)  alloc((size_t)EA*4);
    __bf16* Wt     = (__bf16*)alloc((size_t)576*256*2);
    __bf16* w1rt   = (__bf16*)alloc((size_t)64*192*2);
    __bf16* w1it   = (__bf16*)alloc((size_t)64*192*2);
    __bf16* Wevfm  = (__bf16*)alloc((size_t)256*320*2);
    __bf16* Bnodefm= (__bf16*)alloc((size_t)512*128*2);
    __bf16* Bvfm   = (__bf16*)alloc((size_t)128*384*2);
    __bf16* envfm  = (__bf16*)alloc((size_t)192*128*2);
    __bf16* lpsfm  = (__bf16*)alloc((size_t)128*128*2);
    __bf16* lpvfm  = (__bf16*)alloc((size_t)64*64*2);
    __bf16* ssT    = (__bf16*)alloc((size_t)64*128*128*2);
    __bf16* sgT    = (__bf16*)alloc((size_t)64*128*64*2);
    __bf16* vvT    = (__bf16*)alloc((size_t)64*64*64*2);
    __bf16* nodeCN = (__bf16*)alloc((size_t)N*512*2);
    int2*  ctnb    = (int2*) alloc((size_t)EA*8);
    unsigned short* eout = (unsigned short*)alloc((size_t)EA*320*2);
    unsigned short* w_env= (unsigned short*)alloc((size_t)EA*192*2);
    float*  Rg    = (float*) alloc((size_t)EA*12*4);
    __bf16* m0in  = (__bf16*)alloc((size_t)EA*320*2);
    __bf16* vfg   = (__bf16*)alloc((size_t)EA*384*2);
    size_t split_need = (size_t)(p - (char*)d_ws);
    const bool use_split = (split_need <= ws_size);

    // aliases (split path only; all uses are stream-ordered)
    unsigned short* vpvm  = eout;                   // [EA][128], consumed by mid before eout written
    unsigned short* m0out = (unsigned short*)vfg;   // [EA][256], written after vfg consumed
    unsigned short* As    = (unsigned short*)m0in;  // [EA][128], after m0in consumed
    unsigned short* MVp   = As + (size_t)EA*128;    // 3 planes [EA][64]; 128+192=320 fits m0in width

    hipMemsetAsync(cnt, 0, (size_t)N*sizeof(int), stream);
    prep_all<<<4096, 256, 0, stream>>>(so2_w0, so2_w1r, so2_w1i, env_w, lp_ws, lp_wv,
                                       oh_w_ss, oh_w_sg, oh_w_vv,
                                       Wt, w1rt, w1it, Wevfm, Bnodefm, Bvfm,
                                       envfm, lpsfm, lpvfm, ssT, sgT, vvT);
    node_ln_kernel<<<(N+3)/4, 256, 0, stream>>>(node_features, sln_n_ws, sln_n_bs, sln_n_wv, ns, nv, nsb, nvb, N);
    csr_count<<<(EA+255)/256, 256, 0, stream>>>(edge_index, active_edges, cnt, EA);
    csr_scan<<<1, 256, 0, stream>>>(cnt, offs, cursor, N);
    csr_fill<<<(EA+255)/256, 256, 0, stream>>>(edge_index, active_edges, cursor, elist, EA);

    const float rn0    = 0.0416666666667f;   // 1/sqrt(576)
    const float n1     = 0.0721687836487f;   // 1/sqrt(192)
    const float inv128 = 0.0883883476483f;   // 1/sqrt(128)

    if (use_split){
        const int NB64  = (EA + 63) / 64;
        const int NB128 = (EA + 127) / 128;
        const int NBn   = (N + 63) / 64;
        // node-side contributions: nsb[N][128] x [512 cols] -> nodeCN[N][512] (raw scale)
        gemm_k<512,128,1,EPI_PLAIN,false><<<dim3(NBn,1), 512, 0, stream>>>(
            nsb, nullptr, nullptr, Bnodefm, (unsigned short*)nodeCN, nullptr, nullptr, 1.0f, N);
        stage_kernel<<<(EA+15)/16, 256, 0, stream>>>(edge_features, edge_index, edge_vector, active_edges,
            sln_e_ws, sln_e_bs, sln_e_wv, nvb, m0in, vfg, Rg, ctnb, EA, EF);
        // vp/vm: [EA][384] x Bv -> vpvm[EA][128]  (before main so vfg dead when m0out overlays)
        gemm_k<128,384,2,EPI_PLAIN,false><<<dim3(NB128,1), 256, 0, stream>>>(
            vfg, nullptr, nullptr, Bvfm, vpvm, nullptr, nullptr, n1, EA);
        // main: [EA][320] x Wev -> m0out[EA][256] (partial; node terms added in mid)
        gemm_k<256,320,1,EPI_PLAIN,false><<<dim3(NB64,1), 256, 0, stream>>>(
            m0in, nullptr, nullptr, Wevfm, m0out, nullptr, nullptr, rn0, EA);
        // nodeCN gather-add + gate + rotate-back + silu
        mid_kernel<<<(EA*64+255)/256, 256, 0, stream>>>(m0out, vpvm, Rg, ctnb, nodeCN, As, MVp, EA);
        gemm_k<192,128,1,EPI_PLAIN,true><<<dim3(NB64,1), 192, 0, stream>>>(
            nullptr, latents, active_edges, envfm, w_env, nullptr, nullptr, inv128, EA);
        gemm_k<128,128,2,EPI_LPS,false><<<dim3(NB128,1), 256, 0, stream>>>(
            (const __bf16*)As, nullptr, nullptr, lpsfm, eout, w_env, lp_bs, inv128, EA);
        // lp vector: all 3 planes in one kernel
        gemm_lpv<<<NB128, 128, 0, stream>>>(
            (const __bf16*)MVp, lpvfm, eout, w_env, EA);
    } else {
        edge_kernel_fused<<<(EA+15)/16, 256, 0, stream>>>(latents, edge_features, edge_index, edge_vector, active_edges,
            sln_e_ws, sln_e_bs, sln_e_wv, Wt, w1rt, w1it, env_w, lp_ws, lp_bs, lp_wv,
            ns, nv, eout, EA, EF);
    }
    node_out_kernel<<<N, 256, 0, stream>>>(node_features, atom_type, offs, elist, eout,
        ssT, sgT, vvT, ohl_ws, ohl_bs, ohl_wv, res_param, out, N);
}